// Round 1
// baseline (908.219 us; speedup 1.0000x reference)
//
#include <hip/hip_runtime.h>
#include <hip/hip_bf16.h>

#define T_TOK 8192
#define D_DIM 1024
#define H_DIM 768
#define E_EXP 16
#define K_TOP 2
#define TK (T_TOK * K_TOP)

typedef __bf16 bf16x8 __attribute__((ext_vector_type(8)));
typedef unsigned short u16x8 __attribute__((ext_vector_type(8)));
typedef float f32x4 __attribute__((ext_vector_type(4)));

__device__ __forceinline__ unsigned short f2b(float f) {
    __hip_bfloat16 h = __float2bfloat16(f);
    return __builtin_bit_cast(unsigned short, h);
}
__device__ __forceinline__ float b2f(unsigned short u) {
    unsigned int x = ((unsigned int)u) << 16;
    return __builtin_bit_cast(float, x);
}

// ---------------- routing ----------------
__global__ void k_count(const int* __restrict__ idx, int* __restrict__ cnt) {
    int i = blockIdx.x * blockDim.x + threadIdx.x;
    if (i < TK) atomicAdd(&cnt[idx[i]], 1);
}

__global__ void k_scan(const int* __restrict__ cnt, int* __restrict__ offs) {
    if (threadIdx.x == 0) {
        int s = 0;
        for (int e = 0; e < E_EXP; ++e) { offs[e] = s; s += cnt[e]; }
        offs[E_EXP] = s;
    }
}

__global__ void k_scatter(const int* __restrict__ idx, const float* __restrict__ wts,
                          const int* __restrict__ offs, int* __restrict__ cur,
                          int* __restrict__ rows, float* __restrict__ wslot,
                          int* __restrict__ slot_of) {
    int i = blockIdx.x * blockDim.x + threadIdx.x;
    if (i < TK) {
        int e = idx[i];
        int p = atomicAdd(&cur[e], 1);
        int s = offs[e] + p;
        rows[s] = i >> 1;          // K_TOP == 2
        wslot[s] = wts[i];
        slot_of[i] = s;
    }
}

// ---------------- GEMM1: act = gate(x_gathered @ W1[e]) ----------------
// block: 256 thr (4 waves). BM=128 rows, 64 act cols (=> 128 W1 cols: v|g). BK=32.
__global__ __launch_bounds__(256) void k_gemm1(
    const float* __restrict__ x, const float* __restrict__ W1,
    const int* __restrict__ offs, const int* __restrict__ rows,
    unsigned short* __restrict__ act) {
    const int e = blockIdx.z;
    const int off = offs[e];
    const int n_e = offs[e + 1] - off;
    if (n_e == 0) return;
    const int tiles = (n_e + 127) >> 7;
    const int h0 = blockIdx.y * 64;
    const float* __restrict__ W1e = W1 + (size_t)e * D_DIM * (2 * H_DIM);

    __shared__ unsigned short Ab[128][40];
    __shared__ unsigned short Bb[128][40];

    const int tid = threadIdx.x;
    const int wid = tid >> 6, lane = tid & 63;
    const int l15 = lane & 15, kq = lane >> 4;

    for (int mt = blockIdx.x; mt < tiles; mt += gridDim.x) {
        const int m0 = mt << 7;
        f32x4 accv[2][4], accg[2][4];
#pragma unroll
        for (int m = 0; m < 2; ++m)
#pragma unroll
            for (int n = 0; n < 4; ++n)
#pragma unroll
                for (int r = 0; r < 4; ++r) { accv[m][n][r] = 0.f; accg[m][n][r] = 0.f; }

        for (int k0 = 0; k0 < D_DIM; k0 += 32) {
            __syncthreads();
            {   // A stage: gather x rows, fp32 -> bf16
                const int r0 = tid >> 3, q = tid & 7;
#pragma unroll
                for (int rr = 0; rr < 4; ++rr) {
                    const int r = r0 + rr * 32;
                    float4 v = make_float4(0.f, 0.f, 0.f, 0.f);
                    if (m0 + r < n_e) {
                        const int tok = rows[off + m0 + r];
                        v = *reinterpret_cast<const float4*>(&x[(size_t)tok * D_DIM + k0 + q * 4]);
                    }
                    ushort4 u;
                    u.x = f2b(v.x); u.y = f2b(v.y); u.z = f2b(v.z); u.w = f2b(v.w);
                    *reinterpret_cast<ushort4*>(&Ab[r][q * 4]) = u;
                }
            }
            {   // B stage (transposed): Bb[c][k] = W1e[k0+k][col(c)]; cols 0..63 = v, 64..127 = g
                const int kk = tid & 31, cg = tid >> 5;
#pragma unroll
                for (int j = 0; j < 4; ++j) {
                    const int c0 = (cg + 8 * j) * 4;   // 0..124
                    const int gcol = (c0 < 64) ? (h0 + c0) : (H_DIM + h0 + c0 - 64);
                    const float4 v = *reinterpret_cast<const float4*>(
                        &W1e[(size_t)(k0 + kk) * (2 * H_DIM) + gcol]);
                    Bb[c0 + 0][kk] = f2b(v.x);
                    Bb[c0 + 1][kk] = f2b(v.y);
                    Bb[c0 + 2][kk] = f2b(v.z);
                    Bb[c0 + 3][kk] = f2b(v.w);
                }
            }
            __syncthreads();

            bf16x8 a[2], bv[4], bg[4];
#pragma unroll
            for (int m = 0; m < 2; ++m)
                a[m] = __builtin_bit_cast(bf16x8,
                    *reinterpret_cast<const u16x8*>(&Ab[wid * 32 + m * 16 + l15][kq * 8]));
#pragma unroll
            for (int n = 0; n < 4; ++n) {
                bv[n] = __builtin_bit_cast(bf16x8,
                    *reinterpret_cast<const u16x8*>(&Bb[n * 16 + l15][kq * 8]));
                bg[n] = __builtin_bit_cast(bf16x8,
                    *reinterpret_cast<const u16x8*>(&Bb[64 + n * 16 + l15][kq * 8]));
            }
#pragma unroll
            for (int m = 0; m < 2; ++m)
#pragma unroll
                for (int n = 0; n < 4; ++n) {
                    accv[m][n] = __builtin_amdgcn_mfma_f32_16x16x32_bf16(a[m], bv[n], accv[m][n], 0, 0, 0);
                    accg[m][n] = __builtin_amdgcn_mfma_f32_16x16x32_bf16(a[m], bg[n], accg[m][n], 0, 0, 0);
                }
        }
        // epilogue: act = v * silu(g), bf16 store
#pragma unroll
        for (int m = 0; m < 2; ++m)
#pragma unroll
            for (int n = 0; n < 4; ++n)
#pragma unroll
                for (int r = 0; r < 4; ++r) {
                    const int row = wid * 32 + m * 16 + kq * 4 + r;
                    if (m0 + row < n_e) {
                        const int col = n * 16 + l15;
                        const float vv = accv[m][n][r], gg = accg[m][n][r];
                        const float s = gg / (1.0f + __expf(-gg));
                        act[(size_t)(off + m0 + row) * H_DIM + h0 + col] = f2b(vv * s);
                    }
                }
    }
}

// ---------------- GEMM2: out_slot = wslot * (act @ W2[e]) ----------------
__global__ __launch_bounds__(256) void k_gemm2(
    const unsigned short* __restrict__ act, const float* __restrict__ W2,
    const int* __restrict__ offs, const float* __restrict__ wslot,
    unsigned short* __restrict__ slot_out, float* __restrict__ y,
    const int* __restrict__ rows, int atomic_mode) {
    const int e = blockIdx.z;
    const int off = offs[e];
    const int n_e = offs[e + 1] - off;
    if (n_e == 0) return;
    const int tiles = (n_e + 127) >> 7;
    const int n0 = blockIdx.y * 64;
    const float* __restrict__ W2e = W2 + (size_t)e * H_DIM * D_DIM;

    __shared__ unsigned short Ab[128][40];
    __shared__ unsigned short Bb[64][40];

    const int tid = threadIdx.x;
    const int wid = tid >> 6, lane = tid & 63;
    const int l15 = lane & 15, kq = lane >> 4;

    for (int mt = blockIdx.x; mt < tiles; mt += gridDim.x) {
        const int m0 = mt << 7;
        f32x4 acc[2][4];
#pragma unroll
        for (int m = 0; m < 2; ++m)
#pragma unroll
            for (int n = 0; n < 4; ++n)
#pragma unroll
                for (int r = 0; r < 4; ++r) acc[m][n][r] = 0.f;

        for (int k0 = 0; k0 < H_DIM; k0 += 32) {
            __syncthreads();
            {   // A stage: bf16 act rows (contiguous)
                const int r0 = tid >> 3, q = tid & 7;
#pragma unroll
                for (int rr = 0; rr < 4; ++rr) {
                    const int r = r0 + rr * 32;
                    ushort4 u = make_ushort4(0, 0, 0, 0);
                    if (m0 + r < n_e)
                        u = *reinterpret_cast<const ushort4*>(
                            &act[(size_t)(off + m0 + r) * H_DIM + k0 + q * 4]);
                    *reinterpret_cast<ushort4*>(&Ab[r][q * 4]) = u;
                }
            }
            {   // B stage (transposed): Bb[c][k] = W2e[k0+k][n0+c]
                const int kk = tid & 31, cg = tid >> 5;
#pragma unroll
                for (int j = 0; j < 2; ++j) {
                    const int c0 = (cg + 8 * j) * 4;   // 0..60
                    const float4 v = *reinterpret_cast<const float4*>(
                        &W2e[(size_t)(k0 + kk) * D_DIM + n0 + c0]);
                    Bb[c0 + 0][kk] = f2b(v.x);
                    Bb[c0 + 1][kk] = f2b(v.y);
                    Bb[c0 + 2][kk] = f2b(v.z);
                    Bb[c0 + 3][kk] = f2b(v.w);
                }
            }
            __syncthreads();

            bf16x8 a[2], b[4];
#pragma unroll
            for (int m = 0; m < 2; ++m)
                a[m] = __builtin_bit_cast(bf16x8,
                    *reinterpret_cast<const u16x8*>(&Ab[wid * 32 + m * 16 + l15][kq * 8]));
#pragma unroll
            for (int n = 0; n < 4; ++n)
                b[n] = __builtin_bit_cast(bf16x8,
                    *reinterpret_cast<const u16x8*>(&Bb[n * 16 + l15][kq * 8]));
#pragma unroll
            for (int m = 0; m < 2; ++m)
#pragma unroll
                for (int n = 0; n < 4; ++n)
                    acc[m][n] = __builtin_amdgcn_mfma_f32_16x16x32_bf16(a[m], b[n], acc[m][n], 0, 0, 0);
        }
        // epilogue: scale by routing weight
#pragma unroll
        for (int m = 0; m < 2; ++m)
#pragma unroll
            for (int r = 0; r < 4; ++r) {
                const int row = wid * 32 + m * 16 + kq * 4 + r;
                if (m0 + row < n_e) {
                    const int slot = off + m0 + row;
                    const float w = wslot[slot];
#pragma unroll
                    for (int n = 0; n < 4; ++n) {
                        const int col = n * 16 + l15;
                        const float o = w * acc[m][n][r];
                        if (atomic_mode)
                            atomicAdd(&y[(size_t)rows[slot] * D_DIM + n0 + col], o);
                        else
                            slot_out[(size_t)slot * D_DIM + n0 + col] = f2b(o);
                    }
                }
            }
    }
}

// ---------------- combine: y[t] = out[slot(t,0)] + out[slot(t,1)] ----------------
__global__ __launch_bounds__(256) void k_combine(
    const unsigned short* __restrict__ slot_out, const int* __restrict__ slot_of,
    float* __restrict__ y) {
    const int t = blockIdx.x;
    const int d = threadIdx.x * 4;
    const int s0 = slot_of[2 * t], s1 = slot_of[2 * t + 1];
    const ushort4 a = *reinterpret_cast<const ushort4*>(&slot_out[(size_t)s0 * D_DIM + d]);
    const ushort4 b = *reinterpret_cast<const ushort4*>(&slot_out[(size_t)s1 * D_DIM + d]);
    float4 r;
    r.x = b2f(a.x) + b2f(b.x);
    r.y = b2f(a.y) + b2f(b.y);
    r.z = b2f(a.z) + b2f(b.z);
    r.w = b2f(a.w) + b2f(b.w);
    *reinterpret_cast<float4*>(&y[(size_t)t * D_DIM + d]) = r;
}

extern "C" void kernel_launch(void* const* d_in, const int* in_sizes, int n_in,
                              void* d_out, int out_size, void* d_ws, size_t ws_size,
                              hipStream_t stream) {
    const float* x = (const float*)d_in[0];
    const float* wts = (const float*)d_in[1];
    const int* idx = (const int*)d_in[2];
    // d_in[3] = counts (unused by the reference math)
    const float* W1 = (const float*)d_in[4];
    const float* W2 = (const float*)d_in[5];
    float* y = (float*)d_out;

    char* ws = (char*)d_ws;
    int* cnt = (int*)(ws + 0);         // 16 ints
    int* cur = (int*)(ws + 64);        // 16 ints
    int* offs = (int*)(ws + 128);      // 17 ints
    int* rows = (int*)(ws + 256);                        // TK ints
    float* wslot = (float*)(ws + 256 + (size_t)TK * 4);  // TK floats
    int* slot_of = (int*)(ws + 256 + (size_t)TK * 8);    // TK ints
    const size_t ACT_OFF = 256 + (size_t)TK * 12;        // aligned (divisible by 256)
    unsigned short* act = (unsigned short*)(ws + ACT_OFF);
    const size_t SO_OFF = ACT_OFF + (size_t)TK * H_DIM * 2;
    unsigned short* slot_out = (unsigned short*)(ws + SO_OFF);
    const size_t need_full = SO_OFF + (size_t)TK * D_DIM * 2;

    const int atomic_mode = (ws_size < need_full) ? 1 : 0;

    hipMemsetAsync(ws, 0, 128, stream);  // zero cnt + cur
    k_count<<<(TK + 255) / 256, 256, 0, stream>>>(idx, cnt);
    k_scan<<<1, 64, 0, stream>>>(cnt, offs);
    k_scatter<<<(TK + 255) / 256, 256, 0, stream>>>(idx, wts, offs, cur, rows, wslot, slot_of);

    dim3 g1(16, H_DIM / 64, E_EXP);
    k_gemm1<<<g1, 256, 0, stream>>>(x, W1, offs, rows, act);

    if (atomic_mode) hipMemsetAsync(y, 0, (size_t)out_size * 4, stream);

    dim3 g2(16, D_DIM / 64, E_EXP);
    k_gemm2<<<g2, 256, 0, stream>>>(act, W2, offs, wslot, slot_out, y, rows, atomic_mode);

    if (!atomic_mode)
        k_combine<<<T_TOK, 256, 0, stream>>>(slot_out, slot_of, y);
}

// Round 2
// 348.619 us; speedup vs baseline: 2.6052x; 2.6052x over previous
//
#include <hip/hip_runtime.h>
#include <hip/hip_bf16.h>

#define T_TOK 8192
#define D_DIM 1024
#define H_DIM 768
#define E_EXP 16
#define K_TOP 2
#define TK (T_TOK * K_TOP)
#define NTMAX 144   // max BM=128 tiles: 16384/128 + 16 partials

typedef __bf16 bf16x8 __attribute__((ext_vector_type(8)));
typedef unsigned short u16x8 __attribute__((ext_vector_type(8)));
typedef float f32x4 __attribute__((ext_vector_type(4)));

typedef const __attribute__((address_space(1))) void* gas_t;
typedef __attribute__((address_space(3))) void* las_t;

__device__ __forceinline__ unsigned short f2b(float f) {
    __hip_bfloat16 h = __float2bfloat16(f);
    return __builtin_bit_cast(unsigned short, h);
}
__device__ __forceinline__ float b2f(unsigned short u) {
    unsigned int x = ((unsigned int)u) << 16;
    return __builtin_bit_cast(float, x);
}

// ---------------- routing ----------------
__global__ void k_count(const int* __restrict__ idx, int* __restrict__ cnt) {
    int i = blockIdx.x * blockDim.x + threadIdx.x;
    if (i < TK) atomicAdd(&cnt[idx[i]], 1);
}

__global__ void k_scan(const int* __restrict__ cnt, int* __restrict__ offs,
                       int* __restrict__ tiletab, int* __restrict__ ntiles) {
    if (threadIdx.x == 0) {
        int s = 0, nt = 0;
        for (int e = 0; e < E_EXP; ++e) {
            offs[e] = s;
            const int n = cnt[e];
            for (int m0 = 0; m0 < n; m0 += 128) tiletab[nt++] = (e << 16) | (m0 >> 7);
            s += n;
        }
        offs[E_EXP] = s;
        ntiles[0] = nt;
        for (int i = nt; i < NTMAX; ++i) tiletab[i] = -1;
    }
}

__global__ void k_scatter(const int* __restrict__ idx, const float* __restrict__ wts,
                          const int* __restrict__ offs, int* __restrict__ cur,
                          int* __restrict__ rows, float* __restrict__ wslot,
                          int* __restrict__ slot_of) {
    int i = blockIdx.x * blockDim.x + threadIdx.x;
    if (i < TK) {
        int e = idx[i];
        int p = atomicAdd(&cur[e], 1);
        int s = offs[e] + p;
        rows[s] = i >> 1;          // K_TOP == 2
        wslot[s] = wts[i];
        slot_of[i] = s;
    }
}

// ---------------- gather + cast: xg[slot][D] bf16 ----------------
__global__ __launch_bounds__(256) void k_gather(const float* __restrict__ x,
                                                const int* __restrict__ rows,
                                                unsigned short* __restrict__ xg) {
    const int s = blockIdx.x, t = threadIdx.x;
    const int tok = rows[s];
    const float4 v = *reinterpret_cast<const float4*>(&x[(size_t)tok * D_DIM + t * 4]);
    ushort4 u;
    u.x = f2b(v.x); u.y = f2b(v.y); u.z = f2b(v.z); u.w = f2b(v.w);
    *reinterpret_cast<ushort4*>(&xg[(size_t)s * D_DIM + t * 4]) = u;
}

// ---------------- cast + transpose: src [e][K][C] f32 -> dst [e][C][K] bf16 ----------------
__global__ __launch_bounds__(256) void k_castT(const float* __restrict__ src,
                                               unsigned short* __restrict__ dst,
                                               int K, int C) {
    const int e = blockIdx.z;
    const int kb = blockIdx.x * 32, cb = blockIdx.y * 32;
    __shared__ float t4[32][33];
    const int tid = threadIdx.x;
    const float* s = src + ((size_t)e * K + kb) * C + cb;
    {
        const int kk = tid >> 3, c4 = (tid & 7) * 4;
        const float4 v = *reinterpret_cast<const float4*>(&s[(size_t)kk * C + c4]);
        t4[kk][c4] = v.x; t4[kk][c4 + 1] = v.y; t4[kk][c4 + 2] = v.z; t4[kk][c4 + 3] = v.w;
    }
    __syncthreads();
    {
        const int cc = tid >> 3, k4 = (tid & 7) * 4;
        ushort4 u;
        u.x = f2b(t4[k4][cc]); u.y = f2b(t4[k4 + 1][cc]);
        u.z = f2b(t4[k4 + 2][cc]); u.w = f2b(t4[k4 + 3][cc]);
        *reinterpret_cast<ushort4*>(&dst[((size_t)e * C + cb + cc) * K + kb + k4]) = u;
    }
}

// ---------------- GEMM1: act = v * silu(g),  [v|g] = xg @ W1[e] ----------------
// MODE 0: B from W1T bf16 [e][c][k] via global_load_lds. MODE 1: B from W1 fp32 reg-transpose.
template <int MODE>
__global__ __launch_bounds__(256) void k_gemm1(
    const unsigned short* __restrict__ xg, const float* __restrict__ W1,
    const unsigned short* __restrict__ W1T,
    const int* __restrict__ offs, const int* __restrict__ tiletab,
    unsigned short* __restrict__ act) {
    const int tt = tiletab[blockIdx.x];
    if (tt < 0) return;
    const int e = tt >> 16, m0 = (tt & 0xffff) << 7;
    const int off = offs[e], n_e = offs[e + 1] - off;
    const int h0 = blockIdx.y * 64;

    __shared__ unsigned short Ab[128 * 64];
    __shared__ unsigned short Bb[128 * 66];
    const int BS = (MODE == 0) ? 64 : 66;

    const int tid = threadIdx.x;
    const int wid = tid >> 6, lane = tid & 63;
    const int l15 = lane & 15, kq = lane >> 4;

    f32x4 acc[2][8];
#pragma unroll
    for (int m = 0; m < 2; ++m)
#pragma unroll
        for (int n = 0; n < 8; ++n)
#pragma unroll
            for (int r = 0; r < 4; ++r) acc[m][n][r] = 0.f;

    for (int k0 = 0; k0 < D_DIM; k0 += 64) {
        __syncthreads();
        // ---- A stage: xg rows via global_load_lds (row-major [128][64] bf16) ----
#pragma unroll
        for (int j = 0; j < 4; ++j) {
            const int o = wid * 4096 + j * 1024 + lane * 16;  // byte offset in tile
            const int row = o >> 7, kb = o & 127;
            int gr = off + m0 + row; gr = (gr < TK) ? gr : (TK - 1);  // clamp tail overread
            const unsigned short* gp = xg + (size_t)gr * D_DIM + k0 + (kb >> 1);
            __builtin_amdgcn_global_load_lds((gas_t)gp,
                (las_t)((char*)Ab + wid * 4096 + j * 1024), 16, 0, 0);
        }
        // ---- B stage ----
        if constexpr (MODE == 0) {
#pragma unroll
            for (int j = 0; j < 4; ++j) {
                const int o = wid * 4096 + j * 1024 + lane * 16;
                const int brow = o >> 7, kb = o & 127;
                const int wc = (brow < 64) ? (h0 + brow) : (H_DIM + h0 + brow - 64);
                const unsigned short* gp = W1T + ((size_t)e * (2 * H_DIM) + wc) * D_DIM + k0 + (kb >> 1);
                __builtin_amdgcn_global_load_lds((gas_t)gp,
                    (las_t)((char*)Bb + wid * 4096 + j * 1024), 16, 0, 0);
            }
        } else {
            const float* W1e = W1 + (size_t)e * D_DIM * (2 * H_DIM);
#pragma unroll
            for (int i = 0; i < 8; ++i) {
                const int flat = tid + 256 * i;
                const int cg = flat & 31, kk = flat >> 5;
                const int c = cg * 4;
                const int gc = (c < 64) ? (h0 + c) : (H_DIM + h0 + c - 64);
                const float4 v = *reinterpret_cast<const float4*>(
                    &W1e[(size_t)(k0 + kk) * (2 * H_DIM) + gc]);
                Bb[(c + 0) * 66 + kk] = f2b(v.x);
                Bb[(c + 1) * 66 + kk] = f2b(v.y);
                Bb[(c + 2) * 66 + kk] = f2b(v.z);
                Bb[(c + 3) * 66 + kk] = f2b(v.w);
            }
        }
        __syncthreads();
        // ---- compute: 2 k-slices of 32 ----
#pragma unroll
        for (int ks = 0; ks < 2; ++ks) {
            bf16x8 a[2], b[8];
#pragma unroll
            for (int m = 0; m < 2; ++m)
                a[m] = __builtin_bit_cast(bf16x8, *reinterpret_cast<const u16x8*>(
                    &Ab[(wid * 32 + m * 16 + l15) * 64 + ks * 32 + kq * 8]));
#pragma unroll
            for (int n = 0; n < 8; ++n)
                b[n] = __builtin_bit_cast(bf16x8, *reinterpret_cast<const u16x8*>(
                    &Bb[(n * 16 + l15) * BS + ks * 32 + kq * 8]));
#pragma unroll
            for (int m = 0; m < 2; ++m)
#pragma unroll
                for (int n = 0; n < 8; ++n)
                    acc[m][n] = __builtin_amdgcn_mfma_f32_16x16x32_bf16(a[m], b[n], acc[m][n], 0, 0, 0);
        }
    }
    // ---- epilogue: silu-gate, bf16 store ----
#pragma unroll
    for (int m = 0; m < 2; ++m)
#pragma unroll
        for (int n = 0; n < 4; ++n)
#pragma unroll
            for (int r = 0; r < 4; ++r) {
                const int row = wid * 32 + m * 16 + kq * 4 + r;
                if (m0 + row < n_e) {
                    const int col = n * 16 + l15;
                    const float vv = acc[m][n][r], gg = acc[m][n + 4][r];
                    const float s = gg / (1.0f + __expf(-gg));
                    act[(size_t)(off + m0 + row) * H_DIM + h0 + col] = f2b(vv * s);
                }
            }
}

// ---------------- GEMM2: out = wslot * (act @ W2[e]) ----------------
template <int MODE>
__global__ __launch_bounds__(256) void k_gemm2(
    const unsigned short* __restrict__ act, const float* __restrict__ W2,
    const unsigned short* __restrict__ W2T,
    const int* __restrict__ offs, const int* __restrict__ tiletab,
    const float* __restrict__ wslot, unsigned short* __restrict__ slot_out,
    float* __restrict__ y, const int* __restrict__ rows, int atomic_mode) {
    const int tt = tiletab[blockIdx.x];
    if (tt < 0) return;
    const int e = tt >> 16, m0 = (tt & 0xffff) << 7;
    const int off = offs[e], n_e = offs[e + 1] - off;
    const int n0 = blockIdx.y * 64;

    __shared__ unsigned short Ab[128 * 64];
    __shared__ unsigned short Bb[64 * 66];
    const int BS = (MODE == 0) ? 64 : 66;

    const int tid = threadIdx.x;
    const int wid = tid >> 6, lane = tid & 63;
    const int l15 = lane & 15, kq = lane >> 4;

    f32x4 acc[2][4];
#pragma unroll
    for (int m = 0; m < 2; ++m)
#pragma unroll
        for (int n = 0; n < 4; ++n)
#pragma unroll
            for (int r = 0; r < 4; ++r) acc[m][n][r] = 0.f;

    for (int k0 = 0; k0 < H_DIM; k0 += 64) {
        __syncthreads();
        // ---- A stage: act rows via global_load_lds ----
#pragma unroll
        for (int j = 0; j < 4; ++j) {
            const int o = wid * 4096 + j * 1024 + lane * 16;
            const int row = o >> 7, kb = o & 127;
            int gr = off + m0 + row; gr = (gr < TK) ? gr : (TK - 1);
            const unsigned short* gp = act + (size_t)gr * H_DIM + k0 + (kb >> 1);
            __builtin_amdgcn_global_load_lds((gas_t)gp,
                (las_t)((char*)Ab + wid * 4096 + j * 1024), 16, 0, 0);
        }
        // ---- B stage ----
        if constexpr (MODE == 0) {
#pragma unroll
            for (int j = 0; j < 2; ++j) {
                const int o = wid * 2048 + j * 1024 + lane * 16;
                const int brow = o >> 7, kb = o & 127;
                const unsigned short* gp = W2T + ((size_t)e * D_DIM + n0 + brow) * H_DIM + k0 + (kb >> 1);
                __builtin_amdgcn_global_load_lds((gas_t)gp,
                    (las_t)((char*)Bb + wid * 2048 + j * 1024), 16, 0, 0);
            }
        } else {
            const float* W2e = W2 + (size_t)e * H_DIM * D_DIM;
#pragma unroll
            for (int i = 0; i < 4; ++i) {
                const int flat = tid + 256 * i;
                const int cg = flat & 15, kk = flat >> 4;
                const int c = cg * 4;
                const float4 v = *reinterpret_cast<const float4*>(
                    &W2e[(size_t)(k0 + kk) * D_DIM + n0 + c]);
                Bb[(c + 0) * 66 + kk] = f2b(v.x);
                Bb[(c + 1) * 66 + kk] = f2b(v.y);
                Bb[(c + 2) * 66 + kk] = f2b(v.z);
                Bb[(c + 3) * 66 + kk] = f2b(v.w);
            }
        }
        __syncthreads();
#pragma unroll
        for (int ks = 0; ks < 2; ++ks) {
            bf16x8 a[2], b[4];
#pragma unroll
            for (int m = 0; m < 2; ++m)
                a[m] = __builtin_bit_cast(bf16x8, *reinterpret_cast<const u16x8*>(
                    &Ab[(wid * 32 + m * 16 + l15) * 64 + ks * 32 + kq * 8]));
#pragma unroll
            for (int n = 0; n < 4; ++n)
                b[n] = __builtin_bit_cast(bf16x8, *reinterpret_cast<const u16x8*>(
                    &Bb[(n * 16 + l15) * BS + ks * 32 + kq * 8]));
#pragma unroll
            for (int m = 0; m < 2; ++m)
#pragma unroll
                for (int n = 0; n < 4; ++n)
                    acc[m][n] = __builtin_amdgcn_mfma_f32_16x16x32_bf16(a[m], b[n], acc[m][n], 0, 0, 0);
        }
    }
    // ---- epilogue ----
#pragma unroll
    for (int m = 0; m < 2; ++m)
#pragma unroll
        for (int r = 0; r < 4; ++r) {
            const int row = wid * 32 + m * 16 + kq * 4 + r;
            if (m0 + row < n_e) {
                const int slot = off + m0 + row;
                const float w = wslot[slot];
#pragma unroll
                for (int n = 0; n < 4; ++n) {
                    const int col = n * 16 + l15;
                    const float o = w * acc[m][n][r];
                    if (atomic_mode)
                        atomicAdd(&y[(size_t)rows[slot] * D_DIM + n0 + col], o);
                    else
                        slot_out[(size_t)slot * D_DIM + n0 + col] = f2b(o);
                }
            }
        }
}

// ---------------- combine ----------------
__global__ __launch_bounds__(256) void k_combine(
    const unsigned short* __restrict__ slot_out, const int* __restrict__ slot_of,
    float* __restrict__ y) {
    const int t = blockIdx.x;
    const int d = threadIdx.x * 4;
    const int s0 = slot_of[2 * t], s1 = slot_of[2 * t + 1];
    const ushort4 a = *reinterpret_cast<const ushort4*>(&slot_out[(size_t)s0 * D_DIM + d]);
    const ushort4 b = *reinterpret_cast<const ushort4*>(&slot_out[(size_t)s1 * D_DIM + d]);
    float4 r;
    r.x = b2f(a.x) + b2f(b.x);
    r.y = b2f(a.y) + b2f(b.y);
    r.z = b2f(a.z) + b2f(b.z);
    r.w = b2f(a.w) + b2f(b.w);
    *reinterpret_cast<float4*>(&y[(size_t)t * D_DIM + d]) = r;
}

extern "C" void kernel_launch(void* const* d_in, const int* in_sizes, int n_in,
                              void* d_out, int out_size, void* d_ws, size_t ws_size,
                              hipStream_t stream) {
    const float* x = (const float*)d_in[0];
    const float* wts = (const float*)d_in[1];
    const int* idx = (const int*)d_in[2];
    const float* W1 = (const float*)d_in[4];
    const float* W2 = (const float*)d_in[5];
    float* y = (float*)d_out;

    char* ws = (char*)d_ws;
    int* cnt = (int*)(ws + 0);           // 16
    int* cur = (int*)(ws + 64);          // 16
    int* offs = (int*)(ws + 128);        // 17
    int* ntiles = (int*)(ws + 256);      // 1
    int* tiletab = (int*)(ws + 320);     // 144
    int* rows = (int*)(ws + 1024);                           // TK
    float* wslot = (float*)(ws + 1024 + (size_t)TK * 4);
    int* slot_of = (int*)(ws + 1024 + (size_t)TK * 8);
    const size_t OFF_XG = 1024 + (size_t)TK * 12;            // 197632
    unsigned short* xg = (unsigned short*)(ws + OFF_XG);
    const size_t OFF_ACT = OFF_XG + (size_t)TK * D_DIM * 2;
    unsigned short* act = (unsigned short*)(ws + OFF_ACT);
    const size_t OFF_SO = OFF_ACT + (size_t)TK * H_DIM * 2;
    unsigned short* slot_out = (unsigned short*)(ws + OFF_SO);
    const size_t MID_ATOMIC_END = OFF_SO;                    // no slot_out
    const size_t MID_END = OFF_SO + (size_t)TK * D_DIM * 2;
    const size_t OFF_W1T = MID_END;
    unsigned short* W1T = (unsigned short*)(ws + OFF_W1T);
    const size_t OFF_W2T = OFF_W1T + (size_t)E_EXP * 2 * H_DIM * D_DIM * 2;
    unsigned short* W2T = (unsigned short*)(ws + OFF_W2T);
    const size_t FULL_END = OFF_W2T + (size_t)E_EXP * D_DIM * H_DIM * 2;

    const int full = (ws_size >= FULL_END) ? 1 : 0;
    const int atomic_mode = (!full && ws_size < MID_END) ? 1 : 0;

    hipMemsetAsync(ws, 0, 128, stream);
    k_count<<<(TK + 255) / 256, 256, 0, stream>>>(idx, cnt);
    k_scan<<<1, 64, 0, stream>>>(cnt, offs, tiletab, ntiles);
    k_scatter<<<(TK + 255) / 256, 256, 0, stream>>>(idx, wts, offs, cur, rows, wslot, slot_of);
    k_gather<<<TK, 256, 0, stream>>>(x, rows, xg);

    if (full) {
        dim3 gc1(D_DIM / 32, (2 * H_DIM) / 32, E_EXP);
        k_castT<<<gc1, 256, 0, stream>>>(W1, W1T, D_DIM, 2 * H_DIM);
        dim3 gc2(H_DIM / 32, D_DIM / 32, E_EXP);
        k_castT<<<gc2, 256, 0, stream>>>(W2, W2T, H_DIM, D_DIM);
    }

    dim3 g1(NTMAX, H_DIM / 64);
    if (full) k_gemm1<0><<<g1, 256, 0, stream>>>(xg, W1, W1T, offs, tiletab, act);
    else      k_gemm1<1><<<g1, 256, 0, stream>>>(xg, W1, W1T, offs, tiletab, act);

    if (atomic_mode) hipMemsetAsync(y, 0, (size_t)out_size * 4, stream);

    dim3 g2(NTMAX, D_DIM / 64);
    if (full) k_gemm2<0><<<g2, 256, 0, stream>>>(act, W2, W2T, offs, tiletab, wslot, slot_out, y, rows, atomic_mode);
    else      k_gemm2<1><<<g2, 256, 0, stream>>>(act, W2, W2T, offs, tiletab, wslot, slot_out, y, rows, atomic_mode);

    if (!atomic_mode)
        k_combine<<<T_TOK, 256, 0, stream>>>(slot_out, slot_of, y);
}

// Round 3
// 330.714 us; speedup vs baseline: 2.7462x; 1.0541x over previous
//
#include <hip/hip_runtime.h>
#include <hip/hip_bf16.h>

#define T_TOK 8192
#define D_DIM 1024
#define H_DIM 768
#define E_EXP 16
#define K_TOP 2
#define TK (T_TOK * K_TOP)
#define NTMAX 144

typedef __bf16 bf16x8 __attribute__((ext_vector_type(8)));
typedef unsigned short u16x8 __attribute__((ext_vector_type(8)));
typedef float f32x4 __attribute__((ext_vector_type(4)));

typedef const __attribute__((address_space(1))) void* gas_t;
typedef __attribute__((address_space(3))) void* las_t;

__device__ __forceinline__ unsigned short f2b(float f) {
    __hip_bfloat16 h = __float2bfloat16(f);
    return __builtin_bit_cast(unsigned short, h);
}
__device__ __forceinline__ float b2f(unsigned short u) {
    unsigned int x = ((unsigned int)u) << 16;
    return __builtin_bit_cast(float, x);
}

// ---------------- routing ----------------
__global__ void k_count(const int* __restrict__ idx, int* __restrict__ cnt) {
    int i = blockIdx.x * blockDim.x + threadIdx.x;
    if (i < TK) atomicAdd(&cnt[idx[i]], 1);
}

__global__ void k_scan(const int* __restrict__ cnt, int* __restrict__ offs,
                       int* __restrict__ tiletab, int* __restrict__ ntiles) {
    if (threadIdx.x == 0) {
        int s = 0, nt = 0;
        for (int e = 0; e < E_EXP; ++e) {
            offs[e] = s;
            const int n = cnt[e];
            for (int m0 = 0; m0 < n; m0 += 128) tiletab[nt++] = (e << 16) | (m0 >> 7);
            s += n;
        }
        offs[E_EXP] = s;
        ntiles[0] = nt;
        for (int i = nt; i < NTMAX; ++i) tiletab[i] = -1;
    }
}

__global__ void k_scatter(const int* __restrict__ idx, const float* __restrict__ wts,
                          const int* __restrict__ offs, int* __restrict__ cur,
                          int* __restrict__ rows, float* __restrict__ wslot,
                          int* __restrict__ slot_of) {
    int i = blockIdx.x * blockDim.x + threadIdx.x;
    if (i < TK) {
        int e = idx[i];
        int p = atomicAdd(&cur[e], 1);
        int s = offs[e] + p;
        rows[s] = i >> 1;          // K_TOP == 2
        wslot[s] = wts[i];
        slot_of[i] = s;
    }
}

// ---------------- gather + cast: xg[slot][D] bf16 ----------------
__global__ __launch_bounds__(256) void k_gather(const float* __restrict__ x,
                                                const int* __restrict__ rows,
                                                unsigned short* __restrict__ xg) {
    const int s = blockIdx.x, t = threadIdx.x;
    const int tok = rows[s];
    const float4 v = *reinterpret_cast<const float4*>(&x[(size_t)tok * D_DIM + t * 4]);
    ushort4 u;
    u.x = f2b(v.x); u.y = f2b(v.y); u.z = f2b(v.z); u.w = f2b(v.w);
    *reinterpret_cast<ushort4*>(&xg[(size_t)s * D_DIM + t * 4]) = u;
}

// ---------------- cast + transpose: src [e][K][C] f32 -> dst [e][C][K] bf16 ----------------
__global__ __launch_bounds__(256) void k_castT64(const float* __restrict__ src,
                                                 unsigned short* __restrict__ dst,
                                                 int K, int C) {
    const int e = blockIdx.z;
    const int kb = blockIdx.x * 64, cb = blockIdx.y * 64;
    __shared__ float t4[64][65];
    const int tid = threadIdx.x;
    const float* s = src + ((size_t)e * K + kb) * C + cb;
#pragma unroll
    for (int i = 0; i < 4; ++i) {
        const int kk = (tid >> 4) + i * 16, c4 = (tid & 15) * 4;
        const float4 v = *reinterpret_cast<const float4*>(&s[(size_t)kk * C + c4]);
        t4[kk][c4] = v.x; t4[kk][c4 + 1] = v.y; t4[kk][c4 + 2] = v.z; t4[kk][c4 + 3] = v.w;
    }
    __syncthreads();
#pragma unroll
    for (int i = 0; i < 4; ++i) {
        const int cc = (tid >> 4) + i * 16, k4 = (tid & 15) * 4;
        ushort4 u;
        u.x = f2b(t4[k4][cc]); u.y = f2b(t4[k4 + 1][cc]);
        u.z = f2b(t4[k4 + 2][cc]); u.w = f2b(t4[k4 + 3][cc]);
        *reinterpret_cast<ushort4*>(&dst[((size_t)e * C + cb + cc) * K + kb + k4]) = u;
    }
}

// ================= FAST PATH (full ws): dbuf prefetch + XOR-swizzled LDS =================
// Swizzle (involution): within a 128B tile row, 16B chunk index XOR (row&7).
// Applied on the global SOURCE of global_load_lds (linear LDS dest, rule #21)
// and identically on the ds_read byte offset. row&7 == l15&7 for all fragments.

__global__ __launch_bounds__(256) void k_gemm1_fast(
    const unsigned short* __restrict__ xg, const unsigned short* __restrict__ W1T,
    const int* __restrict__ offs, const int* __restrict__ tiletab,
    unsigned short* __restrict__ act) {
    const int tt = tiletab[blockIdx.x];
    if (tt < 0) return;
    const int e = tt >> 16, m0 = (tt & 0xffff) << 7;
    const int off = offs[e], n_e = offs[e + 1] - off;
    const int h0 = blockIdx.y * 64;

    __shared__ unsigned short Ab[2][128 * 64];
    __shared__ unsigned short Bb[2][128 * 64];

    const int tid = threadIdx.x;
    const int wid = tid >> 6, lane = tid & 63;
    const int l15 = lane & 15, kq = lane >> 4;
    const int swz = (l15 & 7) << 4;   // ds_read byte swizzle

    f32x4 acc[2][8];
#pragma unroll
    for (int m = 0; m < 2; ++m)
#pragma unroll
        for (int n = 0; n < 8; ++n)
#pragma unroll
            for (int r = 0; r < 4; ++r) acc[m][n][r] = 0.f;

    auto stage = [&](int buf, int k0) {
#pragma unroll
        for (int j = 0; j < 4; ++j) {
            const int o = wid * 4096 + j * 1024 + lane * 16;
            const int row = o >> 7;
            const int scb = (o & 127) ^ ((row & 7) << 4);
            int gr = off + m0 + row; gr = (gr < TK) ? gr : (TK - 1);
            const unsigned short* gpA = xg + (size_t)gr * D_DIM + k0 + (scb >> 1);
            __builtin_amdgcn_global_load_lds((gas_t)gpA,
                (las_t)((char*)&Ab[buf][0] + wid * 4096 + j * 1024), 16, 0, 0);
            const int wc = (row < 64) ? (h0 + row) : (H_DIM + h0 + row - 64);
            const unsigned short* gpB = W1T + ((size_t)e * (2 * H_DIM) + wc) * D_DIM + k0 + (scb >> 1);
            __builtin_amdgcn_global_load_lds((gas_t)gpB,
                (las_t)((char*)&Bb[buf][0] + wid * 4096 + j * 1024), 16, 0, 0);
        }
    };

    stage(0, 0);
    __syncthreads();
    int c = 0;
    for (int t = 0; t < 16; ++t) {
        if (t < 15) stage(c ^ 1, (t + 1) * 64);
#pragma unroll
        for (int ks = 0; ks < 2; ++ks) {
            const int po = ((ks * 64 + kq * 16) ^ swz) >> 1;  // ushort offset
            bf16x8 a[2], b[8];
#pragma unroll
            for (int m = 0; m < 2; ++m)
                a[m] = __builtin_bit_cast(bf16x8, *reinterpret_cast<const u16x8*>(
                    &Ab[c][(wid * 32 + m * 16 + l15) * 64 + po]));
#pragma unroll
            for (int n = 0; n < 8; ++n)
                b[n] = __builtin_bit_cast(bf16x8, *reinterpret_cast<const u16x8*>(
                    &Bb[c][(n * 16 + l15) * 64 + po]));
#pragma unroll
            for (int m = 0; m < 2; ++m)
#pragma unroll
                for (int n = 0; n < 8; ++n)
                    acc[m][n] = __builtin_amdgcn_mfma_f32_16x16x32_bf16(a[m], b[n], acc[m][n], 0, 0, 0);
        }
        __syncthreads();
        c ^= 1;
    }
    // ---- epilogue: silu-gate, bf16 store ----
#pragma unroll
    for (int m = 0; m < 2; ++m)
#pragma unroll
        for (int n = 0; n < 4; ++n)
#pragma unroll
            for (int r = 0; r < 4; ++r) {
                const int row = wid * 32 + m * 16 + kq * 4 + r;
                if (m0 + row < n_e) {
                    const int col = n * 16 + l15;
                    const float vv = acc[m][n][r], gg = acc[m][n + 4][r];
                    const float s = gg / (1.0f + __expf(-gg));
                    act[(size_t)(off + m0 + row) * H_DIM + h0 + col] = f2b(vv * s);
                }
            }
}

__global__ __launch_bounds__(256) void k_gemm2_fast(
    const unsigned short* __restrict__ act, const unsigned short* __restrict__ W2T,
    const int* __restrict__ offs, const int* __restrict__ tiletab,
    const float* __restrict__ wslot, unsigned short* __restrict__ slot_out) {
    const int tt = tiletab[blockIdx.x];
    if (tt < 0) return;
    const int e = tt >> 16, m0 = (tt & 0xffff) << 7;
    const int off = offs[e], n_e = offs[e + 1] - off;
    const int n0 = blockIdx.y * 64;

    __shared__ unsigned short Ab[2][128 * 64];
    __shared__ unsigned short Bb[2][64 * 64];

    const int tid = threadIdx.x;
    const int wid = tid >> 6, lane = tid & 63;
    const int l15 = lane & 15, kq = lane >> 4;
    const int swz = (l15 & 7) << 4;

    f32x4 acc[2][4];
#pragma unroll
    for (int m = 0; m < 2; ++m)
#pragma unroll
        for (int n = 0; n < 4; ++n)
#pragma unroll
            for (int r = 0; r < 4; ++r) acc[m][n][r] = 0.f;

    auto stage = [&](int buf, int k0) {
#pragma unroll
        for (int j = 0; j < 4; ++j) {
            const int o = wid * 4096 + j * 1024 + lane * 16;
            const int row = o >> 7;
            const int scb = (o & 127) ^ ((row & 7) << 4);
            int gr = off + m0 + row; gr = (gr < TK) ? gr : (TK - 1);
            const unsigned short* gpA = act + (size_t)gr * H_DIM + k0 + (scb >> 1);
            __builtin_amdgcn_global_load_lds((gas_t)gpA,
                (las_t)((char*)&Ab[buf][0] + wid * 4096 + j * 1024), 16, 0, 0);
        }
#pragma unroll
        for (int j = 0; j < 2; ++j) {
            const int o = wid * 2048 + j * 1024 + lane * 16;
            const int row = o >> 7;
            const int scb = (o & 127) ^ ((row & 7) << 4);
            const unsigned short* gpB = W2T + ((size_t)e * D_DIM + n0 + row) * H_DIM + k0 + (scb >> 1);
            __builtin_amdgcn_global_load_lds((gas_t)gpB,
                (las_t)((char*)&Bb[buf][0] + wid * 2048 + j * 1024), 16, 0, 0);
        }
    };

    stage(0, 0);
    __syncthreads();
    int c = 0;
    for (int t = 0; t < 12; ++t) {
        if (t < 11) stage(c ^ 1, (t + 1) * 64);
#pragma unroll
        for (int ks = 0; ks < 2; ++ks) {
            const int po = ((ks * 64 + kq * 16) ^ swz) >> 1;
            bf16x8 a[2], b[4];
#pragma unroll
            for (int m = 0; m < 2; ++m)
                a[m] = __builtin_bit_cast(bf16x8, *reinterpret_cast<const u16x8*>(
                    &Ab[c][(wid * 32 + m * 16 + l15) * 64 + po]));
#pragma unroll
            for (int n = 0; n < 4; ++n)
                b[n] = __builtin_bit_cast(bf16x8, *reinterpret_cast<const u16x8*>(
                    &Bb[c][(n * 16 + l15) * 64 + po]));
#pragma unroll
            for (int m = 0; m < 2; ++m)
#pragma unroll
                for (int n = 0; n < 4; ++n)
                    acc[m][n] = __builtin_amdgcn_mfma_f32_16x16x32_bf16(a[m], b[n], acc[m][n], 0, 0, 0);
        }
        __syncthreads();
        c ^= 1;
    }
#pragma unroll
    for (int m = 0; m < 2; ++m)
#pragma unroll
        for (int r = 0; r < 4; ++r) {
            const int row = wid * 32 + m * 16 + kq * 4 + r;
            if (m0 + row < n_e) {
                const int slot = off + m0 + row;
                const float w = wslot[slot];
#pragma unroll
                for (int n = 0; n < 4; ++n)
                    slot_out[(size_t)slot * D_DIM + n0 + n * 16 + l15] = f2b(w * acc[m][n][r]);
            }
        }
}

// ================= FALLBACK PATH (small ws): round-2 MODE1 kernels =================
__global__ __launch_bounds__(256) void k_gemm1_fb(
    const unsigned short* __restrict__ xg, const float* __restrict__ W1,
    const int* __restrict__ offs, const int* __restrict__ tiletab,
    unsigned short* __restrict__ act) {
    const int tt = tiletab[blockIdx.x];
    if (tt < 0) return;
    const int e = tt >> 16, m0 = (tt & 0xffff) << 7;
    const int off = offs[e], n_e = offs[e + 1] - off;
    const int h0 = blockIdx.y * 64;

    __shared__ unsigned short Ab[128 * 64];
    __shared__ unsigned short Bb[128 * 66];

    const int tid = threadIdx.x;
    const int wid = tid >> 6, lane = tid & 63;
    const int l15 = lane & 15, kq = lane >> 4;

    f32x4 acc[2][8];
#pragma unroll
    for (int m = 0; m < 2; ++m)
#pragma unroll
        for (int n = 0; n < 8; ++n)
#pragma unroll
            for (int r = 0; r < 4; ++r) acc[m][n][r] = 0.f;

    for (int k0 = 0; k0 < D_DIM; k0 += 64) {
        __syncthreads();
#pragma unroll
        for (int j = 0; j < 4; ++j) {
            const int o = wid * 4096 + j * 1024 + lane * 16;
            const int row = o >> 7, kb = o & 127;
            int gr = off + m0 + row; gr = (gr < TK) ? gr : (TK - 1);
            const unsigned short* gp = xg + (size_t)gr * D_DIM + k0 + (kb >> 1);
            __builtin_amdgcn_global_load_lds((gas_t)gp,
                (las_t)((char*)Ab + wid * 4096 + j * 1024), 16, 0, 0);
        }
        {
            const float* W1e = W1 + (size_t)e * D_DIM * (2 * H_DIM);
#pragma unroll
            for (int i = 0; i < 8; ++i) {
                const int flat = tid + 256 * i;
                const int cg = flat & 31, kk = flat >> 5;
                const int cc = cg * 4;
                const int gc = (cc < 64) ? (h0 + cc) : (H_DIM + h0 + cc - 64);
                const float4 v = *reinterpret_cast<const float4*>(
                    &W1e[(size_t)(k0 + kk) * (2 * H_DIM) + gc]);
                Bb[(cc + 0) * 66 + kk] = f2b(v.x);
                Bb[(cc + 1) * 66 + kk] = f2b(v.y);
                Bb[(cc + 2) * 66 + kk] = f2b(v.z);
                Bb[(cc + 3) * 66 + kk] = f2b(v.w);
            }
        }
        __syncthreads();
#pragma unroll
        for (int ks = 0; ks < 2; ++ks) {
            bf16x8 a[2], b[8];
#pragma unroll
            for (int m = 0; m < 2; ++m)
                a[m] = __builtin_bit_cast(bf16x8, *reinterpret_cast<const u16x8*>(
                    &Ab[(wid * 32 + m * 16 + l15) * 64 + ks * 32 + kq * 8]));
#pragma unroll
            for (int n = 0; n < 8; ++n)
                b[n] = __builtin_bit_cast(bf16x8, *reinterpret_cast<const u16x8*>(
                    &Bb[(n * 16 + l15) * 66 + ks * 32 + kq * 8]));
#pragma unroll
            for (int m = 0; m < 2; ++m)
#pragma unroll
                for (int n = 0; n < 8; ++n)
                    acc[m][n] = __builtin_amdgcn_mfma_f32_16x16x32_bf16(a[m], b[n], acc[m][n], 0, 0, 0);
        }
    }
#pragma unroll
    for (int m = 0; m < 2; ++m)
#pragma unroll
        for (int n = 0; n < 4; ++n)
#pragma unroll
            for (int r = 0; r < 4; ++r) {
                const int row = wid * 32 + m * 16 + kq * 4 + r;
                if (m0 + row < n_e) {
                    const float vv = acc[m][n][r], gg = acc[m][n + 4][r];
                    const float s = gg / (1.0f + __expf(-gg));
                    act[(size_t)(off + m0 + row) * H_DIM + h0 + n * 16 + l15] = f2b(vv * s);
                }
            }
}

__global__ __launch_bounds__(256) void k_gemm2_fb(
    const unsigned short* __restrict__ act, const float* __restrict__ W2,
    const int* __restrict__ offs, const int* __restrict__ tiletab,
    const float* __restrict__ wslot, unsigned short* __restrict__ slot_out,
    float* __restrict__ y, const int* __restrict__ rows, int atomic_mode) {
    const int tt = tiletab[blockIdx.x];
    if (tt < 0) return;
    const int e = tt >> 16, m0 = (tt & 0xffff) << 7;
    const int off = offs[e], n_e = offs[e + 1] - off;
    const int n0 = blockIdx.y * 64;

    __shared__ unsigned short Ab[128 * 64];
    __shared__ unsigned short Bb[64 * 66];

    const int tid = threadIdx.x;
    const int wid = tid >> 6, lane = tid & 63;
    const int l15 = lane & 15, kq = lane >> 4;

    f32x4 acc[2][4];
#pragma unroll
    for (int m = 0; m < 2; ++m)
#pragma unroll
        for (int n = 0; n < 4; ++n)
#pragma unroll
            for (int r = 0; r < 4; ++r) acc[m][n][r] = 0.f;

    for (int k0 = 0; k0 < H_DIM; k0 += 64) {
        __syncthreads();
#pragma unroll
        for (int j = 0; j < 4; ++j) {
            const int o = wid * 4096 + j * 1024 + lane * 16;
            const int row = o >> 7, kb = o & 127;
            int gr = off + m0 + row; gr = (gr < TK) ? gr : (TK - 1);
            const unsigned short* gp = act + (size_t)gr * H_DIM + k0 + (kb >> 1);
            __builtin_amdgcn_global_load_lds((gas_t)gp,
                (las_t)((char*)Ab + wid * 4096 + j * 1024), 16, 0, 0);
        }
        {
            const float* W2e = W2 + (size_t)e * H_DIM * D_DIM;
#pragma unroll
            for (int i = 0; i < 4; ++i) {
                const int flat = tid + 256 * i;
                const int cg = flat & 15, kk = flat >> 4;
                const int cc = cg * 4;
                const float4 v = *reinterpret_cast<const float4*>(
                    &W2e[(size_t)(k0 + kk) * D_DIM + n0 + cc]);
                Bb[(cc + 0) * 66 + kk] = f2b(v.x);
                Bb[(cc + 1) * 66 + kk] = f2b(v.y);
                Bb[(cc + 2) * 66 + kk] = f2b(v.z);
                Bb[(cc + 3) * 66 + kk] = f2b(v.w);
            }
        }
        __syncthreads();
#pragma unroll
        for (int ks = 0; ks < 2; ++ks) {
            bf16x8 a[2], b[4];
#pragma unroll
            for (int m = 0; m < 2; ++m)
                a[m] = __builtin_bit_cast(bf16x8, *reinterpret_cast<const u16x8*>(
                    &Ab[(wid * 32 + m * 16 + l15) * 64 + ks * 32 + kq * 8]));
#pragma unroll
            for (int n = 0; n < 4; ++n)
                b[n] = __builtin_bit_cast(bf16x8, *reinterpret_cast<const u16x8*>(
                    &Bb[(n * 16 + l15) * 66 + ks * 32 + kq * 8]));
#pragma unroll
            for (int m = 0; m < 2; ++m)
#pragma unroll
                for (int n = 0; n < 4; ++n)
                    acc[m][n] = __builtin_amdgcn_mfma_f32_16x16x32_bf16(a[m], b[n], acc[m][n], 0, 0, 0);
        }
    }
#pragma unroll
    for (int m = 0; m < 2; ++m)
#pragma unroll
        for (int r = 0; r < 4; ++r) {
            const int row = wid * 32 + m * 16 + kq * 4 + r;
            if (m0 + row < n_e) {
                const int slot = off + m0 + row;
                const float w = wslot[slot];
#pragma unroll
                for (int n = 0; n < 4; ++n) {
                    const float o = w * acc[m][n][r];
                    if (atomic_mode)
                        atomicAdd(&y[(size_t)rows[slot] * D_DIM + n0 + n * 16 + l15], o);
                    else
                        slot_out[(size_t)slot * D_DIM + n0 + n * 16 + l15] = f2b(o);
                }
            }
        }
}

// ---------------- combine ----------------
__global__ __launch_bounds__(256) void k_combine(
    const unsigned short* __restrict__ slot_out, const int* __restrict__ slot_of,
    float* __restrict__ y) {
    const int t = blockIdx.x;
    const int d = threadIdx.x * 4;
    const int s0 = slot_of[2 * t], s1 = slot_of[2 * t + 1];
    const ushort4 a = *reinterpret_cast<const ushort4*>(&slot_out[(size_t)s0 * D_DIM + d]);
    const ushort4 b = *reinterpret_cast<const ushort4*>(&slot_out[(size_t)s1 * D_DIM + d]);
    float4 r;
    r.x = b2f(a.x) + b2f(b.x);
    r.y = b2f(a.y) + b2f(b.y);
    r.z = b2f(a.z) + b2f(b.z);
    r.w = b2f(a.w) + b2f(b.w);
    *reinterpret_cast<float4*>(&y[(size_t)t * D_DIM + d]) = r;
}

extern "C" void kernel_launch(void* const* d_in, const int* in_sizes, int n_in,
                              void* d_out, int out_size, void* d_ws, size_t ws_size,
                              hipStream_t stream) {
    const float* x = (const float*)d_in[0];
    const float* wts = (const float*)d_in[1];
    const int* idx = (const int*)d_in[2];
    const float* W1 = (const float*)d_in[4];
    const float* W2 = (const float*)d_in[5];
    float* y = (float*)d_out;

    char* ws = (char*)d_ws;
    int* cnt = (int*)(ws + 0);
    int* cur = (int*)(ws + 64);
    int* offs = (int*)(ws + 128);
    int* ntiles = (int*)(ws + 256);
    int* tiletab = (int*)(ws + 320);
    int* rows = (int*)(ws + 1024);
    float* wslot = (float*)(ws + 1024 + (size_t)TK * 4);
    int* slot_of = (int*)(ws + 1024 + (size_t)TK * 8);
    const size_t OFF_XG = 1024 + (size_t)TK * 12;
    unsigned short* xg = (unsigned short*)(ws + OFF_XG);
    const size_t OFF_ACT = OFF_XG + (size_t)TK * D_DIM * 2;
    unsigned short* act = (unsigned short*)(ws + OFF_ACT);
    const size_t OFF_SO = OFF_ACT + (size_t)TK * H_DIM * 2;
    unsigned short* slot_out = (unsigned short*)(ws + OFF_SO);
    const size_t MID_END = OFF_SO + (size_t)TK * D_DIM * 2;
    const size_t OFF_W1T = MID_END;
    unsigned short* W1T = (unsigned short*)(ws + OFF_W1T);
    const size_t OFF_W2T = OFF_W1T + (size_t)E_EXP * 2 * H_DIM * D_DIM * 2;
    unsigned short* W2T = (unsigned short*)(ws + OFF_W2T);
    const size_t FULL_END = OFF_W2T + (size_t)E_EXP * D_DIM * H_DIM * 2;

    const int full = (ws_size >= FULL_END) ? 1 : 0;
    const int atomic_mode = (!full && ws_size < MID_END) ? 1 : 0;

    hipMemsetAsync(ws, 0, 128, stream);
    k_count<<<(TK + 255) / 256, 256, 0, stream>>>(idx, cnt);
    k_scan<<<1, 64, 0, stream>>>(cnt, offs, tiletab, ntiles);
    k_scatter<<<(TK + 255) / 256, 256, 0, stream>>>(idx, wts, offs, cur, rows, wslot, slot_of);
    k_gather<<<TK, 256, 0, stream>>>(x, rows, xg);

    if (full) {
        dim3 gc1(D_DIM / 64, (2 * H_DIM) / 64, E_EXP);
        k_castT64<<<gc1, 256, 0, stream>>>(W1, W1T, D_DIM, 2 * H_DIM);
        dim3 gc2(H_DIM / 64, D_DIM / 64, E_EXP);
        k_castT64<<<gc2, 256, 0, stream>>>(W2, W2T, H_DIM, D_DIM);
    }

    dim3 g1(NTMAX, H_DIM / 64);
    if (full) k_gemm1_fast<<<g1, 256, 0, stream>>>(xg, W1T, offs, tiletab, act);
    else      k_gemm1_fb<<<g1, 256, 0, stream>>>(xg, W1, offs, tiletab, act);

    if (atomic_mode) hipMemsetAsync(y, 0, (size_t)out_size * 4, stream);

    dim3 g2(NTMAX, D_DIM / 64);
    if (full) k_gemm2_fast<<<g2, 256, 0, stream>>>(act, W2T, offs, tiletab, wslot, slot_out);
    else      k_gemm2_fb<<<g2, 256, 0, stream>>>(act, W2, offs, tiletab, wslot, slot_out, y, rows, atomic_mode);

    if (!atomic_mode)
        k_combine<<<T_TOK, 256, 0, stream>>>(slot_out, slot_of, y);
}

// Round 4
// 320.162 us; speedup vs baseline: 2.8367x; 1.0330x over previous
//
#include <hip/hip_runtime.h>
#include <hip/hip_bf16.h>

#define T_TOK 8192
#define D_DIM 1024
#define H_DIM 768
#define E_EXP 16
#define K_TOP 2
#define TK (T_TOK * K_TOP)
#define NT128 144
#define NT256 80

typedef __bf16 bf16x8 __attribute__((ext_vector_type(8)));
typedef unsigned short u16x8 __attribute__((ext_vector_type(8)));
typedef float f32x4 __attribute__((ext_vector_type(4)));

typedef const __attribute__((address_space(1))) void* gas_t;
typedef __attribute__((address_space(3))) void* las_t;

__device__ __forceinline__ unsigned short f2b(float f) {
    __hip_bfloat16 h = __float2bfloat16(f);
    return __builtin_bit_cast(unsigned short, h);
}
__device__ __forceinline__ float b2f(unsigned short u) {
    unsigned int x = ((unsigned int)u) << 16;
    return __builtin_bit_cast(float, x);
}

// ---------------- routing ----------------
__global__ void k_count(const int* __restrict__ idx, int* __restrict__ cnt) {
    int i = blockIdx.x * blockDim.x + threadIdx.x;
    if (i < TK) atomicAdd(&cnt[idx[i]], 1);
}

__global__ void k_scan(const int* __restrict__ cnt, int* __restrict__ offs,
                       int* __restrict__ tiletab, int* __restrict__ tiletab256,
                       int* __restrict__ ntiles) {
    if (threadIdx.x == 0) {
        int s = 0, nt = 0, nt2 = 0;
        for (int e = 0; e < E_EXP; ++e) {
            offs[e] = s;
            const int n = cnt[e];
            for (int m0 = 0; m0 < n; m0 += 128) tiletab[nt++] = (e << 16) | (m0 >> 7);
            for (int m0 = 0; m0 < n; m0 += 256) tiletab256[nt2++] = (e << 16) | (m0 >> 8);
            s += n;
        }
        offs[E_EXP] = s;
        ntiles[0] = nt;
        for (int i = nt; i < NT128; ++i) tiletab[i] = -1;
        for (int i = nt2; i < NT256; ++i) tiletab256[i] = -1;
    }
}

__global__ void k_scatter(const int* __restrict__ idx, const float* __restrict__ wts,
                          const int* __restrict__ offs, int* __restrict__ cur,
                          int* __restrict__ rows, float* __restrict__ wslot,
                          int* __restrict__ slot_of) {
    int i = blockIdx.x * blockDim.x + threadIdx.x;
    if (i < TK) {
        int e = idx[i];
        int p = atomicAdd(&cur[e], 1);
        int s = offs[e] + p;
        rows[s] = i >> 1;          // K_TOP == 2
        wslot[s] = wts[i];
        slot_of[i] = s;
    }
}

// ---------------- cast x -> bf16 [T][D] (full path) ----------------
__global__ __launch_bounds__(256) void k_castx(const float* __restrict__ x,
                                               unsigned short* __restrict__ xb) {
    const int t = blockIdx.x, d = threadIdx.x * 4;
    const float4 v = *reinterpret_cast<const float4*>(&x[(size_t)t * D_DIM + d]);
    ushort4 u;
    u.x = f2b(v.x); u.y = f2b(v.y); u.z = f2b(v.z); u.w = f2b(v.w);
    *reinterpret_cast<ushort4*>(&xb[(size_t)t * D_DIM + d]) = u;
}

// ---------------- gather + cast: xg[slot][D] bf16 (fallback path) ----------------
__global__ __launch_bounds__(256) void k_gather(const float* __restrict__ x,
                                                const int* __restrict__ rows,
                                                unsigned short* __restrict__ xg) {
    const int s = blockIdx.x, t = threadIdx.x;
    const int tok = rows[s];
    const float4 v = *reinterpret_cast<const float4*>(&x[(size_t)tok * D_DIM + t * 4]);
    ushort4 u;
    u.x = f2b(v.x); u.y = f2b(v.y); u.z = f2b(v.z); u.w = f2b(v.w);
    *reinterpret_cast<ushort4*>(&xg[(size_t)s * D_DIM + t * 4]) = u;
}

// ---- cast + transpose: src [e][K][C] f32 -> dst [e][perm(C)][K] bf16 ----
// PACK=1 (W1): col j<H (v) -> row (j>>5)*64+(j&31); j>=H (g) -> ((j-H)>>5)*64+32+((j-H)&31)
template <int PACK>
__global__ __launch_bounds__(256) void k_castT64(const float* __restrict__ src,
                                                 unsigned short* __restrict__ dst,
                                                 int K, int C) {
    const int e = blockIdx.z;
    const int kb = blockIdx.x * 64, cb = blockIdx.y * 64;
    __shared__ float t4[64][65];
    const int tid = threadIdx.x;
    const float* s = src + ((size_t)e * K + kb) * C + cb;
#pragma unroll
    for (int i = 0; i < 4; ++i) {
        const int kk = (tid >> 4) + i * 16, c4 = (tid & 15) * 4;
        const float4 v = *reinterpret_cast<const float4*>(&s[(size_t)kk * C + c4]);
        t4[kk][c4] = v.x; t4[kk][c4 + 1] = v.y; t4[kk][c4 + 2] = v.z; t4[kk][c4 + 3] = v.w;
    }
    __syncthreads();
#pragma unroll
    for (int i = 0; i < 4; ++i) {
        const int cc = (tid >> 4) + i * 16, k4 = (tid & 15) * 4;
        const int j = cb + cc;
        int drow;
        if (PACK) drow = (j < H_DIM) ? ((j >> 5) * 64 + (j & 31))
                                     : (((j - H_DIM) >> 5) * 64 + 32 + ((j - H_DIM) & 31));
        else drow = j;
        ushort4 u;
        u.x = f2b(t4[k4][cc]); u.y = f2b(t4[k4 + 1][cc]);
        u.z = f2b(t4[k4 + 2][cc]); u.w = f2b(t4[k4 + 3][cc]);
        *reinterpret_cast<ushort4*>(&dst[((size_t)e * C + drow) * K + kb + k4]) = u;
    }
}

// ================= FAST PATH: 256-row tiles, 8 waves, dbuf, XOR-swizzle =================
// gemm1: BM=256 rows x 128 act-cols (B-tile = 256 packed W1 rows: v|g interleaved 32-blocks)
__global__ __launch_bounds__(512, 2) void k_gemm1_fast(
    const unsigned short* __restrict__ xb, const unsigned short* __restrict__ W1T,
    const int* __restrict__ offs, const int* __restrict__ tiletab256,
    const int* __restrict__ rows, unsigned short* __restrict__ act) {
    const int ti = (blockIdx.x & 7) * (NT256 / 8) + (blockIdx.x >> 3);  // XCD swizzle
    const int tt = tiletab256[ti];
    if (tt < 0) return;
    const int e = tt >> 16, m0 = (tt & 0xffff) << 8;
    const int off = offs[e], n_e = offs[e + 1] - off;
    const int by = blockIdx.y;   // 0..5 (128 act cols each)

    __shared__ unsigned short Ab[2][256 * 64];
    __shared__ unsigned short Bb[2][256 * 64];

    const int tid = threadIdx.x;
    const int wid = tid >> 6, lane = tid & 63;
    const int l15 = lane & 15, kq = lane >> 4;
    const int wm = wid >> 2, wn = wid & 3;
    const int srow = tid >> 3;                               // staging row (+j*64)
    const int eoff = ((((tid & 7) << 4) ^ ((srow & 7) << 4)) >> 1);  // swizzled elem offset
    const int rswz = (l15 & 7) << 4;                         // read-side byte swizzle

    int tok[4];
#pragma unroll
    for (int j = 0; j < 4; ++j) {
        int s = m0 + j * 64 + srow;
        s = (s < n_e) ? s : (n_e - 1);
        tok[j] = rows[off + s];
    }

    f32x4 acc[8][4];
#pragma unroll
    for (int m = 0; m < 8; ++m)
#pragma unroll
        for (int n = 0; n < 4; ++n)
#pragma unroll
            for (int r = 0; r < 4; ++r) acc[m][n][r] = 0.f;

    auto stage = [&](int buf, int k0) {
#pragma unroll
        for (int j = 0; j < 4; ++j) {
            const unsigned short* ga = xb + (size_t)tok[j] * D_DIM + k0 + eoff;
            __builtin_amdgcn_global_load_lds((gas_t)ga,
                (las_t)((char*)&Ab[buf][0] + j * 8192 + wid * 1024), 16, 0, 0);
            const unsigned short* gb = W1T +
                ((size_t)e * (2 * H_DIM) + by * 256 + j * 64 + srow) * D_DIM + k0 + eoff;
            __builtin_amdgcn_global_load_lds((gas_t)gb,
                (las_t)((char*)&Bb[buf][0] + j * 8192 + wid * 1024), 16, 0, 0);
        }
    };

    stage(0, 0);
    __syncthreads();
    int c = 0;
    for (int t = 0; t < 16; ++t) {
        if (t < 15) stage(c ^ 1, (t + 1) * 64);
#pragma unroll
        for (int ks = 0; ks < 2; ++ks) {
            const int ko = (ks * 64 + kq * 16) ^ rswz;
            bf16x8 a[8], b[4];
#pragma unroll
            for (int m = 0; m < 8; ++m) {
                const int row = wm * 128 + m * 16 + l15;
                a[m] = __builtin_bit_cast(bf16x8, *reinterpret_cast<const u16x8*>(
                    &Ab[c][(row * 128 + ko) >> 1]));
            }
#pragma unroll
            for (int n = 0; n < 4; ++n) {
                const int row = wn * 64 + n * 16 + l15;
                b[n] = __builtin_bit_cast(bf16x8, *reinterpret_cast<const u16x8*>(
                    &Bb[c][(row * 128 + ko) >> 1]));
            }
#pragma unroll
            for (int m = 0; m < 8; ++m)
#pragma unroll
                for (int n = 0; n < 4; ++n)
                    acc[m][n] = __builtin_amdgcn_mfma_f32_16x16x32_bf16(a[m], b[n], acc[m][n], 0, 0, 0);
        }
        __syncthreads();
        c ^= 1;
    }
    // epilogue: silu-gate; frag n<2 = v-cols, n>=2 = paired g-cols
#pragma unroll
    for (int m = 0; m < 8; ++m)
#pragma unroll
        for (int r = 0; r < 4; ++r) {
            const int row = wm * 128 + m * 16 + kq * 4 + r;
            if (m0 + row < n_e) {
#pragma unroll
                for (int nv = 0; nv < 2; ++nv) {
                    const int col = by * 128 + wn * 32 + nv * 16 + l15;
                    const float vv = acc[m][nv][r], gg = acc[m][2 + nv][r];
                    const float s = gg / (1.0f + __expf(-gg));
                    act[(size_t)(off + m0 + row) * H_DIM + col] = f2b(vv * s);
                }
            }
        }
}

// gemm2: BM=256 x BN=256, K=768
__global__ __launch_bounds__(512, 2) void k_gemm2_fast(
    const unsigned short* __restrict__ act, const unsigned short* __restrict__ W2T,
    const int* __restrict__ offs, const int* __restrict__ tiletab256,
    const float* __restrict__ wslot, unsigned short* __restrict__ slot_out) {
    const int ti = (blockIdx.x & 7) * (NT256 / 8) + (blockIdx.x >> 3);
    const int tt = tiletab256[ti];
    if (tt < 0) return;
    const int e = tt >> 16, m0 = (tt & 0xffff) << 8;
    const int off = offs[e], n_e = offs[e + 1] - off;
    const int by = blockIdx.y;   // 0..3

    __shared__ unsigned short Ab[2][256 * 64];
    __shared__ unsigned short Bb[2][256 * 64];

    const int tid = threadIdx.x;
    const int wid = tid >> 6, lane = tid & 63;
    const int l15 = lane & 15, kq = lane >> 4;
    const int wm = wid >> 2, wn = wid & 3;
    const int srow = tid >> 3;
    const int eoff = ((((tid & 7) << 4) ^ ((srow & 7) << 4)) >> 1);
    const int rswz = (l15 & 7) << 4;

    int slotA[4];
#pragma unroll
    for (int j = 0; j < 4; ++j) {
        int s = m0 + j * 64 + srow;
        s = (s < n_e) ? s : (n_e - 1);
        slotA[j] = off + s;
    }

    f32x4 acc[8][4];
#pragma unroll
    for (int m = 0; m < 8; ++m)
#pragma unroll
        for (int n = 0; n < 4; ++n)
#pragma unroll
            for (int r = 0; r < 4; ++r) acc[m][n][r] = 0.f;

    auto stage = [&](int buf, int k0) {
#pragma unroll
        for (int j = 0; j < 4; ++j) {
            const unsigned short* ga = act + (size_t)slotA[j] * H_DIM + k0 + eoff;
            __builtin_amdgcn_global_load_lds((gas_t)ga,
                (las_t)((char*)&Ab[buf][0] + j * 8192 + wid * 1024), 16, 0, 0);
            const unsigned short* gb = W2T +
                ((size_t)e * D_DIM + by * 256 + j * 64 + srow) * H_DIM + k0 + eoff;
            __builtin_amdgcn_global_load_lds((gas_t)gb,
                (las_t)((char*)&Bb[buf][0] + j * 8192 + wid * 1024), 16, 0, 0);
        }
    };

    stage(0, 0);
    __syncthreads();
    int c = 0;
    for (int t = 0; t < 12; ++t) {
        if (t < 11) stage(c ^ 1, (t + 1) * 64);
#pragma unroll
        for (int ks = 0; ks < 2; ++ks) {
            const int ko = (ks * 64 + kq * 16) ^ rswz;
            bf16x8 a[8], b[4];
#pragma unroll
            for (int m = 0; m < 8; ++m) {
                const int row = wm * 128 + m * 16 + l15;
                a[m] = __builtin_bit_cast(bf16x8, *reinterpret_cast<const u16x8*>(
                    &Ab[c][(row * 128 + ko) >> 1]));
            }
#pragma unroll
            for (int n = 0; n < 4; ++n) {
                const int row = wn * 64 + n * 16 + l15;
                b[n] = __builtin_bit_cast(bf16x8, *reinterpret_cast<const u16x8*>(
                    &Bb[c][(row * 128 + ko) >> 1]));
            }
#pragma unroll
            for (int m = 0; m < 8; ++m)
#pragma unroll
                for (int n = 0; n < 4; ++n)
                    acc[m][n] = __builtin_amdgcn_mfma_f32_16x16x32_bf16(a[m], b[n], acc[m][n], 0, 0, 0);
        }
        __syncthreads();
        c ^= 1;
    }
#pragma unroll
    for (int m = 0; m < 8; ++m)
#pragma unroll
        for (int r = 0; r < 4; ++r) {
            const int row = wm * 128 + m * 16 + kq * 4 + r;
            if (m0 + row < n_e) {
                const int slot = off + m0 + row;
                const float w = wslot[slot];
#pragma unroll
                for (int n = 0; n < 4; ++n) {
                    const int col = by * 256 + wn * 64 + n * 16 + l15;
                    slot_out[(size_t)slot * D_DIM + col] = f2b(w * acc[m][n][r]);
                }
            }
        }
}

// ================= FALLBACK PATH (small ws): round-2 style kernels =================
__global__ __launch_bounds__(256) void k_gemm1_fb(
    const unsigned short* __restrict__ xg, const float* __restrict__ W1,
    const int* __restrict__ offs, const int* __restrict__ tiletab,
    unsigned short* __restrict__ act) {
    const int tt = tiletab[blockIdx.x];
    if (tt < 0) return;
    const int e = tt >> 16, m0 = (tt & 0xffff) << 7;
    const int off = offs[e], n_e = offs[e + 1] - off;
    const int h0 = blockIdx.y * 64;

    __shared__ unsigned short Ab[128 * 64];
    __shared__ unsigned short Bb[128 * 66];

    const int tid = threadIdx.x;
    const int wid = tid >> 6, lane = tid & 63;
    const int l15 = lane & 15, kq = lane >> 4;

    f32x4 acc[2][8];
#pragma unroll
    for (int m = 0; m < 2; ++m)
#pragma unroll
        for (int n = 0; n < 8; ++n)
#pragma unroll
            for (int r = 0; r < 4; ++r) acc[m][n][r] = 0.f;

    for (int k0 = 0; k0 < D_DIM; k0 += 64) {
        __syncthreads();
#pragma unroll
        for (int j = 0; j < 4; ++j) {
            const int o = wid * 4096 + j * 1024 + lane * 16;
            const int row = o >> 7, kb = o & 127;
            int gr = off + m0 + row; gr = (gr < TK) ? gr : (TK - 1);
            const unsigned short* gp = xg + (size_t)gr * D_DIM + k0 + (kb >> 1);
            __builtin_amdgcn_global_load_lds((gas_t)gp,
                (las_t)((char*)Ab + wid * 4096 + j * 1024), 16, 0, 0);
        }
        {
            const float* W1e = W1 + (size_t)e * D_DIM * (2 * H_DIM);
#pragma unroll
            for (int i = 0; i < 8; ++i) {
                const int flat = tid + 256 * i;
                const int cg = flat & 31, kk = flat >> 5;
                const int cc = cg * 4;
                const int gc = (cc < 64) ? (h0 + cc) : (H_DIM + h0 + cc - 64);
                const float4 v = *reinterpret_cast<const float4*>(
                    &W1e[(size_t)(k0 + kk) * (2 * H_DIM) + gc]);
                Bb[(cc + 0) * 66 + kk] = f2b(v.x);
                Bb[(cc + 1) * 66 + kk] = f2b(v.y);
                Bb[(cc + 2) * 66 + kk] = f2b(v.z);
                Bb[(cc + 3) * 66 + kk] = f2b(v.w);
            }
        }
        __syncthreads();
#pragma unroll
        for (int ks = 0; ks < 2; ++ks) {
            bf16x8 a[2], b[8];
#pragma unroll
            for (int m = 0; m < 2; ++m)
                a[m] = __builtin_bit_cast(bf16x8, *reinterpret_cast<const u16x8*>(
                    &Ab[(wid * 32 + m * 16 + l15) * 64 + ks * 32 + kq * 8]));
#pragma unroll
            for (int n = 0; n < 8; ++n)
                b[n] = __builtin_bit_cast(bf16x8, *reinterpret_cast<const u16x8*>(
                    &Bb[(n * 16 + l15) * 66 + ks * 32 + kq * 8]));
#pragma unroll
            for (int m = 0; m < 2; ++m)
#pragma unroll
                for (int n = 0; n < 8; ++n)
                    acc[m][n] = __builtin_amdgcn_mfma_f32_16x16x32_bf16(a[m], b[n], acc[m][n], 0, 0, 0);
        }
    }
#pragma unroll
    for (int m = 0; m < 2; ++m)
#pragma unroll
        for (int n = 0; n < 4; ++n)
#pragma unroll
            for (int r = 0; r < 4; ++r) {
                const int row = wid * 32 + m * 16 + kq * 4 + r;
                if (m0 + row < n_e) {
                    const float vv = acc[m][n][r], gg = acc[m][n + 4][r];
                    const float s = gg / (1.0f + __expf(-gg));
                    act[(size_t)(off + m0 + row) * H_DIM + h0 + n * 16 + l15] = f2b(vv * s);
                }
            }
}

__global__ __launch_bounds__(256) void k_gemm2_fb(
    const unsigned short* __restrict__ act, const float* __restrict__ W2,
    const int* __restrict__ offs, const int* __restrict__ tiletab,
    const float* __restrict__ wslot, unsigned short* __restrict__ slot_out,
    float* __restrict__ y, const int* __restrict__ rows, int atomic_mode) {
    const int tt = tiletab[blockIdx.x];
    if (tt < 0) return;
    const int e = tt >> 16, m0 = (tt & 0xffff) << 7;
    const int off = offs[e], n_e = offs[e + 1] - off;
    const int n0 = blockIdx.y * 64;

    __shared__ unsigned short Ab[128 * 64];
    __shared__ unsigned short Bb[64 * 66];

    const int tid = threadIdx.x;
    const int wid = tid >> 6, lane = tid & 63;
    const int l15 = lane & 15, kq = lane >> 4;

    f32x4 acc[2][4];
#pragma unroll
    for (int m = 0; m < 2; ++m)
#pragma unroll
        for (int n = 0; n < 4; ++n)
#pragma unroll
            for (int r = 0; r < 4; ++r) acc[m][n][r] = 0.f;

    for (int k0 = 0; k0 < H_DIM; k0 += 64) {
        __syncthreads();
#pragma unroll
        for (int j = 0; j < 4; ++j) {
            const int o = wid * 4096 + j * 1024 + lane * 16;
            const int row = o >> 7, kb = o & 127;
            int gr = off + m0 + row; gr = (gr < TK) ? gr : (TK - 1);
            const unsigned short* gp = act + (size_t)gr * H_DIM + k0 + (kb >> 1);
            __builtin_amdgcn_global_load_lds((gas_t)gp,
                (las_t)((char*)Ab + wid * 4096 + j * 1024), 16, 0, 0);
        }
        {
            const float* W2e = W2 + (size_t)e * H_DIM * D_DIM;
#pragma unroll
            for (int i = 0; i < 4; ++i) {
                const int flat = tid + 256 * i;
                const int cg = flat & 15, kk = flat >> 4;
                const int cc = cg * 4;
                const float4 v = *reinterpret_cast<const float4*>(
                    &W2e[(size_t)(k0 + kk) * D_DIM + n0 + cc]);
                Bb[(cc + 0) * 66 + kk] = f2b(v.x);
                Bb[(cc + 1) * 66 + kk] = f2b(v.y);
                Bb[(cc + 2) * 66 + kk] = f2b(v.z);
                Bb[(cc + 3) * 66 + kk] = f2b(v.w);
            }
        }
        __syncthreads();
#pragma unroll
        for (int ks = 0; ks < 2; ++ks) {
            bf16x8 a[2], b[4];
#pragma unroll
            for (int m = 0; m < 2; ++m)
                a[m] = __builtin_bit_cast(bf16x8, *reinterpret_cast<const u16x8*>(
                    &Ab[(wid * 32 + m * 16 + l15) * 64 + ks * 32 + kq * 8]));
#pragma unroll
            for (int n = 0; n < 4; ++n)
                b[n] = __builtin_bit_cast(bf16x8, *reinterpret_cast<const u16x8*>(
                    &Bb[(n * 16 + l15) * 66 + ks * 32 + kq * 8]));
#pragma unroll
            for (int m = 0; m < 2; ++m)
#pragma unroll
                for (int n = 0; n < 4; ++n)
                    acc[m][n] = __builtin_amdgcn_mfma_f32_16x16x32_bf16(a[m], b[n], acc[m][n], 0, 0, 0);
        }
    }
#pragma unroll
    for (int m = 0; m < 2; ++m)
#pragma unroll
        for (int r = 0; r < 4; ++r) {
            const int row = wid * 32 + m * 16 + kq * 4 + r;
            if (m0 + row < n_e) {
                const int slot = off + m0 + row;
                const float w = wslot[slot];
#pragma unroll
                for (int n = 0; n < 4; ++n) {
                    const float o = w * acc[m][n][r];
                    if (atomic_mode)
                        atomicAdd(&y[(size_t)rows[slot] * D_DIM + n0 + n * 16 + l15], o);
                    else
                        slot_out[(size_t)slot * D_DIM + n0 + n * 16 + l15] = f2b(o);
                }
            }
        }
}

// ---------------- combine ----------------
__global__ __launch_bounds__(256) void k_combine(
    const unsigned short* __restrict__ slot_out, const int* __restrict__ slot_of,
    float* __restrict__ y) {
    const int t = blockIdx.x;
    const int d = threadIdx.x * 4;
    const int s0 = slot_of[2 * t], s1 = slot_of[2 * t + 1];
    const ushort4 a = *reinterpret_cast<const ushort4*>(&slot_out[(size_t)s0 * D_DIM + d]);
    const ushort4 b = *reinterpret_cast<const ushort4*>(&slot_out[(size_t)s1 * D_DIM + d]);
    float4 r;
    r.x = b2f(a.x) + b2f(b.x);
    r.y = b2f(a.y) + b2f(b.y);
    r.z = b2f(a.z) + b2f(b.z);
    r.w = b2f(a.w) + b2f(b.w);
    *reinterpret_cast<float4*>(&y[(size_t)t * D_DIM + d]) = r;
}

extern "C" void kernel_launch(void* const* d_in, const int* in_sizes, int n_in,
                              void* d_out, int out_size, void* d_ws, size_t ws_size,
                              hipStream_t stream) {
    const float* x = (const float*)d_in[0];
    const float* wts = (const float*)d_in[1];
    const int* idx = (const int*)d_in[2];
    const float* W1 = (const float*)d_in[4];
    const float* W2 = (const float*)d_in[5];
    float* y = (float*)d_out;

    char* ws = (char*)d_ws;
    int* cnt = (int*)(ws + 0);
    int* cur = (int*)(ws + 64);
    int* offs = (int*)(ws + 128);
    int* ntiles = (int*)(ws + 256);
    int* tiletab = (int*)(ws + 320);       // 144 ints
    int* tiletab256 = (int*)(ws + 1024);   // 80 ints
    int* rows = (int*)(ws + 2048);
    float* wslot = (float*)(ws + 2048 + (size_t)TK * 4);
    int* slot_of = (int*)(ws + 2048 + (size_t)TK * 8);
    const size_t OFF_XG = 2048 + (size_t)TK * 12;
    unsigned short* xg = (unsigned short*)(ws + OFF_XG);           // fb: [TK][D]; full: xb [T][D] aliased
    unsigned short* xb = xg;
    const size_t OFF_ACT = OFF_XG + (size_t)TK * D_DIM * 2;
    unsigned short* act = (unsigned short*)(ws + OFF_ACT);
    const size_t OFF_SO = OFF_ACT + (size_t)TK * H_DIM * 2;
    unsigned short* slot_out = (unsigned short*)(ws + OFF_SO);
    const size_t MID_END = OFF_SO + (size_t)TK * D_DIM * 2;
    const size_t OFF_W1T = MID_END;
    unsigned short* W1T = (unsigned short*)(ws + OFF_W1T);
    const size_t OFF_W2T = OFF_W1T + (size_t)E_EXP * 2 * H_DIM * D_DIM * 2;
    unsigned short* W2T = (unsigned short*)(ws + OFF_W2T);
    const size_t FULL_END = OFF_W2T + (size_t)E_EXP * D_DIM * H_DIM * 2;

    const int full = (ws_size >= FULL_END) ? 1 : 0;
    const int atomic_mode = (!full && ws_size < MID_END) ? 1 : 0;

    hipMemsetAsync(ws, 0, 128, stream);
    k_count<<<(TK + 255) / 256, 256, 0, stream>>>(idx, cnt);
    k_scan<<<1, 64, 0, stream>>>(cnt, offs, tiletab, tiletab256, ntiles);
    k_scatter<<<(TK + 255) / 256, 256, 0, stream>>>(idx, wts, offs, cur, rows, wslot, slot_of);

    if (full) {
        k_castx<<<T_TOK, 256, 0, stream>>>(x, xb);
        dim3 gc1(D_DIM / 64, (2 * H_DIM) / 64, E_EXP);
        k_castT64<1><<<gc1, 256, 0, stream>>>(W1, W1T, D_DIM, 2 * H_DIM);
        dim3 gc2(H_DIM / 64, D_DIM / 64, E_EXP);
        k_castT64<0><<<gc2, 256, 0, stream>>>(W2, W2T, H_DIM, D_DIM);

        dim3 g1(NT256, H_DIM / 128);
        k_gemm1_fast<<<g1, 512, 0, stream>>>(xb, W1T, offs, tiletab256, rows, act);
        dim3 g2(NT256, D_DIM / 256);
        k_gemm2_fast<<<g2, 512, 0, stream>>>(act, W2T, offs, tiletab256, wslot, slot_out);
        k_combine<<<T_TOK, 256, 0, stream>>>(slot_out, slot_of, y);
    } else {
        k_gather<<<TK, 256, 0, stream>>>(x, rows, xg);
        dim3 g1(NT128, H_DIM / 64);
        k_gemm1_fb<<<g1, 256, 0, stream>>>(xg, W1, offs, tiletab, act);
        if (atomic_mode) hipMemsetAsync(y, 0, (size_t)out_size * 4, stream);
        dim3 g2(NT128, D_DIM / 64);
        k_gemm2_fb<<<g2, 256, 0, stream>>>(act, W2, offs, tiletab, wslot, slot_out, y, rows, atomic_mode);
        if (!atomic_mode)
            k_combine<<<T_TOK, 256, 0, stream>>>(slot_out, slot_of, y);
    }
}

// Round 5
// 254.314 us; speedup vs baseline: 3.5712x; 1.2589x over previous
//
#include <hip/hip_runtime.h>
#include <hip/hip_bf16.h>

#define T_TOK 8192
#define D_DIM 1024
#define H_DIM 768
#define E_EXP 16
#define K_TOP 2
#define TK (T_TOK * K_TOP)
#define NT128 144
#define NT256 80

typedef __bf16 bf16x8 __attribute__((ext_vector_type(8)));
typedef unsigned short u16x8 __attribute__((ext_vector_type(8)));
typedef float f32x4 __attribute__((ext_vector_type(4)));

typedef const __attribute__((address_space(1))) void* gas_t;
typedef __attribute__((address_space(3))) void* las_t;

__device__ __forceinline__ unsigned short f2b(float f) {
    __hip_bfloat16 h = __float2bfloat16(f);
    return __builtin_bit_cast(unsigned short, h);
}
__device__ __forceinline__ float b2f(unsigned short u) {
    unsigned int x = ((unsigned int)u) << 16;
    return __builtin_bit_cast(float, x);
}

// ---------------- fused routing: count + scan + scatter (1 block) ----------------
__global__ __launch_bounds__(1024) void k_route(
    const int* __restrict__ idx, const float* __restrict__ wts,
    int* __restrict__ offs, int* __restrict__ tiletab, int* __restrict__ tiletab256,
    int* __restrict__ rows, float* __restrict__ wslot, int* __restrict__ slot_of) {
    __shared__ int lcnt[E_EXP];
    __shared__ int lcur[E_EXP];
    const int tid = threadIdx.x;
    if (tid < E_EXP) lcnt[tid] = 0;
    __syncthreads();
    for (int i = tid; i < TK; i += 1024) atomicAdd(&lcnt[idx[i]], 1);
    __syncthreads();
    if (tid == 0) {
        int s = 0, nt = 0, nt2 = 0;
        for (int e = 0; e < E_EXP; ++e) {
            offs[e] = s;
            lcur[e] = s;
            const int n = lcnt[e];
            for (int m0 = 0; m0 < n; m0 += 128) tiletab[nt++] = (e << 16) | (m0 >> 7);
            for (int m0 = 0; m0 < n; m0 += 256) tiletab256[nt2++] = (e << 16) | (m0 >> 8);
            s += n;
        }
        offs[E_EXP] = s;
        for (int i = nt; i < NT128; ++i) tiletab[i] = -1;
        for (int i = nt2; i < NT256; ++i) tiletab256[i] = -1;
    }
    __syncthreads();
    for (int i = tid; i < TK; i += 1024) {
        const int e = idx[i];
        const int p = atomicAdd(&lcur[e], 1);
        rows[p] = i >> 1;          // K_TOP == 2
        wslot[p] = wts[i];
        slot_of[i] = p;
    }
}

// ---------------- fused prep: cast x + transpose/cast W1,W2 (full path) ----------------
// blocks [0, T) : castx ; [T, T+6144) : W1T ; [T+6144, T+9216) : W2T
#define PREP_X T_TOK
#define PREP_W1 (PREP_X + (D_DIM / 64) * ((2 * H_DIM) / 64) * E_EXP)   // +6144
#define PREP_W2 (PREP_W1 + (H_DIM / 64) * (D_DIM / 64) * E_EXP)        // +3072

__global__ __launch_bounds__(256) void k_prep(
    const float* __restrict__ x, const float* __restrict__ W1, const float* __restrict__ W2,
    unsigned short* __restrict__ xb, unsigned short* __restrict__ W1T,
    unsigned short* __restrict__ W2T) {
    const int b = blockIdx.x;
    const int tid = threadIdx.x;
    if (b < PREP_X) {
        const int d = tid * 4;
        const float4 v = *reinterpret_cast<const float4*>(&x[(size_t)b * D_DIM + d]);
        ushort4 u;
        u.x = f2b(v.x); u.y = f2b(v.y); u.z = f2b(v.z); u.w = f2b(v.w);
        *reinterpret_cast<ushort4*>(&xb[(size_t)b * D_DIM + d]) = u;
        return;
    }
    __shared__ float t4[64][65];
    const float* src; unsigned short* dst; int K, C, e, kb, cb, pack;
    if (b < PREP_W1) {
        const int q = b - PREP_X;
        K = D_DIM; C = 2 * H_DIM; pack = 1;
        e = q / ((K / 64) * (C / 64));
        const int r = q % ((K / 64) * (C / 64));
        kb = (r % (K / 64)) * 64; cb = (r / (K / 64)) * 64;
        src = W1; dst = W1T;
    } else {
        const int q = b - PREP_W1;
        K = H_DIM; C = D_DIM; pack = 0;
        e = q / ((K / 64) * (C / 64));
        const int r = q % ((K / 64) * (C / 64));
        kb = (r % (K / 64)) * 64; cb = (r / (K / 64)) * 64;
        src = W2; dst = W2T;
    }
    const float* s = src + ((size_t)e * K + kb) * C + cb;
#pragma unroll
    for (int i = 0; i < 4; ++i) {
        const int kk = (tid >> 4) + i * 16, c4 = (tid & 15) * 4;
        const float4 v = *reinterpret_cast<const float4*>(&s[(size_t)kk * C + c4]);
        t4[kk][c4] = v.x; t4[kk][c4 + 1] = v.y; t4[kk][c4 + 2] = v.z; t4[kk][c4 + 3] = v.w;
    }
    __syncthreads();
#pragma unroll
    for (int i = 0; i < 4; ++i) {
        const int cc = (tid >> 4) + i * 16, k4 = (tid & 15) * 4;
        const int j = cb + cc;
        int drow;
        if (pack) drow = (j < H_DIM) ? ((j >> 5) * 64 + (j & 31))
                                     : (((j - H_DIM) >> 5) * 64 + 32 + ((j - H_DIM) & 31));
        else drow = j;
        ushort4 u;
        u.x = f2b(t4[k4][cc]); u.y = f2b(t4[k4 + 1][cc]);
        u.z = f2b(t4[k4 + 2][cc]); u.w = f2b(t4[k4 + 3][cc]);
        *reinterpret_cast<ushort4*>(&dst[((size_t)e * C + drow) * K + kb + k4]) = u;
    }
}

// ================= FAST PATH: BK=32, 4-slot LDS rotation, counted vmcnt =================
// Slot layout: SA/SB[slot][256*32] bf16 (16 KiB each). Chunk swizzle (involution):
// 64B row = 4 chunks of 16B; phys_chunk = log_chunk ^ ((row>>1)&3).
// Staged via pre-swizzled GLOBAL source (linear LDS dest, rule #21); reads XOR identically.
// Prefetch distance 3; per-tile s_waitcnt vmcnt(8) (tail: 4, 0); raw s_barrier; T5 setprio.

__global__ __launch_bounds__(512, 1) void k_gemm1_fast(
    const unsigned short* __restrict__ xb, const unsigned short* __restrict__ W1T,
    const int* __restrict__ offs, const int* __restrict__ tiletab256,
    const int* __restrict__ rows, unsigned short* __restrict__ act) {
    const int ti = (blockIdx.x & 7) * (NT256 / 8) + (blockIdx.x >> 3);  // XCD swizzle
    const int tt = tiletab256[ti];
    if (tt < 0) return;
    const int e = tt >> 16, m0 = (tt & 0xffff) << 8;
    const int off = offs[e], n_e = offs[e + 1] - off;
    const int by = blockIdx.y;   // 0..5 (128 act cols each)

    __shared__ unsigned short SA[4][256 * 32];
    __shared__ unsigned short SB[4][256 * 32];

    const int tid = threadIdx.x;
    const int wid = tid >> 6, lane = tid & 63;
    const int l15 = lane & 15, kq = lane >> 4;
    const int wm = wid >> 2, wn = wid & 3;
    // staging: thread covers rows j*128 + (tid>>2), chunk tid&3 (16B); src chunk pre-swizzled
    const int srow_lo = tid >> 2;
    const int esw = (((tid & 3) ^ ((tid >> 3) & 3)) << 3);   // bf16 elems within 64B row
    // read-side phys chunk for MFMA frags
    const int rk = ((kq ^ ((l15 >> 1) & 3)) << 3);           // bf16 elems

    int tok[2];
    long bB[2];
#pragma unroll
    for (int j = 0; j < 2; ++j) {
        int s = m0 + j * 128 + srow_lo;
        s = (s < n_e) ? s : (n_e - 1);
        tok[j] = rows[off + s];
        bB[j] = ((size_t)e * (2 * H_DIM) + by * 256 + j * 128 + srow_lo) * D_DIM + esw;
    }

    f32x4 acc[8][4];
#pragma unroll
    for (int m = 0; m < 8; ++m)
#pragma unroll
        for (int n = 0; n < 4; ++n)
#pragma unroll
            for (int r = 0; r < 4; ++r) acc[m][n][r] = 0.f;

    auto stage = [&](int t) {
        const int sl = t & 3;
        const int k0 = t * 32;
#pragma unroll
        for (int j = 0; j < 2; ++j) {
            const unsigned short* ga = xb + (size_t)tok[j] * D_DIM + k0 + esw;
            __builtin_amdgcn_global_load_lds((gas_t)ga,
                (las_t)((char*)&SA[sl][0] + j * 8192 + tid * 16), 16, 0, 0);
            const unsigned short* gb = W1T + bB[j] + k0;
            __builtin_amdgcn_global_load_lds((gas_t)gb,
                (las_t)((char*)&SB[sl][0] + j * 8192 + tid * 16), 16, 0, 0);
        }
    };

    stage(0); stage(1); stage(2);
    const int NT = D_DIM / 32;   // 32
    for (int t = 0; t < NT; ++t) {
        if (t < NT - 2)       asm volatile("s_waitcnt vmcnt(8)" ::: "memory");
        else if (t == NT - 2) asm volatile("s_waitcnt vmcnt(4)" ::: "memory");
        else                  asm volatile("s_waitcnt vmcnt(0)" ::: "memory");
        __builtin_amdgcn_s_barrier();
        asm volatile("" ::: "memory");
        if (t + 3 < NT) stage(t + 3);
        const int sl = t & 3;
        bf16x8 a[8], b[4];
#pragma unroll
        for (int m = 0; m < 8; ++m) {
            const int row = wm * 128 + m * 16 + l15;
            a[m] = __builtin_bit_cast(bf16x8, *reinterpret_cast<const u16x8*>(
                &SA[sl][row * 32 + rk]));
        }
#pragma unroll
        for (int n = 0; n < 4; ++n) {
            const int row = wn * 64 + n * 16 + l15;
            b[n] = __builtin_bit_cast(bf16x8, *reinterpret_cast<const u16x8*>(
                &SB[sl][row * 32 + rk]));
        }
        __builtin_amdgcn_s_setprio(1);
#pragma unroll
        for (int m = 0; m < 8; ++m)
#pragma unroll
            for (int n = 0; n < 4; ++n)
                acc[m][n] = __builtin_amdgcn_mfma_f32_16x16x32_bf16(a[m], b[n], acc[m][n], 0, 0, 0);
        __builtin_amdgcn_s_setprio(0);
    }
    // epilogue: silu-gate; frag n<2 = v-cols, n>=2 = paired g-cols
#pragma unroll
    for (int m = 0; m < 8; ++m)
#pragma unroll
        for (int r = 0; r < 4; ++r) {
            const int row = wm * 128 + m * 16 + kq * 4 + r;
            if (m0 + row < n_e) {
#pragma unroll
                for (int nv = 0; nv < 2; ++nv) {
                    const int col = by * 128 + wn * 32 + nv * 16 + l15;
                    const float vv = acc[m][nv][r], gg = acc[m][2 + nv][r];
                    const float s = gg / (1.0f + __expf(-gg));
                    act[(size_t)(off + m0 + row) * H_DIM + col] = f2b(vv * s);
                }
            }
        }
}

__global__ __launch_bounds__(512, 1) void k_gemm2_fast(
    const unsigned short* __restrict__ act, const unsigned short* __restrict__ W2T,
    const int* __restrict__ offs, const int* __restrict__ tiletab256,
    const float* __restrict__ wslot, unsigned short* __restrict__ slot_out) {
    const int ti = (blockIdx.x & 7) * (NT256 / 8) + (blockIdx.x >> 3);
    const int tt = tiletab256[ti];
    if (tt < 0) return;
    const int e = tt >> 16, m0 = (tt & 0xffff) << 8;
    const int off = offs[e], n_e = offs[e + 1] - off;
    const int by = blockIdx.y;   // 0..3

    __shared__ unsigned short SA[4][256 * 32];
    __shared__ unsigned short SB[4][256 * 32];

    const int tid = threadIdx.x;
    const int wid = tid >> 6, lane = tid & 63;
    const int l15 = lane & 15, kq = lane >> 4;
    const int wm = wid >> 2, wn = wid & 3;
    const int srow_lo = tid >> 2;
    const int esw = (((tid & 3) ^ ((tid >> 3) & 3)) << 3);
    const int rk = ((kq ^ ((l15 >> 1) & 3)) << 3);

    int slotA[2];
    long bB[2];
#pragma unroll
    for (int j = 0; j < 2; ++j) {
        int s = m0 + j * 128 + srow_lo;
        s = (s < n_e) ? s : (n_e - 1);
        slotA[j] = off + s;
        bB[j] = ((size_t)e * D_DIM + by * 256 + j * 128 + srow_lo) * H_DIM + esw;
    }

    f32x4 acc[8][4];
#pragma unroll
    for (int m = 0; m < 8; ++m)
#pragma unroll
        for (int n = 0; n < 4; ++n)
#pragma unroll
            for (int r = 0; r < 4; ++r) acc[m][n][r] = 0.f;

    auto stage = [&](int t) {
        const int sl = t & 3;
        const int k0 = t * 32;
#pragma unroll
        for (int j = 0; j < 2; ++j) {
            const unsigned short* ga = act + (size_t)slotA[j] * H_DIM + k0 + esw;
            __builtin_amdgcn_global_load_lds((gas_t)ga,
                (las_t)((char*)&SA[sl][0] + j * 8192 + tid * 16), 16, 0, 0);
            const unsigned short* gb = W2T + bB[j] + k0;
            __builtin_amdgcn_global_load_lds((gas_t)gb,
                (las_t)((char*)&SB[sl][0] + j * 8192 + tid * 16), 16, 0, 0);
        }
    };

    stage(0); stage(1); stage(2);
    const int NT = H_DIM / 32;   // 24
    for (int t = 0; t < NT; ++t) {
        if (t < NT - 2)       asm volatile("s_waitcnt vmcnt(8)" ::: "memory");
        else if (t == NT - 2) asm volatile("s_waitcnt vmcnt(4)" ::: "memory");
        else                  asm volatile("s_waitcnt vmcnt(0)" ::: "memory");
        __builtin_amdgcn_s_barrier();
        asm volatile("" ::: "memory");
        if (t + 3 < NT) stage(t + 3);
        const int sl = t & 3;
        bf16x8 a[8], b[4];
#pragma unroll
        for (int m = 0; m < 8; ++m) {
            const int row = wm * 128 + m * 16 + l15;
            a[m] = __builtin_bit_cast(bf16x8, *reinterpret_cast<const u16x8*>(
                &SA[sl][row * 32 + rk]));
        }
#pragma unroll
        for (int n = 0; n < 4; ++n) {
            const int row = wn * 64 + n * 16 + l15;
            b[n] = __builtin_bit_cast(bf16x8, *reinterpret_cast<const u16x8*>(
                &SB[sl][row * 32 + rk]));
        }
        __builtin_amdgcn_s_setprio(1);
#pragma unroll
        for (int m = 0; m < 8; ++m)
#pragma unroll
            for (int n = 0; n < 4; ++n)
                acc[m][n] = __builtin_amdgcn_mfma_f32_16x16x32_bf16(a[m], b[n], acc[m][n], 0, 0, 0);
        __builtin_amdgcn_s_setprio(0);
    }
#pragma unroll
    for (int m = 0; m < 8; ++m)
#pragma unroll
        for (int r = 0; r < 4; ++r) {
            const int row = wm * 128 + m * 16 + kq * 4 + r;
            if (m0 + row < n_e) {
                const int slot = off + m0 + row;
                const float w = wslot[slot];
#pragma unroll
                for (int n = 0; n < 4; ++n) {
                    const int col = by * 256 + wn * 64 + n * 16 + l15;
                    slot_out[(size_t)slot * D_DIM + col] = f2b(w * acc[m][n][r]);
                }
            }
        }
}

// ================= FALLBACK PATH (small ws) =================
__global__ __launch_bounds__(256) void k_gather(const float* __restrict__ x,
                                                const int* __restrict__ rows,
                                                unsigned short* __restrict__ xg) {
    const int s = blockIdx.x, t = threadIdx.x;
    const int tok = rows[s];
    const float4 v = *reinterpret_cast<const float4*>(&x[(size_t)tok * D_DIM + t * 4]);
    ushort4 u;
    u.x = f2b(v.x); u.y = f2b(v.y); u.z = f2b(v.z); u.w = f2b(v.w);
    *reinterpret_cast<ushort4*>(&xg[(size_t)s * D_DIM + t * 4]) = u;
}

__global__ __launch_bounds__(256) void k_gemm1_fb(
    const unsigned short* __restrict__ xg, const float* __restrict__ W1,
    const int* __restrict__ offs, const int* __restrict__ tiletab,
    unsigned short* __restrict__ act) {
    const int tt = tiletab[blockIdx.x];
    if (tt < 0) return;
    const int e = tt >> 16, m0 = (tt & 0xffff) << 7;
    const int off = offs[e], n_e = offs[e + 1] - off;
    const int h0 = blockIdx.y * 64;

    __shared__ unsigned short Ab[128 * 64];
    __shared__ unsigned short Bb[128 * 66];

    const int tid = threadIdx.x;
    const int wid = tid >> 6, lane = tid & 63;
    const int l15 = lane & 15, kq = lane >> 4;

    f32x4 acc[2][8];
#pragma unroll
    for (int m = 0; m < 2; ++m)
#pragma unroll
        for (int n = 0; n < 8; ++n)
#pragma unroll
            for (int r = 0; r < 4; ++r) acc[m][n][r] = 0.f;

    for (int k0 = 0; k0 < D_DIM; k0 += 64) {
        __syncthreads();
#pragma unroll
        for (int j = 0; j < 4; ++j) {
            const int o = wid * 4096 + j * 1024 + lane * 16;
            const int row = o >> 7, kb = o & 127;
            int gr = off + m0 + row; gr = (gr < TK) ? gr : (TK - 1);
            const unsigned short* gp = xg + (size_t)gr * D_DIM + k0 + (kb >> 1);
            __builtin_amdgcn_global_load_lds((gas_t)gp,
                (las_t)((char*)Ab + wid * 4096 + j * 1024), 16, 0, 0);
        }
        {
            const float* W1e = W1 + (size_t)e * D_DIM * (2 * H_DIM);
#pragma unroll
            for (int i = 0; i < 8; ++i) {
                const int flat = tid + 256 * i;
                const int cg = flat & 31, kk = flat >> 5;
                const int cc = cg * 4;
                const int gc = (cc < 64) ? (h0 + cc) : (H_DIM + h0 + cc - 64);
                const float4 v = *reinterpret_cast<const float4*>(
                    &W1e[(size_t)(k0 + kk) * (2 * H_DIM) + gc]);
                Bb[(cc + 0) * 66 + kk] = f2b(v.x);
                Bb[(cc + 1) * 66 + kk] = f2b(v.y);
                Bb[(cc + 2) * 66 + kk] = f2b(v.z);
                Bb[(cc + 3) * 66 + kk] = f2b(v.w);
            }
        }
        __syncthreads();
#pragma unroll
        for (int ks = 0; ks < 2; ++ks) {
            bf16x8 a[2], b[8];
#pragma unroll
            for (int m = 0; m < 2; ++m)
                a[m] = __builtin_bit_cast(bf16x8, *reinterpret_cast<const u16x8*>(
                    &Ab[(wid * 32 + m * 16 + l15) * 64 + ks * 32 + kq * 8]));
#pragma unroll
            for (int n = 0; n < 8; ++n)
                b[n] = __builtin_bit_cast(bf16x8, *reinterpret_cast<const u16x8*>(
                    &Bb[(n * 16 + l15) * 66 + ks * 32 + kq * 8]));
#pragma unroll
            for (int m = 0; m < 2; ++m)
#pragma unroll
                for (int n = 0; n < 8; ++n)
                    acc[m][n] = __builtin_amdgcn_mfma_f32_16x16x32_bf16(a[m], b[n], acc[m][n], 0, 0, 0);
        }
    }
#pragma unroll
    for (int m = 0; m < 2; ++m)
#pragma unroll
        for (int n = 0; n < 4; ++n)
#pragma unroll
            for (int r = 0; r < 4; ++r) {
                const int row = wid * 32 + m * 16 + kq * 4 + r;
                if (m0 + row < n_e) {
                    const float vv = acc[m][n][r], gg = acc[m][n + 4][r];
                    const float s = gg / (1.0f + __expf(-gg));
                    act[(size_t)(off + m0 + row) * H_DIM + h0 + n * 16 + l15] = f2b(vv * s);
                }
            }
}

__global__ __launch_bounds__(256) void k_gemm2_fb(
    const unsigned short* __restrict__ act, const float* __restrict__ W2,
    const int* __restrict__ offs, const int* __restrict__ tiletab,
    const float* __restrict__ wslot, unsigned short* __restrict__ slot_out,
    float* __restrict__ y, const int* __restrict__ rows, int atomic_mode) {
    const int tt = tiletab[blockIdx.x];
    if (tt < 0) return;
    const int e = tt >> 16, m0 = (tt & 0xffff) << 7;
    const int off = offs[e], n_e = offs[e + 1] - off;
    const int n0 = blockIdx.y * 64;

    __shared__ unsigned short Ab[128 * 64];
    __shared__ unsigned short Bb[64 * 66];

    const int tid = threadIdx.x;
    const int wid = tid >> 6, lane = tid & 63;
    const int l15 = lane & 15, kq = lane >> 4;

    f32x4 acc[2][4];
#pragma unroll
    for (int m = 0; m < 2; ++m)
#pragma unroll
        for (int n = 0; n < 4; ++n)
#pragma unroll
            for (int r = 0; r < 4; ++r) acc[m][n][r] = 0.f;

    for (int k0 = 0; k0 < H_DIM; k0 += 64) {
        __syncthreads();
#pragma unroll
        for (int j = 0; j < 4; ++j) {
            const int o = wid * 4096 + j * 1024 + lane * 16;
            const int row = o >> 7, kb = o & 127;
            int gr = off + m0 + row; gr = (gr < TK) ? gr : (TK - 1);
            const unsigned short* gp = act + (size_t)gr * H_DIM + k0 + (kb >> 1);
            __builtin_amdgcn_global_load_lds((gas_t)gp,
                (las_t)((char*)Ab + wid * 4096 + j * 1024), 16, 0, 0);
        }
        {
            const float* W2e = W2 + (size_t)e * H_DIM * D_DIM;
#pragma unroll
            for (int i = 0; i < 4; ++i) {
                const int flat = tid + 256 * i;
                const int cg = flat & 15, kk = flat >> 4;
                const int cc = cg * 4;
                const float4 v = *reinterpret_cast<const float4*>(
                    &W2e[(size_t)(k0 + kk) * D_DIM + n0 + cc]);
                Bb[(cc + 0) * 66 + kk] = f2b(v.x);
                Bb[(cc + 1) * 66 + kk] = f2b(v.y);
                Bb[(cc + 2) * 66 + kk] = f2b(v.z);
                Bb[(cc + 3) * 66 + kk] = f2b(v.w);
            }
        }
        __syncthreads();
#pragma unroll
        for (int ks = 0; ks < 2; ++ks) {
            bf16x8 a[2], b[4];
#pragma unroll
            for (int m = 0; m < 2; ++m)
                a[m] = __builtin_bit_cast(bf16x8, *reinterpret_cast<const u16x8*>(
                    &Ab[(wid * 32 + m * 16 + l15) * 64 + ks * 32 + kq * 8]));
#pragma unroll
            for (int n = 0; n < 4; ++n)
                b[n] = __builtin_bit_cast(bf16x8, *reinterpret_cast<const u16x8*>(
                    &Bb[(n * 16 + l15) * 66 + ks * 32 + kq * 8]));
#pragma unroll
            for (int m = 0; m < 2; ++m)
#pragma unroll
                for (int n = 0; n < 4; ++n)
                    acc[m][n] = __builtin_amdgcn_mfma_f32_16x16x32_bf16(a[m], b[n], acc[m][n], 0, 0, 0);
        }
    }
#pragma unroll
    for (int m = 0; m < 2; ++m)
#pragma unroll
        for (int r = 0; r < 4; ++r) {
            const int row = wid * 32 + m * 16 + kq * 4 + r;
            if (m0 + row < n_e) {
                const int slot = off + m0 + row;
                const float w = wslot[slot];
#pragma unroll
                for (int n = 0; n < 4; ++n) {
                    const float o = w * acc[m][n][r];
                    if (atomic_mode)
                        atomicAdd(&y[(size_t)rows[slot] * D_DIM + n0 + n * 16 + l15], o);
                    else
                        slot_out[(size_t)slot * D_DIM + n0 + n * 16 + l15] = f2b(o);
                }
            }
        }
}

// ---------------- combine ----------------
__global__ __launch_bounds__(256) void k_combine(
    const unsigned short* __restrict__ slot_out, const int* __restrict__ slot_of,
    float* __restrict__ y) {
    const int t = blockIdx.x;
    const int d = threadIdx.x * 4;
    const int s0 = slot_of[2 * t], s1 = slot_of[2 * t + 1];
    const ushort4 a = *reinterpret_cast<const ushort4*>(&slot_out[(size_t)s0 * D_DIM + d]);
    const ushort4 b = *reinterpret_cast<const ushort4*>(&slot_out[(size_t)s1 * D_DIM + d]);
    float4 r;
    r.x = b2f(a.x) + b2f(b.x);
    r.y = b2f(a.y) + b2f(b.y);
    r.z = b2f(a.z) + b2f(b.z);
    r.w = b2f(a.w) + b2f(b.w);
    *reinterpret_cast<float4*>(&y[(size_t)t * D_DIM + d]) = r;
}

extern "C" void kernel_launch(void* const* d_in, const int* in_sizes, int n_in,
                              void* d_out, int out_size, void* d_ws, size_t ws_size,
                              hipStream_t stream) {
    const float* x = (const float*)d_in[0];
    const float* wts = (const float*)d_in[1];
    const int* idx = (const int*)d_in[2];
    const float* W1 = (const float*)d_in[4];
    const float* W2 = (const float*)d_in[5];
    float* y = (float*)d_out;

    char* ws = (char*)d_ws;
    int* offs = (int*)(ws + 128);
    int* tiletab = (int*)(ws + 320);       // 144 ints
    int* tiletab256 = (int*)(ws + 1024);   // 80 ints
    int* rows = (int*)(ws + 2048);
    float* wslot = (float*)(ws + 2048 + (size_t)TK * 4);
    int* slot_of = (int*)(ws + 2048 + (size_t)TK * 8);
    const size_t OFF_XG = 2048 + (size_t)TK * 12;
    unsigned short* xg = (unsigned short*)(ws + OFF_XG);   // fb: [TK][D]; full: xb [T][D] aliased
    unsigned short* xb = xg;
    const size_t OFF_ACT = OFF_XG + (size_t)TK * D_DIM * 2;
    unsigned short* act = (unsigned short*)(ws + OFF_ACT);
    const size_t OFF_SO = OFF_ACT + (size_t)TK * H_DIM * 2;
    unsigned short* slot_out = (unsigned short*)(ws + OFF_SO);
    const size_t MID_END = OFF_SO + (size_t)TK * D_DIM * 2;
    const size_t OFF_W1T = MID_END;
    unsigned short* W1T = (unsigned short*)(ws + OFF_W1T);
    const size_t OFF_W2T = OFF_W1T + (size_t)E_EXP * 2 * H_DIM * D_DIM * 2;
    unsigned short* W2T = (unsigned short*)(ws + OFF_W2T);
    const size_t FULL_END = OFF_W2T + (size_t)E_EXP * D_DIM * H_DIM * 2;

    const int full = (ws_size >= FULL_END) ? 1 : 0;
    const int atomic_mode = (!full && ws_size < MID_END) ? 1 : 0;

    k_route<<<1, 1024, 0, stream>>>(idx, wts, offs, tiletab, tiletab256, rows, wslot, slot_of);

    if (full) {
        k_prep<<<PREP_W2, 256, 0, stream>>>(x, W1, W2, xb, W1T, W2T);
        dim3 g1(NT256, H_DIM / 128);
        k_gemm1_fast<<<g1, 512, 0, stream>>>(xb, W1T, offs, tiletab256, rows, act);
        dim3 g2(NT256, D_DIM / 256);
        k_gemm2_fast<<<g2, 512, 0, stream>>>(act, W2T, offs, tiletab256, wslot, slot_out);
        k_combine<<<T_TOK, 256, 0, stream>>>(slot_out, slot_of, y);
    } else {
        k_gather<<<TK, 256, 0, stream>>>(x, rows, xg);
        dim3 g1(NT128, H_DIM / 64);
        k_gemm1_fb<<<g1, 256, 0, stream>>>(xg, W1, offs, tiletab, act);
        if (atomic_mode) hipMemsetAsync(y, 0, (size_t)out_size * 4, stream);
        dim3 g2(NT128, D_DIM / 64);
        k_gemm2_fb<<<g2, 256, 0, stream>>>(act, W2, offs, tiletab, wslot, slot_out, y, rows, atomic_mode);
        if (!atomic_mode)
            k_combine<<<T_TOK, 256, 0, stream>>>(slot_out, slot_of, y);
    }
}

// Round 6
// 244.926 us; speedup vs baseline: 3.7081x; 1.0383x over previous
//
#include <hip/hip_runtime.h>
#include <hip/hip_bf16.h>

#define T_TOK 8192
#define D_DIM 1024
#define H_DIM 768
#define E_EXP 16
#define K_TOP 2
#define TK (T_TOK * K_TOP)
#define NT128 144
#define NT256 80

typedef __bf16 bf16x8 __attribute__((ext_vector_type(8)));
typedef unsigned short u16x8 __attribute__((ext_vector_type(8)));
typedef float f32x4 __attribute__((ext_vector_type(4)));

typedef const __attribute__((address_space(1))) void* gas_t;
typedef __attribute__((address_space(3))) void* las_t;

__device__ __forceinline__ unsigned short f2b(float f) {
    __hip_bfloat16 h = __float2bfloat16(f);
    return __builtin_bit_cast(unsigned short, h);
}
__device__ __forceinline__ float b2f(unsigned short u) {
    unsigned int x = ((unsigned int)u) << 16;
    return __builtin_bit_cast(float, x);
}

// ---------------- fused routing: count + scan + scatter (1 block) ----------------
__global__ __launch_bounds__(1024) void k_route(
    const int* __restrict__ idx, const float* __restrict__ wts,
    int* __restrict__ offs, int* __restrict__ tiletab, int* __restrict__ tiletab256,
    int* __restrict__ rows, float* __restrict__ wslot, int* __restrict__ slot_of) {
    __shared__ int lcnt[E_EXP];
    __shared__ int lcur[E_EXP];
    const int tid = threadIdx.x;
    if (tid < E_EXP) lcnt[tid] = 0;
    __syncthreads();
    for (int i = tid; i < TK; i += 1024) atomicAdd(&lcnt[idx[i]], 1);
    __syncthreads();
    if (tid == 0) {
        int s = 0, nt = 0, nt2 = 0;
        for (int e = 0; e < E_EXP; ++e) {
            offs[e] = s;
            lcur[e] = s;
            const int n = lcnt[e];
            for (int m0 = 0; m0 < n; m0 += 128) tiletab[nt++] = (e << 16) | (m0 >> 7);
            for (int m0 = 0; m0 < n; m0 += 256) tiletab256[nt2++] = (e << 16) | (m0 >> 8);
            s += n;
        }
        offs[E_EXP] = s;
        for (int i = nt; i < NT128; ++i) tiletab[i] = -1;
        for (int i = nt2; i < NT256; ++i) tiletab256[i] = -1;
    }
    __syncthreads();
    for (int i = tid; i < TK; i += 1024) {
        const int e = idx[i];
        const int p = atomicAdd(&lcur[e], 1);
        rows[p] = i >> 1;          // K_TOP == 2
        wslot[p] = wts[i];
        slot_of[i] = p;
    }
}

// ---------------- fused prep: cast x + transpose/cast W1,W2 (full path) ----------------
#define PREP_X T_TOK
#define PREP_W1 (PREP_X + (D_DIM / 64) * ((2 * H_DIM) / 64) * E_EXP)
#define PREP_W2 (PREP_W1 + (H_DIM / 64) * (D_DIM / 64) * E_EXP)

__global__ __launch_bounds__(256) void k_prep(
    const float* __restrict__ x, const float* __restrict__ W1, const float* __restrict__ W2,
    unsigned short* __restrict__ xb, unsigned short* __restrict__ W1T,
    unsigned short* __restrict__ W2T) {
    const int b = blockIdx.x;
    const int tid = threadIdx.x;
    if (b < PREP_X) {
        const int d = tid * 4;
        const float4 v = *reinterpret_cast<const float4*>(&x[(size_t)b * D_DIM + d]);
        ushort4 u;
        u.x = f2b(v.x); u.y = f2b(v.y); u.z = f2b(v.z); u.w = f2b(v.w);
        *reinterpret_cast<ushort4*>(&xb[(size_t)b * D_DIM + d]) = u;
        return;
    }
    __shared__ float t4[64][65];
    const float* src; unsigned short* dst; int K, C, e, kb, cb, pack;
    if (b < PREP_W1) {
        const int q = b - PREP_X;
        K = D_DIM; C = 2 * H_DIM; pack = 1;
        e = q / ((K / 64) * (C / 64));
        const int r = q % ((K / 64) * (C / 64));
        kb = (r % (K / 64)) * 64; cb = (r / (K / 64)) * 64;
        src = W1; dst = W1T;
    } else {
        const int q = b - PREP_W1;
        K = H_DIM; C = D_DIM; pack = 0;
        e = q / ((K / 64) * (C / 64));
        const int r = q % ((K / 64) * (C / 64));
        kb = (r % (K / 64)) * 64; cb = (r / (K / 64)) * 64;
        src = W2; dst = W2T;
    }
    const float* s = src + ((size_t)e * K + kb) * C + cb;
#pragma unroll
    for (int i = 0; i < 4; ++i) {
        const int kk = (tid >> 4) + i * 16, c4 = (tid & 15) * 4;
        const float4 v = *reinterpret_cast<const float4*>(&s[(size_t)kk * C + c4]);
        t4[kk][c4] = v.x; t4[kk][c4 + 1] = v.y; t4[kk][c4 + 2] = v.z; t4[kk][c4 + 3] = v.w;
    }
    __syncthreads();
#pragma unroll
    for (int i = 0; i < 4; ++i) {
        const int cc = (tid >> 4) + i * 16, k4 = (tid & 15) * 4;
        const int j = cb + cc;
        int drow;
        if (pack) drow = (j < H_DIM) ? ((j >> 5) * 64 + (j & 31))
                                     : (((j - H_DIM) >> 5) * 64 + 32 + ((j - H_DIM) & 31));
        else drow = j;
        ushort4 u;
        u.x = f2b(t4[k4][cc]); u.y = f2b(t4[k4 + 1][cc]);
        u.z = f2b(t4[k4 + 2][cc]); u.w = f2b(t4[k4 + 3][cc]);
        *reinterpret_cast<ushort4*>(&dst[((size_t)e * C + drow) * K + kb + k4]) = u;
    }
}

// ================= FAST PATH: 8-phase m201-style schedule =================
// BM=256, BN(logical)=256, BK=64 split in 2 k-halves of 32. 8 waves (2M x 4N),
// per-wave 128x64. LDS: [2 dbuf][2 khalf][256 rows][32 k] for A and B = 128 KiB.
// Per tile: 4 phases (khalf x mgroup), each {ds_read frags | stage one half of
// tile t+1 | barrier | lgkmcnt(0) | sched_barrier | setprio(1) | 16 MFMA |
// setprio(0) | barrier}. Counted vmcnt(4) at end of phases 1 and 3 only.
// Bank swizzle: 16B chunk ^= (row>>1)&3 (involution; pre-swizzled global src,
// linear LDS dest; identical XOR on ds_read). Proven 0-conflict (r4/r5).

#define PH_OPEN()                                          \
    asm volatile("" ::: "memory");                         \
    __builtin_amdgcn_s_barrier();                          \
    asm volatile("s_waitcnt lgkmcnt(0)" ::: "memory");     \
    __builtin_amdgcn_sched_barrier(0);                     \
    __builtin_amdgcn_s_setprio(1);

#define PH_CLOSE()                                         \
    __builtin_amdgcn_s_setprio(0);                         \
    asm volatile("" ::: "memory");                         \
    __builtin_amdgcn_s_barrier();

#define MM4(BASE)                                                          \
    _Pragma("unroll")                                                      \
    for (int mf = 0; mf < 4; ++mf)                                         \
        _Pragma("unroll")                                                  \
        for (int nf = 0; nf < 4; ++nf)                                     \
            acc[(BASE) + mf][nf] = __builtin_amdgcn_mfma_f32_16x16x32_bf16( \
                a[mf], b[nf], acc[(BASE) + mf][nf], 0, 0, 0);

#define LDA4(SL, KS, MG)                                                   \
    _Pragma("unroll")                                                      \
    for (int mf = 0; mf < 4; ++mf) {                                       \
        const int row_ = wm * 128 + (MG) * 64 + mf * 16 + l15;             \
        a[mf] = __builtin_bit_cast(bf16x8, *reinterpret_cast<const u16x8*>( \
            &SA[(((SL) * 2 + (KS)) * 256 + row_) * 32 + rk]));             \
    }

#define LDB4(SL, KS)                                                       \
    _Pragma("unroll")                                                      \
    for (int nf = 0; nf < 4; ++nf) {                                       \
        const int row_ = wn * 64 + nf * 16 + l15;                          \
        b[nf] = __builtin_bit_cast(bf16x8, *reinterpret_cast<const u16x8*>( \
            &SB[(((SL) * 2 + (KS)) * 256 + row_) * 32 + rk]));             \
    }

__global__ __launch_bounds__(512, 1) void k_gemm1_fast(
    const unsigned short* __restrict__ xb, const unsigned short* __restrict__ W1T,
    const int* __restrict__ offs, const int* __restrict__ tiletab256,
    const int* __restrict__ rows, unsigned short* __restrict__ act) {
    const int ti = (blockIdx.x & 7) * (NT256 / 8) + (blockIdx.x >> 3);  // XCD swizzle
    const int tt = tiletab256[ti];
    if (tt < 0) return;
    const int e = tt >> 16, m0 = (tt & 0xffff) << 8;
    const int off = offs[e], n_e = offs[e + 1] - off;
    const int by = blockIdx.y;   // 0..5

    __shared__ unsigned short SA[2 * 2 * 256 * 32];
    __shared__ unsigned short SB[2 * 2 * 256 * 32];

    const int tid = threadIdx.x;
    const int wid = tid >> 6, lane = tid & 63;
    const int l15 = lane & 15, kq = lane >> 4;
    const int wm = wid >> 2, wn = wid & 3;
    const int row_lo = tid >> 2;                             // staging row (+j*128)
    const int esw = (((tid & 3) ^ ((tid >> 3) & 3)) << 3);   // swizzled src elem off
    const int rk = ((kq ^ ((l15 >> 1) & 3)) << 3);           // swizzled read elem off

    int tok[2];
    size_t bB[2];
#pragma unroll
    for (int j = 0; j < 2; ++j) {
        int s = m0 + j * 128 + row_lo;
        s = (s < n_e) ? s : (n_e - 1);
        tok[j] = rows[off + s];
        bB[j] = ((size_t)e * (2 * H_DIM) + by * 256 + j * 128 + row_lo) * D_DIM + esw;
    }

    f32x4 acc[8][4];
#pragma unroll
    for (int m = 0; m < 8; ++m)
#pragma unroll
        for (int n = 0; n < 4; ++n)
#pragma unroll
            for (int r = 0; r < 4; ++r) acc[m][n][r] = 0.f;

    auto STAGE_A = [&](int sl, int ks, int t) {   // one 16 KB half: 2 glds/thread
#pragma unroll
        for (int j = 0; j < 2; ++j) {
            const unsigned short* ga = xb + (size_t)tok[j] * D_DIM + t * 64 + ks * 32 + esw;
            __builtin_amdgcn_global_load_lds((gas_t)ga,
                (las_t)((char*)SA + ((sl * 2 + ks) * 256 + j * 128) * 64 + tid * 16), 16, 0, 0);
        }
    };
    auto STAGE_B = [&](int sl, int ks, int t) {
#pragma unroll
        for (int j = 0; j < 2; ++j) {
            const unsigned short* gb = W1T + bB[j] + t * 64 + ks * 32;
            __builtin_amdgcn_global_load_lds((gas_t)gb,
                (las_t)((char*)SB + ((sl * 2 + ks) * 256 + j * 128) * 64 + tid * 16), 16, 0, 0);
        }
    };

    // prologue: full tile 0, wait its k-half0, barrier
    STAGE_A(0, 0, 0); STAGE_B(0, 0, 0); STAGE_A(0, 1, 0); STAGE_B(0, 1, 0);
    asm volatile("s_waitcnt vmcnt(4)" ::: "memory");
    asm volatile("" ::: "memory");
    __builtin_amdgcn_s_barrier();

    const int NTILE = D_DIM / 64;   // 16
    bf16x8 a[4], b[4];
    for (int t = 0; t < NTILE; ++t) {
        const int sl = t & 1, sn = sl ^ 1;
        const int tn = t + 1;
        const bool st = (tn < NTILE);
        // ---- phase 0: ks=0 mg=0 ; stage A-h0(t+1) ----
        LDB4(sl, 0);
        LDA4(sl, 0, 0);
        if (st) STAGE_A(sn, 0, tn);
        PH_OPEN();
        MM4(0);
        PH_CLOSE();
        // ---- phase 1: ks=0 mg=1 ; stage B-h0(t+1) ; vmcnt -> k-half1 ready ----
        LDA4(sl, 0, 1);
        if (st) STAGE_B(sn, 0, tn);
        PH_OPEN();
        MM4(4);
        __builtin_amdgcn_s_setprio(0);
        if (st) { asm volatile("s_waitcnt vmcnt(4)" ::: "memory"); }
        else    { asm volatile("s_waitcnt vmcnt(0)" ::: "memory"); }
        asm volatile("" ::: "memory");
        __builtin_amdgcn_s_barrier();
        // ---- phase 2: ks=1 mg=0 ; stage A-h1(t+1) ----
        LDB4(sl, 1);
        LDA4(sl, 1, 0);
        if (st) STAGE_A(sn, 1, tn);
        PH_OPEN();
        MM4(0);
        PH_CLOSE();
        // ---- phase 3: ks=1 mg=1 ; stage B-h1(t+1) ; vmcnt -> next tile h0 ready ----
        LDA4(sl, 1, 1);
        if (st) STAGE_B(sn, 1, tn);
        PH_OPEN();
        MM4(4);
        __builtin_amdgcn_s_setprio(0);
        if (st) { asm volatile("s_waitcnt vmcnt(4)" ::: "memory"); }
        asm volatile("" ::: "memory");
        __builtin_amdgcn_s_barrier();
    }
    // epilogue: silu-gate; frag n<2 = v-cols, n>=2 = paired g-cols
#pragma unroll
    for (int m = 0; m < 8; ++m)
#pragma unroll
        for (int r = 0; r < 4; ++r) {
            const int row = wm * 128 + m * 16 + kq * 4 + r;
            if (m0 + row < n_e) {
#pragma unroll
                for (int nv = 0; nv < 2; ++nv) {
                    const int col = by * 128 + wn * 32 + nv * 16 + l15;
                    const float vv = acc[m][nv][r], gg = acc[m][2 + nv][r];
                    const float s = gg / (1.0f + __expf(-gg));
                    act[(size_t)(off + m0 + row) * H_DIM + col] = f2b(vv * s);
                }
            }
        }
}

__global__ __launch_bounds__(512, 1) void k_gemm2_fast(
    const unsigned short* __restrict__ act, const unsigned short* __restrict__ W2T,
    const int* __restrict__ offs, const int* __restrict__ tiletab256,
    const float* __restrict__ wslot, unsigned short* __restrict__ slot_out) {
    const int ti = (blockIdx.x & 7) * (NT256 / 8) + (blockIdx.x >> 3);
    const int tt = tiletab256[ti];
    if (tt < 0) return;
    const int e = tt >> 16, m0 = (tt & 0xffff) << 8;
    const int off = offs[e], n_e = offs[e + 1] - off;
    const int by = blockIdx.y;   // 0..3

    __shared__ unsigned short SA[2 * 2 * 256 * 32];
    __shared__ unsigned short SB[2 * 2 * 256 * 32];

    const int tid = threadIdx.x;
    const int wid = tid >> 6, lane = tid & 63;
    const int l15 = lane & 15, kq = lane >> 4;
    const int wm = wid >> 2, wn = wid & 3;
    const int row_lo = tid >> 2;
    const int esw = (((tid & 3) ^ ((tid >> 3) & 3)) << 3);
    const int rk = ((kq ^ ((l15 >> 1) & 3)) << 3);

    int slotA[2];
    size_t bB[2];
#pragma unroll
    for (int j = 0; j < 2; ++j) {
        int s = m0 + j * 128 + row_lo;
        s = (s < n_e) ? s : (n_e - 1);
        slotA[j] = off + s;
        bB[j] = ((size_t)e * D_DIM + by * 256 + j * 128 + row_lo) * H_DIM + esw;
    }

    f32x4 acc[8][4];
#pragma unroll
    for (int m = 0; m < 8; ++m)
#pragma unroll
        for (int n = 0; n < 4; ++n)
#pragma unroll
            for (int r = 0; r < 4; ++r) acc[m][n][r] = 0.f;

    auto STAGE_A = [&](int sl, int ks, int t) {
#pragma unroll
        for (int j = 0; j < 2; ++j) {
            const unsigned short* ga = act + (size_t)slotA[j] * H_DIM + t * 64 + ks * 32 + esw;
            __builtin_amdgcn_global_load_lds((gas_t)ga,
                (las_t)((char*)SA + ((sl * 2 + ks) * 256 + j * 128) * 64 + tid * 16), 16, 0, 0);
        }
    };
    auto STAGE_B = [&](int sl, int ks, int t) {
#pragma unroll
        for (int j = 0; j < 2; ++j) {
            const unsigned short* gb = W2T + bB[j] + t * 64 + ks * 32;
            __builtin_amdgcn_global_load_lds((gas_t)gb,
                (las_t)((char*)SB + ((sl * 2 + ks) * 256 + j * 128) * 64 + tid * 16), 16, 0, 0);
        }
    };

    STAGE_A(0, 0, 0); STAGE_B(0, 0, 0); STAGE_A(0, 1, 0); STAGE_B(0, 1, 0);
    asm volatile("s_waitcnt vmcnt(4)" ::: "memory");
    asm volatile("" ::: "memory");
    __builtin_amdgcn_s_barrier();

    const int NTILE = H_DIM / 64;   // 12
    bf16x8 a[4], b[4];
    for (int t = 0; t < NTILE; ++t) {
        const int sl = t & 1, sn = sl ^ 1;
        const int tn = t + 1;
        const bool st = (tn < NTILE);
        LDB4(sl, 0);
        LDA4(sl, 0, 0);
        if (st) STAGE_A(sn, 0, tn);
        PH_OPEN();
        MM4(0);
        PH_CLOSE();
        LDA4(sl, 0, 1);
        if (st) STAGE_B(sn, 0, tn);
        PH_OPEN();
        MM4(4);
        __builtin_amdgcn_s_setprio(0);
        if (st) { asm volatile("s_waitcnt vmcnt(4)" ::: "memory"); }
        else    { asm volatile("s_waitcnt vmcnt(0)" ::: "memory"); }
        asm volatile("" ::: "memory");
        __builtin_amdgcn_s_barrier();
        LDB4(sl, 1);
        LDA4(sl, 1, 0);
        if (st) STAGE_A(sn, 1, tn);
        PH_OPEN();
        MM4(0);
        PH_CLOSE();
        LDA4(sl, 1, 1);
        if (st) STAGE_B(sn, 1, tn);
        PH_OPEN();
        MM4(4);
        __builtin_amdgcn_s_setprio(0);
        if (st) { asm volatile("s_waitcnt vmcnt(4)" ::: "memory"); }
        asm volatile("" ::: "memory");
        __builtin_amdgcn_s_barrier();
    }
#pragma unroll
    for (int m = 0; m < 8; ++m)
#pragma unroll
        for (int r = 0; r < 4; ++r) {
            const int row = wm * 128 + m * 16 + kq * 4 + r;
            if (m0 + row < n_e) {
                const int slot = off + m0 + row;
                const float w = wslot[slot];
#pragma unroll
                for (int n = 0; n < 4; ++n) {
                    const int col = by * 256 + wn * 64 + n * 16 + l15;
                    slot_out[(size_t)slot * D_DIM + col] = f2b(w * acc[m][n][r]);
                }
            }
        }
}

// ================= FALLBACK PATH (small ws) =================
__global__ __launch_bounds__(256) void k_gather(const float* __restrict__ x,
                                                const int* __restrict__ rows,
                                                unsigned short* __restrict__ xg) {
    const int s = blockIdx.x, t = threadIdx.x;
    const int tok = rows[s];
    const float4 v = *reinterpret_cast<const float4*>(&x[(size_t)tok * D_DIM + t * 4]);
    ushort4 u;
    u.x = f2b(v.x); u.y = f2b(v.y); u.z = f2b(v.z); u.w = f2b(v.w);
    *reinterpret_cast<ushort4*>(&xg[(size_t)s * D_DIM + t * 4]) = u;
}

__global__ __launch_bounds__(256) void k_gemm1_fb(
    const unsigned short* __restrict__ xg, const float* __restrict__ W1,
    const int* __restrict__ offs, const int* __restrict__ tiletab,
    unsigned short* __restrict__ act) {
    const int tt = tiletab[blockIdx.x];
    if (tt < 0) return;
    const int e = tt >> 16, m0 = (tt & 0xffff) << 7;
    const int off = offs[e], n_e = offs[e + 1] - off;
    const int h0 = blockIdx.y * 64;

    __shared__ unsigned short Ab[128 * 64];
    __shared__ unsigned short Bb[128 * 66];

    const int tid = threadIdx.x;
    const int wid = tid >> 6, lane = tid & 63;
    const int l15 = lane & 15, kq = lane >> 4;

    f32x4 acc[2][8];
#pragma unroll
    for (int m = 0; m < 2; ++m)
#pragma unroll
        for (int n = 0; n < 8; ++n)
#pragma unroll
            for (int r = 0; r < 4; ++r) acc[m][n][r] = 0.f;

    for (int k0 = 0; k0 < D_DIM; k0 += 64) {
        __syncthreads();
#pragma unroll
        for (int j = 0; j < 4; ++j) {
            const int o = wid * 4096 + j * 1024 + lane * 16;
            const int row = o >> 7, kb = o & 127;
            int gr = off + m0 + row; gr = (gr < TK) ? gr : (TK - 1);
            const unsigned short* gp = xg + (size_t)gr * D_DIM + k0 + (kb >> 1);
            __builtin_amdgcn_global_load_lds((gas_t)gp,
                (las_t)((char*)Ab + wid * 4096 + j * 1024), 16, 0, 0);
        }
        {
            const float* W1e = W1 + (size_t)e * D_DIM * (2 * H_DIM);
#pragma unroll
            for (int i = 0; i < 8; ++i) {
                const int flat = tid + 256 * i;
                const int cg = flat & 31, kk = flat >> 5;
                const int cc = cg * 4;
                const int gc = (cc < 64) ? (h0 + cc) : (H_DIM + h0 + cc - 64);
                const float4 v = *reinterpret_cast<const float4*>(
                    &W1e[(size_t)(k0 + kk) * (2 * H_DIM) + gc]);
                Bb[(cc + 0) * 66 + kk] = f2b(v.x);
                Bb[(cc + 1) * 66 + kk] = f2b(v.y);
                Bb[(cc + 2) * 66 + kk] = f2b(v.z);
                Bb[(cc + 3) * 66 + kk] = f2b(v.w);
            }
        }
        __syncthreads();
#pragma unroll
        for (int ks = 0; ks < 2; ++ks) {
            bf16x8 a[2], b[8];
#pragma unroll
            for (int m = 0; m < 2; ++m)
                a[m] = __builtin_bit_cast(bf16x8, *reinterpret_cast<const u16x8*>(
                    &Ab[(wid * 32 + m * 16 + l15) * 64 + ks * 32 + kq * 8]));
#pragma unroll
            for (int n = 0; n < 8; ++n)
                b[n] = __builtin_bit_cast(bf16x8, *reinterpret_cast<const u16x8*>(
                    &Bb[(n * 16 + l15) * 66 + ks * 32 + kq * 8]));
#pragma unroll
            for (int m = 0; m < 2; ++m)
#pragma unroll
                for (int n = 0; n < 8; ++n)
                    acc[m][n] = __builtin_amdgcn_mfma_f32_16x16x32_bf16(a[m], b[n], acc[m][n], 0, 0, 0);
        }
    }
#pragma unroll
    for (int m = 0; m < 2; ++m)
#pragma unroll
        for (int n = 0; n < 4; ++n)
#pragma unroll
            for (int r = 0; r < 4; ++r) {
                const int row = wid * 32 + m * 16 + kq * 4 + r;
                if (m0 + row < n_e) {
                    const float vv = acc[m][n][r], gg = acc[m][n + 4][r];
                    const float s = gg / (1.0f + __expf(-gg));
                    act[(size_t)(off + m0 + row) * H_DIM + h0 + n * 16 + l15] = f2b(vv * s);
                }
            }
}

__global__ __launch_bounds__(256) void k_gemm2_fb(
    const unsigned short* __restrict__ act, const float* __restrict__ W2,
    const int* __restrict__ offs, const int* __restrict__ tiletab,
    const float* __restrict__ wslot, unsigned short* __restrict__ slot_out,
    float* __restrict__ y, const int* __restrict__ rows, int atomic_mode) {
    const int tt = tiletab[blockIdx.x];
    if (tt < 0) return;
    const int e = tt >> 16, m0 = (tt & 0xffff) << 7;
    const int off = offs[e], n_e = offs[e + 1] - off;
    const int n0 = blockIdx.y * 64;

    __shared__ unsigned short Ab[128 * 64];
    __shared__ unsigned short Bb[64 * 66];

    const int tid = threadIdx.x;
    const int wid = tid >> 6, lane = tid & 63;
    const int l15 = lane & 15, kq = lane >> 4;

    f32x4 acc[2][4];
#pragma unroll
    for (int m = 0; m < 2; ++m)
#pragma unroll
        for (int n = 0; n < 4; ++n)
#pragma unroll
            for (int r = 0; r < 4; ++r) acc[m][n][r] = 0.f;

    for (int k0 = 0; k0 < H_DIM; k0 += 64) {
        __syncthreads();
#pragma unroll
        for (int j = 0; j < 4; ++j) {
            const int o = wid * 4096 + j * 1024 + lane * 16;
            const int row = o >> 7, kb = o & 127;
            int gr = off + m0 + row; gr = (gr < TK) ? gr : (TK - 1);
            const unsigned short* gp = act + (size_t)gr * H_DIM + k0 + (kb >> 1);
            __builtin_amdgcn_global_load_lds((gas_t)gp,
                (las_t)((char*)Ab + wid * 4096 + j * 1024), 16, 0, 0);
        }
        {
            const float* W2e = W2 + (size_t)e * H_DIM * D_DIM;
#pragma unroll
            for (int i = 0; i < 4; ++i) {
                const int flat = tid + 256 * i;
                const int cg = flat & 15, kk = flat >> 4;
                const int cc = cg * 4;
                const float4 v = *reinterpret_cast<const float4*>(
                    &W2e[(size_t)(k0 + kk) * D_DIM + n0 + cc]);
                Bb[(cc + 0) * 66 + kk] = f2b(v.x);
                Bb[(cc + 1) * 66 + kk] = f2b(v.y);
                Bb[(cc + 2) * 66 + kk] = f2b(v.z);
                Bb[(cc + 3) * 66 + kk] = f2b(v.w);
            }
        }
        __syncthreads();
#pragma unroll
        for (int ks = 0; ks < 2; ++ks) {
            bf16x8 a[2], b[4];
#pragma unroll
            for (int m = 0; m < 2; ++m)
                a[m] = __builtin_bit_cast(bf16x8, *reinterpret_cast<const u16x8*>(
                    &Ab[(wid * 32 + m * 16 + l15) * 64 + ks * 32 + kq * 8]));
#pragma unroll
            for (int n = 0; n < 4; ++n)
                b[n] = __builtin_bit_cast(bf16x8, *reinterpret_cast<const u16x8*>(
                    &Bb[(n * 16 + l15) * 66 + ks * 32 + kq * 8]));
#pragma unroll
            for (int m = 0; m < 2; ++m)
#pragma unroll
                for (int n = 0; n < 4; ++n)
                    acc[m][n] = __builtin_amdgcn_mfma_f32_16x16x32_bf16(a[m], b[n], acc[m][n], 0, 0, 0);
        }
    }
#pragma unroll
    for (int m = 0; m < 2; ++m)
#pragma unroll
        for (int r = 0; r < 4; ++r) {
            const int row = wid * 32 + m * 16 + kq * 4 + r;
            if (m0 + row < n_e) {
                const int slot = off + m0 + row;
                const float w = wslot[slot];
#pragma unroll
                for (int n = 0; n < 4; ++n) {
                    const float o = w * acc[m][n][r];
                    if (atomic_mode)
                        atomicAdd(&y[(size_t)rows[slot] * D_DIM + n0 + n * 16 + l15], o);
                    else
                        slot_out[(size_t)slot * D_DIM + n0 + n * 16 + l15] = f2b(o);
                }
            }
        }
}

// ---------------- combine ----------------
__global__ __launch_bounds__(256) void k_combine(
    const unsigned short* __restrict__ slot_out, const int* __restrict__ slot_of,
    float* __restrict__ y) {
    const int t = blockIdx.x;
    const int d = threadIdx.x * 4;
    const int s0 = slot_of[2 * t], s1 = slot_of[2 * t + 1];
    const ushort4 a = *reinterpret_cast<const ushort4*>(&slot_out[(size_t)s0 * D_DIM + d]);
    const ushort4 b = *reinterpret_cast<const ushort4*>(&slot_out[(size_t)s1 * D_DIM + d]);
    float4 r;
    r.x = b2f(a.x) + b2f(b.x);
    r.y = b2f(a.y) + b2f(b.y);
    r.z = b2f(a.z) + b2f(b.z);
    r.w = b2f(a.w) + b2f(b.w);
    *reinterpret_cast<float4*>(&y[(size_t)t * D_DIM + d]) = r;
}

extern "C" void kernel_launch(void* const* d_in, const int* in_sizes, int n_in,
                              void* d_out, int out_size, void* d_ws, size_t ws_size,
                              hipStream_t stream) {
    const float* x = (const float*)d_in[0];
    const float* wts = (const float*)d_in[1];
    const int* idx = (const int*)d_in[2];
    const float* W1 = (const float*)d_in[4];
    const float* W2 = (const float*)d_in[5];
    float* y = (float*)d_out;

    char* ws = (char*)d_ws;
    int* offs = (int*)(ws + 128);
    int* tiletab = (int*)(ws + 320);
    int* tiletab256 = (int*)(ws + 1024);
    int* rows = (int*)(ws + 2048);
    float* wslot = (float*)(ws + 2048 + (size_t)TK * 4);
    int* slot_of = (int*)(ws + 2048 + (size_t)TK * 8);
    const size_t OFF_XG = 2048 + (size_t)TK * 12;
    unsigned short* xg = (unsigned short*)(ws + OFF_XG);
    unsigned short* xb = xg;
    const size_t OFF_ACT = OFF_XG + (size_t)TK * D_DIM * 2;
    unsigned short* act = (unsigned short*)(ws + OFF_ACT);
    const size_t OFF_SO = OFF_ACT + (size_t)TK * H_DIM * 2;
    unsigned short* slot_out = (unsigned short*)(ws + OFF_SO);
    const size_t MID_END = OFF_SO + (size_t)TK * D_DIM * 2;
    const size_t OFF_W1T = MID_END;
    unsigned short* W1T = (unsigned short*)(ws + OFF_W1T);
    const size_t OFF_W2T = OFF_W1T + (size_t)E_EXP * 2 * H_DIM * D_DIM * 2;
    unsigned short* W2T = (unsigned short*)(ws + OFF_W2T);
    const size_t FULL_END = OFF_W2T + (size_t)E_EXP * D_DIM * H_DIM * 2;

    const int full = (ws_size >= FULL_END) ? 1 : 0;
    const int atomic_mode = (!full && ws_size < MID_END) ? 1 : 0;

    k_route<<<1, 1024, 0, stream>>>(idx, wts, offs, tiletab, tiletab256, rows, wslot, slot_of);

    if (full) {
        k_prep<<<PREP_W2, 256, 0, stream>>>(x, W1, W2, xb, W1T, W2T);
        dim3 g1(NT256, H_DIM / 128);
        k_gemm1_fast<<<g1, 512, 0, stream>>>(xb, W1T, offs, tiletab256, rows, act);
        dim3 g2(NT256, D_DIM / 256);
        k_gemm2_fast<<<g2, 512, 0, stream>>>(act, W2T, offs, tiletab256, wslot, slot_out);
        k_combine<<<T_TOK, 256, 0, stream>>>(slot_out, slot_of, y);
    } else {
        k_gather<<<TK, 256, 0, stream>>>(x, rows, xg);
        dim3 g1(NT128, H_DIM / 64);
        k_gemm1_fb<<<g1, 256, 0, stream>>>(xg, W1, offs, tiletab, act);
        if (atomic_mode) hipMemsetAsync(y, 0, (size_t)out_size * 4, stream);
        dim3 g2(NT128, D_DIM / 64);
        k_gemm2_fb<<<g2, 256, 0, stream>>>(act, W2, offs, tiletab, wslot, slot_out, y, rows, atomic_mode);
        if (!atomic_mode)
            k_combine<<<T_TOK, 256, 0, stream>>>(slot_out, slot_of, y);
    }
}

// Round 7
// 212.231 us; speedup vs baseline: 4.2794x; 1.1540x over previous
//
#include <hip/hip_runtime.h>
#include <hip/hip_bf16.h>

#define T_TOK 8192
#define D_DIM 1024
#define H_DIM 768
#define E_EXP 16
#define K_TOP 2
#define TK (T_TOK * K_TOP)
#define NT128 144
#define NT256 80

typedef __bf16 bf16x8 __attribute__((ext_vector_type(8)));
typedef unsigned short u16x8 __attribute__((ext_vector_type(8)));
typedef float f32x4 __attribute__((ext_vector_type(4)));

typedef const __attribute__((address_space(1))) void* gas_t;
typedef __attribute__((address_space(3))) void* las_t;

__device__ __forceinline__ unsigned short f2b(float f) {
    __hip_bfloat16 h = __float2bfloat16(f);
    return __builtin_bit_cast(unsigned short, h);
}
__device__ __forceinline__ float b2f(unsigned short u) {
    unsigned int x = ((unsigned int)u) << 16;
    return __builtin_bit_cast(float, x);
}

// ---------------- fused routing: count + scan + scatter (1 block) ----------------
__global__ __launch_bounds__(1024) void k_route(
    const int* __restrict__ idx, const float* __restrict__ wts,
    int* __restrict__ offs, int* __restrict__ tiletab,
    int* __restrict__ rows, float* __restrict__ wslot, int* __restrict__ slot_of) {
    __shared__ int lcnt[E_EXP];
    __shared__ int lcur[E_EXP];
    const int tid = threadIdx.x;
    if (tid < E_EXP) lcnt[tid] = 0;
    __syncthreads();
    for (int i = tid; i < TK; i += 1024) atomicAdd(&lcnt[idx[i]], 1);
    __syncthreads();
    if (tid == 0) {
        int s = 0, nt = 0;
        for (int e = 0; e < E_EXP; ++e) {
            offs[e] = s;
            lcur[e] = s;
            const int n = lcnt[e];
            for (int m0 = 0; m0 < n; m0 += 128) tiletab[nt++] = (e << 16) | (m0 >> 7);
            s += n;
        }
        offs[E_EXP] = s;
        for (int i = nt; i < NT128; ++i) tiletab[i] = -1;
    }
    __syncthreads();
    for (int i = tid; i < TK; i += 1024) {
        const int e = idx[i];
        const int p = atomicAdd(&lcur[e], 1);
        rows[p] = i >> 1;          // K_TOP == 2
        wslot[p] = wts[i];
        slot_of[i] = p;
    }
}

// ---------------- fused prep: cast x + transpose/cast W1,W2 (full path) ----------------
#define PREP_X T_TOK
#define PREP_W1 (PREP_X + (D_DIM / 64) * ((2 * H_DIM) / 64) * E_EXP)
#define PREP_W2 (PREP_W1 + (H_DIM / 64) * (D_DIM / 64) * E_EXP)

__global__ __launch_bounds__(256) void k_prep(
    const float* __restrict__ x, const float* __restrict__ W1, const float* __restrict__ W2,
    unsigned short* __restrict__ xb, unsigned short* __restrict__ W1T,
    unsigned short* __restrict__ W2T) {
    const int b = blockIdx.x;
    const int tid = threadIdx.x;
    if (b < PREP_X) {
        const int d = tid * 4;
        const float4 v = *reinterpret_cast<const float4*>(&x[(size_t)b * D_DIM + d]);
        ushort4 u;
        u.x = f2b(v.x); u.y = f2b(v.y); u.z = f2b(v.z); u.w = f2b(v.w);
        *reinterpret_cast<ushort4*>(&xb[(size_t)b * D_DIM + d]) = u;
        return;
    }
    __shared__ float t4[64][65];
    const float* src; unsigned short* dst; int K, C, e, kb, cb, pack;
    if (b < PREP_W1) {
        const int q = b - PREP_X;
        K = D_DIM; C = 2 * H_DIM; pack = 1;
        e = q / ((K / 64) * (C / 64));
        const int r = q % ((K / 64) * (C / 64));
        kb = (r % (K / 64)) * 64; cb = (r / (K / 64)) * 64;
        src = W1; dst = W1T;
    } else {
        const int q = b - PREP_W1;
        K = H_DIM; C = D_DIM; pack = 0;
        e = q / ((K / 64) * (C / 64));
        const int r = q % ((K / 64) * (C / 64));
        kb = (r % (K / 64)) * 64; cb = (r / (K / 64)) * 64;
        src = W2; dst = W2T;
    }
    const float* s = src + ((size_t)e * K + kb) * C + cb;
#pragma unroll
    for (int i = 0; i < 4; ++i) {
        const int kk = (tid >> 4) + i * 16, c4 = (tid & 15) * 4;
        const float4 v = *reinterpret_cast<const float4*>(&s[(size_t)kk * C + c4]);
        t4[kk][c4] = v.x; t4[kk][c4 + 1] = v.y; t4[kk][c4 + 2] = v.z; t4[kk][c4 + 3] = v.w;
    }
    __syncthreads();
#pragma unroll
    for (int i = 0; i < 4; ++i) {
        const int cc = (tid >> 4) + i * 16, k4 = (tid & 15) * 4;
        const int j = cb + cc;
        int drow;
        if (pack) drow = (j < H_DIM) ? ((j >> 5) * 64 + (j & 31))
                                     : (((j - H_DIM) >> 5) * 64 + 32 + ((j - H_DIM) & 31));
        else drow = j;
        ushort4 u;
        u.x = f2b(t4[k4][cc]); u.y = f2b(t4[k4 + 1][cc]);
        u.z = f2b(t4[k4 + 2][cc]); u.w = f2b(t4[k4 + 3][cc]);
        *reinterpret_cast<ushort4*>(&dst[((size_t)e * C + drow) * K + kb + k4]) = u;
    }
}

// ================= FAST PATH: BM=128, BK=32, 48 KiB LDS dbuf, 2 blocks/CU =================
// 8 waves (2m x 4n), per-wave 64x64 output, acc[4][4] (64 regs).
// Swizzle (involution, proven 0-conflict r5/r6): 16B chunk ^= (row>>1)&3,
// pre-swizzled on the GLOBAL source (linear LDS dest, rule #21), same XOR on reads.
// Simple r4 loop: stage(t+1) -> ds_read + 16 MFMA -> one __syncthreads.
// Occupancy (2 blocks/CU) provides the cross-block overlap that hides the
// barrier's vmcnt drain (m114 regime) -- r6 showed lockstep 1-block/CU cannot.

__global__ __launch_bounds__(512, 2) void k_gemm1_fast(
    const unsigned short* __restrict__ xb, const unsigned short* __restrict__ W1T,
    const int* __restrict__ offs, const int* __restrict__ tiletab,
    const int* __restrict__ rows, unsigned short* __restrict__ act) {
    const int ti = (blockIdx.x & 7) * (NT128 / 8) + (blockIdx.x >> 3);  // XCD swizzle (144%8==0)
    const int tt = tiletab[ti];
    if (tt < 0) return;
    const int e = tt >> 16, m0 = (tt & 0xffff) << 7;
    const int off = offs[e], n_e = offs[e + 1] - off;
    const int by = blockIdx.y;   // 0..5 (128 act cols = 256 packed W1T rows)

    __shared__ unsigned short SA[2][128 * 32];   // 16 KiB
    __shared__ unsigned short SB[2][256 * 32];   // 32 KiB

    const int tid = threadIdx.x;
    const int wid = tid >> 6, lane = tid & 63;
    const int l15 = lane & 15, kq = lane >> 4;
    const int wm = wid >> 2, wn = wid & 3;
    const int srow = tid >> 2;                               // 0..127
    const int esw = (((tid & 3) ^ ((tid >> 3) & 3)) << 3);   // swizzled src elem off
    const int rk = ((kq ^ ((l15 >> 1) & 3)) << 3);           // swizzled read elem off

    int tok;
    { int s = m0 + srow; s = (s < n_e) ? s : (n_e - 1); tok = rows[off + s]; }
    size_t bB[2];
#pragma unroll
    for (int j = 0; j < 2; ++j)
        bB[j] = ((size_t)e * (2 * H_DIM) + by * 256 + j * 128 + srow) * D_DIM + esw;

    f32x4 acc[4][4];
#pragma unroll
    for (int m = 0; m < 4; ++m)
#pragma unroll
        for (int n = 0; n < 4; ++n)
#pragma unroll
            for (int r = 0; r < 4; ++r) acc[m][n][r] = 0.f;

    auto stage = [&](int buf, int k0) {
        const unsigned short* ga = xb + (size_t)tok * D_DIM + k0 + esw;
        __builtin_amdgcn_global_load_lds((gas_t)ga,
            (las_t)((char*)&SA[buf][0] + tid * 16), 16, 0, 0);
#pragma unroll
        for (int j = 0; j < 2; ++j) {
            const unsigned short* gb = W1T + bB[j] + k0;
            __builtin_amdgcn_global_load_lds((gas_t)gb,
                (las_t)((char*)&SB[buf][0] + j * 8192 + tid * 16), 16, 0, 0);
        }
    };

    stage(0, 0);
    __syncthreads();
    int c = 0;
    const int NT = D_DIM / 32;   // 32
    for (int t = 0; t < NT; ++t) {
        if (t + 1 < NT) stage(c ^ 1, (t + 1) * 32);
        bf16x8 a[4], b[4];
#pragma unroll
        for (int m = 0; m < 4; ++m) {
            const int row = wm * 64 + m * 16 + l15;
            a[m] = __builtin_bit_cast(bf16x8, *reinterpret_cast<const u16x8*>(
                &SA[c][row * 32 + rk]));
        }
#pragma unroll
        for (int n = 0; n < 4; ++n) {
            const int row = wn * 64 + n * 16 + l15;
            b[n] = __builtin_bit_cast(bf16x8, *reinterpret_cast<const u16x8*>(
                &SB[c][row * 32 + rk]));
        }
#pragma unroll
        for (int m = 0; m < 4; ++m)
#pragma unroll
            for (int n = 0; n < 4; ++n)
                acc[m][n] = __builtin_amdgcn_mfma_f32_16x16x32_bf16(a[m], b[n], acc[m][n], 0, 0, 0);
        __syncthreads();
        c ^= 1;
    }
    // epilogue: silu-gate; frag n<2 = v-cols, n>=2 = paired g-cols
#pragma unroll
    for (int m = 0; m < 4; ++m)
#pragma unroll
        for (int r = 0; r < 4; ++r) {
            const int row = wm * 64 + m * 16 + kq * 4 + r;
            if (m0 + row < n_e) {
#pragma unroll
                for (int nv = 0; nv < 2; ++nv) {
                    const int col = by * 128 + wn * 32 + nv * 16 + l15;
                    const float vv = acc[m][nv][r], gg = acc[m][2 + nv][r];
                    const float s = gg / (1.0f + __expf(-gg));
                    act[(size_t)(off + m0 + row) * H_DIM + col] = f2b(vv * s);
                }
            }
        }
}

__global__ __launch_bounds__(512, 2) void k_gemm2_fast(
    const unsigned short* __restrict__ act, const unsigned short* __restrict__ W2T,
    const int* __restrict__ offs, const int* __restrict__ tiletab,
    const float* __restrict__ wslot, unsigned short* __restrict__ slot_out) {
    const int ti = (blockIdx.x & 7) * (NT128 / 8) + (blockIdx.x >> 3);
    const int tt = tiletab[ti];
    if (tt < 0) return;
    const int e = tt >> 16, m0 = (tt & 0xffff) << 7;
    const int off = offs[e], n_e = offs[e + 1] - off;
    const int by = blockIdx.y;   // 0..3 (256 output cols)

    __shared__ unsigned short SA[2][128 * 32];
    __shared__ unsigned short SB[2][256 * 32];

    const int tid = threadIdx.x;
    const int wid = tid >> 6, lane = tid & 63;
    const int l15 = lane & 15, kq = lane >> 4;
    const int wm = wid >> 2, wn = wid & 3;
    const int srow = tid >> 2;
    const int esw = (((tid & 3) ^ ((tid >> 3) & 3)) << 3);
    const int rk = ((kq ^ ((l15 >> 1) & 3)) << 3);

    int slotA;
    { int s = m0 + srow; s = (s < n_e) ? s : (n_e - 1); slotA = off + s; }
    size_t bB[2];
#pragma unroll
    for (int j = 0; j < 2; ++j)
        bB[j] = ((size_t)e * D_DIM + by * 256 + j * 128 + srow) * H_DIM + esw;

    f32x4 acc[4][4];
#pragma unroll
    for (int m = 0; m < 4; ++m)
#pragma unroll
        for (int n = 0; n < 4; ++n)
#pragma unroll
            for (int r = 0; r < 4; ++r) acc[m][n][r] = 0.f;

    auto stage = [&](int buf, int k0) {
        const unsigned short* ga = act + (size_t)slotA * H_DIM + k0 + esw;
        __builtin_amdgcn_global_load_lds((gas_t)ga,
            (las_t)((char*)&SA[buf][0] + tid * 16), 16, 0, 0);
#pragma unroll
        for (int j = 0; j < 2; ++j) {
            const unsigned short* gb = W2T + bB[j] + k0;
            __builtin_amdgcn_global_load_lds((gas_t)gb,
                (las_t)((char*)&SB[buf][0] + j * 8192 + tid * 16), 16, 0, 0);
        }
    };

    stage(0, 0);
    __syncthreads();
    int c = 0;
    const int NT = H_DIM / 32;   // 24
    for (int t = 0; t < NT; ++t) {
        if (t + 1 < NT) stage(c ^ 1, (t + 1) * 32);
        bf16x8 a[4], b[4];
#pragma unroll
        for (int m = 0; m < 4; ++m) {
            const int row = wm * 64 + m * 16 + l15;
            a[m] = __builtin_bit_cast(bf16x8, *reinterpret_cast<const u16x8*>(
                &SA[c][row * 32 + rk]));
        }
#pragma unroll
        for (int n = 0; n < 4; ++n) {
            const int row = wn * 64 + n * 16 + l15;
            b[n] = __builtin_bit_cast(bf16x8, *reinterpret_cast<const u16x8*>(
                &SB[c][row * 32 + rk]));
        }
#pragma unroll
        for (int m = 0; m < 4; ++m)
#pragma unroll
            for (int n = 0; n < 4; ++n)
                acc[m][n] = __builtin_amdgcn_mfma_f32_16x16x32_bf16(a[m], b[n], acc[m][n], 0, 0, 0);
        __syncthreads();
        c ^= 1;
    }
#pragma unroll
    for (int m = 0; m < 4; ++m)
#pragma unroll
        for (int r = 0; r < 4; ++r) {
            const int row = wm * 64 + m * 16 + kq * 4 + r;
            if (m0 + row < n_e) {
                const int slot = off + m0 + row;
                const float w = wslot[slot];
#pragma unroll
                for (int n = 0; n < 4; ++n) {
                    const int col = by * 256 + wn * 64 + n * 16 + l15;
                    slot_out[(size_t)slot * D_DIM + col] = f2b(w * acc[m][n][r]);
                }
            }
        }
}

// ================= FALLBACK PATH (small ws) =================
__global__ __launch_bounds__(256) void k_gather(const float* __restrict__ x,
                                                const int* __restrict__ rows,
                                                unsigned short* __restrict__ xg) {
    const int s = blockIdx.x, t = threadIdx.x;
    const int tok = rows[s];
    const float4 v = *reinterpret_cast<const float4*>(&x[(size_t)tok * D_DIM + t * 4]);
    ushort4 u;
    u.x = f2b(v.x); u.y = f2b(v.y); u.z = f2b(v.z); u.w = f2b(v.w);
    *reinterpret_cast<ushort4*>(&xg[(size_t)s * D_DIM + t * 4]) = u;
}

__global__ __launch_bounds__(256) void k_gemm1_fb(
    const unsigned short* __restrict__ xg, const float* __restrict__ W1,
    const int* __restrict__ offs, const int* __restrict__ tiletab,
    unsigned short* __restrict__ act) {
    const int tt = tiletab[blockIdx.x];
    if (tt < 0) return;
    const int e = tt >> 16, m0 = (tt & 0xffff) << 7;
    const int off = offs[e], n_e = offs[e + 1] - off;
    const int h0 = blockIdx.y * 64;

    __shared__ unsigned short Ab[128 * 64];
    __shared__ unsigned short Bb[128 * 66];

    const int tid = threadIdx.x;
    const int wid = tid >> 6, lane = tid & 63;
    const int l15 = lane & 15, kq = lane >> 4;

    f32x4 acc[2][8];
#pragma unroll
    for (int m = 0; m < 2; ++m)
#pragma unroll
        for (int n = 0; n < 8; ++n)
#pragma unroll
            for (int r = 0; r < 4; ++r) acc[m][n][r] = 0.f;

    for (int k0 = 0; k0 < D_DIM; k0 += 64) {
        __syncthreads();
#pragma unroll
        for (int j = 0; j < 4; ++j) {
            const int o = wid * 4096 + j * 1024 + lane * 16;
            const int row = o >> 7, kb = o & 127;
            int gr = off + m0 + row; gr = (gr < TK) ? gr : (TK - 1);
            const unsigned short* gp = xg + (size_t)gr * D_DIM + k0 + (kb >> 1);
            __builtin_amdgcn_global_load_lds((gas_t)gp,
                (las_t)((char*)Ab + wid * 4096 + j * 1024), 16, 0, 0);
        }
        {
            const float* W1e = W1 + (size_t)e * D_DIM * (2 * H_DIM);
#pragma unroll
            for (int i = 0; i < 8; ++i) {
                const int flat = tid + 256 * i;
                const int cg = flat & 31, kk = flat >> 5;
                const int cc = cg * 4;
                const int gc = (cc < 64) ? (h0 + cc) : (H_DIM + h0 + cc - 64);
                const float4 v = *reinterpret_cast<const float4*>(
                    &W1e[(size_t)(k0 + kk) * (2 * H_DIM) + gc]);
                Bb[(cc + 0) * 66 + kk] = f2b(v.x);
                Bb[(cc + 1) * 66 + kk] = f2b(v.y);
                Bb[(cc + 2) * 66 + kk] = f2b(v.z);
                Bb[(cc + 3) * 66 + kk] = f2b(v.w);
            }
        }
        __syncthreads();
#pragma unroll
        for (int ks = 0; ks < 2; ++ks) {
            bf16x8 a[2], b[8];
#pragma unroll
            for (int m = 0; m < 2; ++m)
                a[m] = __builtin_bit_cast(bf16x8, *reinterpret_cast<const u16x8*>(
                    &Ab[(wid * 32 + m * 16 + l15) * 64 + ks * 32 + kq * 8]));
#pragma unroll
            for (int n = 0; n < 8; ++n)
                b[n] = __builtin_bit_cast(bf16x8, *reinterpret_cast<const u16x8*>(
                    &Bb[(n * 16 + l15) * 66 + ks * 32 + kq * 8]));
#pragma unroll
            for (int m = 0; m < 2; ++m)
#pragma unroll
                for (int n = 0; n < 8; ++n)
                    acc[m][n] = __builtin_amdgcn_mfma_f32_16x16x32_bf16(a[m], b[n], acc[m][n], 0, 0, 0);
        }
    }
#pragma unroll
    for (int m = 0; m < 2; ++m)
#pragma unroll
        for (int n = 0; n < 4; ++n)
#pragma unroll
            for (int r = 0; r < 4; ++r) {
                const int row = wid * 32 + m * 16 + kq * 4 + r;
                if (m0 + row < n_e) {
                    const float vv = acc[m][n][r], gg = acc[m][n + 4][r];
                    const float s = gg / (1.0f + __expf(-gg));
                    act[(size_t)(off + m0 + row) * H_DIM + h0 + n * 16 + l15] = f2b(vv * s);
                }
            }
}

__global__ __launch_bounds__(256) void k_gemm2_fb(
    const unsigned short* __restrict__ act, const float* __restrict__ W2,
    const int* __restrict__ offs, const int* __restrict__ tiletab,
    const float* __restrict__ wslot, unsigned short* __restrict__ slot_out,
    float* __restrict__ y, const int* __restrict__ rows, int atomic_mode) {
    const int tt = tiletab[blockIdx.x];
    if (tt < 0) return;
    const int e = tt >> 16, m0 = (tt & 0xffff) << 7;
    const int off = offs[e], n_e = offs[e + 1] - off;
    const int n0 = blockIdx.y * 64;

    __shared__ unsigned short Ab[128 * 64];
    __shared__ unsigned short Bb[64 * 66];

    const int tid = threadIdx.x;
    const int wid = tid >> 6, lane = tid & 63;
    const int l15 = lane & 15, kq = lane >> 4;

    f32x4 acc[2][4];
#pragma unroll
    for (int m = 0; m < 2; ++m)
#pragma unroll
        for (int n = 0; n < 4; ++n)
#pragma unroll
            for (int r = 0; r < 4; ++r) acc[m][n][r] = 0.f;

    for (int k0 = 0; k0 < H_DIM; k0 += 64) {
        __syncthreads();
#pragma unroll
        for (int j = 0; j < 4; ++j) {
            const int o = wid * 4096 + j * 1024 + lane * 16;
            const int row = o >> 7, kb = o & 127;
            int gr = off + m0 + row; gr = (gr < TK) ? gr : (TK - 1);
            const unsigned short* gp = act + (size_t)gr * H_DIM + k0 + (kb >> 1);
            __builtin_amdgcn_global_load_lds((gas_t)gp,
                (las_t)((char*)Ab + wid * 4096 + j * 1024), 16, 0, 0);
        }
        {
            const float* W2e = W2 + (size_t)e * H_DIM * D_DIM;
#pragma unroll
            for (int i = 0; i < 4; ++i) {
                const int flat = tid + 256 * i;
                const int cg = flat & 15, kk = flat >> 4;
                const int cc = cg * 4;
                const float4 v = *reinterpret_cast<const float4*>(
                    &W2e[(size_t)(k0 + kk) * D_DIM + n0 + cc]);
                Bb[(cc + 0) * 66 + kk] = f2b(v.x);
                Bb[(cc + 1) * 66 + kk] = f2b(v.y);
                Bb[(cc + 2) * 66 + kk] = f2b(v.z);
                Bb[(cc + 3) * 66 + kk] = f2b(v.w);
            }
        }
        __syncthreads();
#pragma unroll
        for (int ks = 0; ks < 2; ++ks) {
            bf16x8 a[2], b[4];
#pragma unroll
            for (int m = 0; m < 2; ++m)
                a[m] = __builtin_bit_cast(bf16x8, *reinterpret_cast<const u16x8*>(
                    &Ab[(wid * 32 + m * 16 + l15) * 64 + ks * 32 + kq * 8]));
#pragma unroll
            for (int n = 0; n < 4; ++n)
                b[n] = __builtin_bit_cast(bf16x8, *reinterpret_cast<const u16x8*>(
                    &Bb[(n * 16 + l15) * 66 + ks * 32 + kq * 8]));
#pragma unroll
            for (int m = 0; m < 2; ++m)
#pragma unroll
                for (int n = 0; n < 4; ++n)
                    acc[m][n] = __builtin_amdgcn_mfma_f32_16x16x32_bf16(a[m], b[n], acc[m][n], 0, 0, 0);
        }
    }
#pragma unroll
    for (int m = 0; m < 2; ++m)
#pragma unroll
        for (int r = 0; r < 4; ++r) {
            const int row = wid * 32 + m * 16 + kq * 4 + r;
            if (m0 + row < n_e) {
                const int slot = off + m0 + row;
                const float w = wslot[slot];
#pragma unroll
                for (int n = 0; n < 4; ++n) {
                    const float o = w * acc[m][n][r];
                    if (atomic_mode)
                        atomicAdd(&y[(size_t)rows[slot] * D_DIM + n0 + n * 16 + l15], o);
                    else
                        slot_out[(size_t)slot * D_DIM + n0 + n * 16 + l15] = f2b(o);
                }
            }
        }
}

// ---------------- combine ----------------
__global__ __launch_bounds__(256) void k_combine(
    const unsigned short* __restrict__ slot_out, const int* __restrict__ slot_of,
    float* __restrict__ y) {
    const int t = blockIdx.x;
    const int d = threadIdx.x * 4;
    const int s0 = slot_of[2 * t], s1 = slot_of[2 * t + 1];
    const ushort4 a = *reinterpret_cast<const ushort4*>(&slot_out[(size_t)s0 * D_DIM + d]);
    const ushort4 b = *reinterpret_cast<const ushort4*>(&slot_out[(size_t)s1 * D_DIM + d]);
    float4 r;
    r.x = b2f(a.x) + b2f(b.x);
    r.y = b2f(a.y) + b2f(b.y);
    r.z = b2f(a.z) + b2f(b.z);
    r.w = b2f(a.w) + b2f(b.w);
    *reinterpret_cast<float4*>(&y[(size_t)t * D_DIM + d]) = r;
}

extern "C" void kernel_launch(void* const* d_in, const int* in_sizes, int n_in,
                              void* d_out, int out_size, void* d_ws, size_t ws_size,
                              hipStream_t stream) {
    const float* x = (const float*)d_in[0];
    const float* wts = (const float*)d_in[1];
    const int* idx = (const int*)d_in[2];
    const float* W1 = (const float*)d_in[4];
    const float* W2 = (const float*)d_in[5];
    float* y = (float*)d_out;

    char* ws = (char*)d_ws;
    int* offs = (int*)(ws + 128);
    int* tiletab = (int*)(ws + 320);
    int* rows = (int*)(ws + 2048);
    float* wslot = (float*)(ws + 2048 + (size_t)TK * 4);
    int* slot_of = (int*)(ws + 2048 + (size_t)TK * 8);
    const size_t OFF_XG = 2048 + (size_t)TK * 12;
    unsigned short* xg = (unsigned short*)(ws + OFF_XG);
    unsigned short* xb = xg;
    const size_t OFF_ACT = OFF_XG + (size_t)TK * D_DIM * 2;
    unsigned short* act = (unsigned short*)(ws + OFF_ACT);
    const size_t OFF_SO = OFF_ACT + (size_t)TK * H_DIM * 2;
    unsigned short* slot_out = (unsigned short*)(ws + OFF_SO);
    const size_t MID_END = OFF_SO + (size_t)TK * D_DIM * 2;
    const size_t OFF_W1T = MID_END;
    unsigned short* W1T = (unsigned short*)(ws + OFF_W1T);
    const size_t OFF_W2T = OFF_W1T + (size_t)E_EXP * 2 * H_DIM * D_DIM * 2;
    unsigned short* W2T = (unsigned short*)(ws + OFF_W2T);
    const size_t FULL_END = OFF_W2T + (size_t)E_EXP * D_DIM * H_DIM * 2;

    const int full = (ws_size >= FULL_END) ? 1 : 0;
    const int atomic_mode = (!full && ws_size < MID_END) ? 1 : 0;

    k_route<<<1, 1024, 0, stream>>>(idx, wts, offs, tiletab, rows, wslot, slot_of);

    if (full) {
        k_prep<<<PREP_W2, 256, 0, stream>>>(x, W1, W2, xb, W1T, W2T);
        dim3 g1(NT128, H_DIM / 128);
        k_gemm1_fast<<<g1, 512, 0, stream>>>(xb, W1T, offs, tiletab, rows, act);
        dim3 g2(NT128, D_DIM / 256);
        k_gemm2_fast<<<g2, 512, 0, stream>>>(act, W2T, offs, tiletab, wslot, slot_out);
        k_combine<<<T_TOK, 256, 0, stream>>>(slot_out, slot_of, y);
    } else {
        k_gather<<<TK, 256, 0, stream>>>(x, rows, xg);
        dim3 g1(NT128, H_DIM / 64);
        k_gemm1_fb<<<g1, 256, 0, stream>>>(xg, W1, offs, tiletab, act);
        if (atomic_mode) hipMemsetAsync(y, 0, (size_t)out_size * 4, stream);
        dim3 g2(NT128, D_DIM / 64);
        k_gemm2_fb<<<g2, 256, 0, stream>>>(act, W2, offs, tiletab, wslot, slot_out, y, rows, atomic_mode);
        if (!atomic_mode)
            k_combine<<<T_TOK, 256, 0, stream>>>(slot_out, slot_of, y);
    }
}

// Round 8
// 208.946 us; speedup vs baseline: 4.3467x; 1.0157x over previous
//
#include <hip/hip_runtime.h>
#include <hip/hip_bf16.h>

#define T_TOK 8192
#define D_DIM 1024
#define H_DIM 768
#define E_EXP 16
#define K_TOP 2
#define TK (T_TOK * K_TOP)
#define NT128 144

typedef __bf16 bf16x8 __attribute__((ext_vector_type(8)));
typedef unsigned short u16x8 __attribute__((ext_vector_type(8)));
typedef float f32x4 __attribute__((ext_vector_type(4)));

typedef const __attribute__((address_space(1))) void* gas_t;
typedef __attribute__((address_space(3))) void* las_t;

__device__ __forceinline__ unsigned short f2b(float f) {
    __hip_bfloat16 h = __float2bfloat16(f);
    return __builtin_bit_cast(unsigned short, h);
}
__device__ __forceinline__ float b2f(unsigned short u) {
    unsigned int x = ((unsigned int)u) << 16;
    return __builtin_bit_cast(float, x);
}

// ---------------- standalone route (fallback path) ----------------
__global__ __launch_bounds__(1024) void k_route(
    const int* __restrict__ idx, const float* __restrict__ wts,
    int* __restrict__ offs, int* __restrict__ tiletab,
    int* __restrict__ rows, float* __restrict__ wslot, int* __restrict__ slot_of) {
    __shared__ int lcnt[E_EXP];
    __shared__ int lcur[E_EXP];
    const int tid = threadIdx.x;
    if (tid < E_EXP) lcnt[tid] = 0;
    __syncthreads();
    for (int i = tid; i < TK; i += 1024) atomicAdd(&lcnt[idx[i]], 1);
    __syncthreads();
    if (tid == 0) {
        int s = 0, nt = 0;
        for (int e = 0; e < E_EXP; ++e) {
            offs[e] = s;
            lcur[e] = s;
            const int n = lcnt[e];
            for (int m0 = 0; m0 < n; m0 += 128) tiletab[nt++] = (e << 16) | (m0 >> 7);
            s += n;
        }
        offs[E_EXP] = s;
        for (int i = nt; i < NT128; ++i) tiletab[i] = -1;
    }
    __syncthreads();
    for (int i = tid; i < TK; i += 1024) {
        const int e = idx[i];
        const int p = atomicAdd(&lcur[e], 1);
        rows[p] = i >> 1;
        wslot[p] = wts[i];
        slot_of[i] = p;
    }
}

// ---------------- fused route + prep (full path) ----------------
// block 0: route (count+scan+scatter, hides under prep BW work)
// blocks [1, 2048]                : x-cast (4 rows/block, 16B stores)
// blocks [2049, 5120]             : W1T (2 64x64 tiles/block, packed v|g rows)
// blocks [5121, 6656]             : W2T (2 tiles/block)
#define PRB_X 2048
#define PRB_W1 3072
#define PRB_W2 1536
#define PRB_TOT (1 + PRB_X + PRB_W1 + PRB_W2)

__global__ __launch_bounds__(512) void k_preproute(
    const float* __restrict__ x, const float* __restrict__ W1, const float* __restrict__ W2,
    const int* __restrict__ idx, const float* __restrict__ wts,
    unsigned short* __restrict__ xb, unsigned short* __restrict__ W1T,
    unsigned short* __restrict__ W2T,
    int* __restrict__ offs, int* __restrict__ tiletab,
    int* __restrict__ rows, float* __restrict__ wslot, int* __restrict__ slot_of) {
    const int b = blockIdx.x;
    const int tid = threadIdx.x;
    if (b == 0) {
        __shared__ int lcnt[E_EXP];
        __shared__ int lcur[E_EXP];
        if (tid < E_EXP) lcnt[tid] = 0;
        __syncthreads();
        for (int i = tid; i < TK; i += 512) atomicAdd(&lcnt[idx[i]], 1);
        __syncthreads();
        if (tid == 0) {
            int s = 0, nt = 0;
            for (int e = 0; e < E_EXP; ++e) {
                offs[e] = s;
                lcur[e] = s;
                const int n = lcnt[e];
                for (int m0 = 0; m0 < n; m0 += 128) tiletab[nt++] = (e << 16) | (m0 >> 7);
                s += n;
            }
            offs[E_EXP] = s;
            for (int i = nt; i < NT128; ++i) tiletab[i] = -1;
        }
        __syncthreads();
        for (int i = tid; i < TK; i += 512) {
            const int e = idx[i];
            const int p = atomicAdd(&lcur[e], 1);
            rows[p] = i >> 1;          // K_TOP == 2
            wslot[p] = wts[i];
            slot_of[i] = p;
        }
        return;
    }
    if (b <= PRB_X) {   // x-cast: 4 rows (4096 elems) per block
        const size_t base = (size_t)(b - 1) * 4096 + (size_t)tid * 8;
        const float4 v0 = *reinterpret_cast<const float4*>(&x[base]);
        const float4 v1 = *reinterpret_cast<const float4*>(&x[base + 4]);
        u16x8 u;
        u[0] = f2b(v0.x); u[1] = f2b(v0.y); u[2] = f2b(v0.z); u[3] = f2b(v0.w);
        u[4] = f2b(v1.x); u[5] = f2b(v1.y); u[6] = f2b(v1.z); u[7] = f2b(v1.w);
        *reinterpret_cast<u16x8*>(&xb[base]) = u;
        return;
    }
    // weight transpose: 2 tiles per block (256 threads each)
    __shared__ float t4[2][64][65];
    const int sub = tid >> 8, t2 = tid & 255;
    const float* src; unsigned short* dst;
    int K, C, e, kb, cb, pack;
    if (b <= PRB_X + PRB_W1) {
        const int q = (b - 1 - PRB_X) * 2 + sub;
        K = D_DIM; C = 2 * H_DIM; pack = 1;
        e = q / 384; const int r = q % 384;
        kb = (r % 16) * 64; cb = (r / 16) * 64;
        src = W1; dst = W1T;
    } else {
        const int q = (b - 1 - PRB_X - PRB_W1) * 2 + sub;
        K = H_DIM; C = D_DIM; pack = 0;
        e = q / 192; const int r = q % 192;
        kb = (r % 12) * 64; cb = (r / 12) * 64;
        src = W2; dst = W2T;
    }
    const float* s = src + ((size_t)e * K + kb) * C + cb;
#pragma unroll
    for (int i = 0; i < 4; ++i) {
        const int kk = (t2 >> 4) + i * 16, c4 = (t2 & 15) * 4;
        const float4 v = *reinterpret_cast<const float4*>(&s[(size_t)kk * C + c4]);
        t4[sub][kk][c4] = v.x; t4[sub][kk][c4 + 1] = v.y;
        t4[sub][kk][c4 + 2] = v.z; t4[sub][kk][c4 + 3] = v.w;
    }
    __syncthreads();
#pragma unroll
    for (int i = 0; i < 2; ++i) {
        const int cc = (t2 >> 3) + i * 32, k8 = (t2 & 7) * 8;
        const int j = cb + cc;
        int drow;
        if (pack) drow = (j < H_DIM) ? ((j >> 5) * 64 + (j & 31))
                                     : (((j - H_DIM) >> 5) * 64 + 32 + ((j - H_DIM) & 31));
        else drow = j;
        u16x8 u;
#pragma unroll
        for (int q8 = 0; q8 < 8; ++q8) u[q8] = f2b(t4[sub][k8 + q8][cc]);
        *reinterpret_cast<u16x8*>(&dst[((size_t)e * C + drow) * K + kb + k8]) = u;
    }
}

// ================= FAST PATH: BM=128, BK=32, 48 KiB dbuf, counted vmcnt =================
// 8 waves (2m x 4n), per-wave 64x64, 2 blocks/CU. Depth-2 prefetch: prologue stages
// tiles 0,1; step t waits vmcnt(3) (stage(t) landed, stage(t+1) in flight), reads slot
// t&1, MFMA, lgkmcnt(0)+barrier, then stages t+2 into the just-read slot. Only the
// last step drains vmcnt(0). Swizzle (involution, 0-conflict proven r5-r7):
// 16B chunk ^= (row>>1)&3, pre-swizzled global source, same XOR on ds_read.

__global__ __launch_bounds__(512, 2) void k_gemm1_fast(
    const unsigned short* __restrict__ xb, const unsigned short* __restrict__ W1T,
    const int* __restrict__ offs, const int* __restrict__ tiletab,
    const int* __restrict__ rows, unsigned short* __restrict__ act) {
    const int ti = (blockIdx.x & 7) * (NT128 / 8) + (blockIdx.x >> 3);  // XCD swizzle
    const int tt = tiletab[ti];
    if (tt < 0) return;
    const int e = tt >> 16, m0 = (tt & 0xffff) << 7;
    const int off = offs[e], n_e = offs[e + 1] - off;
    const int by = blockIdx.y;   // 0..5

    __shared__ unsigned short SA[2][128 * 32];   // 16 KiB
    __shared__ unsigned short SB[2][256 * 32];   // 32 KiB

    const int tid = threadIdx.x;
    const int wid = tid >> 6, lane = tid & 63;
    const int l15 = lane & 15, kq = lane >> 4;
    const int wm = wid >> 2, wn = wid & 3;
    const int srow = tid >> 2;
    const int esw = (((tid & 3) ^ ((tid >> 3) & 3)) << 3);
    const int rk = ((kq ^ ((l15 >> 1) & 3)) << 3);

    int tok;
    { int s = m0 + srow; s = (s < n_e) ? s : (n_e - 1); tok = rows[off + s]; }
    size_t bB[2];
#pragma unroll
    for (int j = 0; j < 2; ++j)
        bB[j] = ((size_t)e * (2 * H_DIM) + by * 256 + j * 128 + srow) * D_DIM + esw;

    f32x4 acc[4][4];
#pragma unroll
    for (int m = 0; m < 4; ++m)
#pragma unroll
        for (int n = 0; n < 4; ++n)
#pragma unroll
            for (int r = 0; r < 4; ++r) acc[m][n][r] = 0.f;

    auto stage = [&](int buf, int k0) {
        const unsigned short* ga = xb + (size_t)tok * D_DIM + k0 + esw;
        __builtin_amdgcn_global_load_lds((gas_t)ga,
            (las_t)((char*)&SA[buf][0] + tid * 16), 16, 0, 0);
#pragma unroll
        for (int j = 0; j < 2; ++j) {
            const unsigned short* gb = W1T + bB[j] + k0;
            __builtin_amdgcn_global_load_lds((gas_t)gb,
                (las_t)((char*)&SB[buf][0] + j * 8192 + tid * 16), 16, 0, 0);
        }
    };

    stage(0, 0);
    stage(1, 32);
    int c = 0;
    const int NT = D_DIM / 32;   // 32
    for (int t = 0; t < NT; ++t) {
        if (t < NT - 1) asm volatile("s_waitcnt vmcnt(3)" ::: "memory");
        else            asm volatile("s_waitcnt vmcnt(0)" ::: "memory");
        __builtin_amdgcn_s_barrier();
        asm volatile("" ::: "memory");
        bf16x8 a[4], b[4];
#pragma unroll
        for (int m = 0; m < 4; ++m) {
            const int row = wm * 64 + m * 16 + l15;
            a[m] = __builtin_bit_cast(bf16x8, *reinterpret_cast<const u16x8*>(
                &SA[c][row * 32 + rk]));
        }
#pragma unroll
        for (int n = 0; n < 4; ++n) {
            const int row = wn * 64 + n * 16 + l15;
            b[n] = __builtin_bit_cast(bf16x8, *reinterpret_cast<const u16x8*>(
                &SB[c][row * 32 + rk]));
        }
#pragma unroll
        for (int m = 0; m < 4; ++m)
#pragma unroll
            for (int n = 0; n < 4; ++n)
                acc[m][n] = __builtin_amdgcn_mfma_f32_16x16x32_bf16(a[m], b[n], acc[m][n], 0, 0, 0);
        asm volatile("s_waitcnt lgkmcnt(0)" ::: "memory");
        __builtin_amdgcn_s_barrier();
        asm volatile("" ::: "memory");
        if (t + 2 < NT) stage(c, (t + 2) * 32);
        c ^= 1;
    }
    // epilogue: silu-gate; frag n<2 = v-cols, n>=2 = paired g-cols
#pragma unroll
    for (int m = 0; m < 4; ++m)
#pragma unroll
        for (int r = 0; r < 4; ++r) {
            const int row = wm * 64 + m * 16 + kq * 4 + r;
            if (m0 + row < n_e) {
#pragma unroll
                for (int nv = 0; nv < 2; ++nv) {
                    const int col = by * 128 + wn * 32 + nv * 16 + l15;
                    const float vv = acc[m][nv][r], gg = acc[m][2 + nv][r];
                    const float s = gg / (1.0f + __expf(-gg));
                    act[(size_t)(off + m0 + row) * H_DIM + col] = f2b(vv * s);
                }
            }
        }
}

__global__ __launch_bounds__(512, 2) void k_gemm2_fast(
    const unsigned short* __restrict__ act, const unsigned short* __restrict__ W2T,
    const int* __restrict__ offs, const int* __restrict__ tiletab,
    const float* __restrict__ wslot, unsigned short* __restrict__ slot_out) {
    const int ti = (blockIdx.x & 7) * (NT128 / 8) + (blockIdx.x >> 3);
    const int tt = tiletab[ti];
    if (tt < 0) return;
    const int e = tt >> 16, m0 = (tt & 0xffff) << 7;
    const int off = offs[e], n_e = offs[e + 1] - off;
    const int by = blockIdx.y;   // 0..3

    __shared__ unsigned short SA[2][128 * 32];
    __shared__ unsigned short SB[2][256 * 32];

    const int tid = threadIdx.x;
    const int wid = tid >> 6, lane = tid & 63;
    const int l15 = lane & 15, kq = lane >> 4;
    const int wm = wid >> 2, wn = wid & 3;
    const int srow = tid >> 2;
    const int esw = (((tid & 3) ^ ((tid >> 3) & 3)) << 3);
    const int rk = ((kq ^ ((l15 >> 1) & 3)) << 3);

    int slotA;
    { int s = m0 + srow; s = (s < n_e) ? s : (n_e - 1); slotA = off + s; }
    size_t bB[2];
#pragma unroll
    for (int j = 0; j < 2; ++j)
        bB[j] = ((size_t)e * D_DIM + by * 256 + j * 128 + srow) * H_DIM + esw;

    f32x4 acc[4][4];
#pragma unroll
    for (int m = 0; m < 4; ++m)
#pragma unroll
        for (int n = 0; n < 4; ++n)
#pragma unroll
            for (int r = 0; r < 4; ++r) acc[m][n][r] = 0.f;

    auto stage = [&](int buf, int k0) {
        const unsigned short* ga = act + (size_t)slotA * H_DIM + k0 + esw;
        __builtin_amdgcn_global_load_lds((gas_t)ga,
            (las_t)((char*)&SA[buf][0] + tid * 16), 16, 0, 0);
#pragma unroll
        for (int j = 0; j < 2; ++j) {
            const unsigned short* gb = W2T + bB[j] + k0;
            __builtin_amdgcn_global_load_lds((gas_t)gb,
                (las_t)((char*)&SB[buf][0] + j * 8192 + tid * 16), 16, 0, 0);
        }
    };

    stage(0, 0);
    stage(1, 32);
    int c = 0;
    const int NT = H_DIM / 32;   // 24
    for (int t = 0; t < NT; ++t) {
        if (t < NT - 1) asm volatile("s_waitcnt vmcnt(3)" ::: "memory");
        else            asm volatile("s_waitcnt vmcnt(0)" ::: "memory");
        __builtin_amdgcn_s_barrier();
        asm volatile("" ::: "memory");
        bf16x8 a[4], b[4];
#pragma unroll
        for (int m = 0; m < 4; ++m) {
            const int row = wm * 64 + m * 16 + l15;
            a[m] = __builtin_bit_cast(bf16x8, *reinterpret_cast<const u16x8*>(
                &SA[c][row * 32 + rk]));
        }
#pragma unroll
        for (int n = 0; n < 4; ++n) {
            const int row = wn * 64 + n * 16 + l15;
            b[n] = __builtin_bit_cast(bf16x8, *reinterpret_cast<const u16x8*>(
                &SB[c][row * 32 + rk]));
        }
#pragma unroll
        for (int m = 0; m < 4; ++m)
#pragma unroll
            for (int n = 0; n < 4; ++n)
                acc[m][n] = __builtin_amdgcn_mfma_f32_16x16x32_bf16(a[m], b[n], acc[m][n], 0, 0, 0);
        asm volatile("s_waitcnt lgkmcnt(0)" ::: "memory");
        __builtin_amdgcn_s_barrier();
        asm volatile("" ::: "memory");
        if (t + 2 < NT) stage(c, (t + 2) * 32);
        c ^= 1;
    }
#pragma unroll
    for (int m = 0; m < 4; ++m)
#pragma unroll
        for (int r = 0; r < 4; ++r) {
            const int row = wm * 64 + m * 16 + kq * 4 + r;
            if (m0 + row < n_e) {
                const int slot = off + m0 + row;
                const float w = wslot[slot];
#pragma unroll
                for (int n = 0; n < 4; ++n) {
                    const int col = by * 256 + wn * 64 + n * 16 + l15;
                    slot_out[(size_t)slot * D_DIM + col] = f2b(w * acc[m][n][r]);
                }
            }
        }
}

// ================= FALLBACK PATH (small ws) =================
__global__ __launch_bounds__(256) void k_gather(const float* __restrict__ x,
                                                const int* __restrict__ rows,
                                                unsigned short* __restrict__ xg) {
    const int s = blockIdx.x, t = threadIdx.x;
    const int tok = rows[s];
    const float4 v = *reinterpret_cast<const float4*>(&x[(size_t)tok * D_DIM + t * 4]);
    ushort4 u;
    u.x = f2b(v.x); u.y = f2b(v.y); u.z = f2b(v.z); u.w = f2b(v.w);
    *reinterpret_cast<ushort4*>(&xg[(size_t)s * D_DIM + t * 4]) = u;
}

__global__ __launch_bounds__(256) void k_gemm1_fb(
    const unsigned short* __restrict__ xg, const float* __restrict__ W1,
    const int* __restrict__ offs, const int* __restrict__ tiletab,
    unsigned short* __restrict__ act) {
    const int tt = tiletab[blockIdx.x];
    if (tt < 0) return;
    const int e = tt >> 16, m0 = (tt & 0xffff) << 7;
    const int off = offs[e], n_e = offs[e + 1] - off;
    const int h0 = blockIdx.y * 64;

    __shared__ unsigned short Ab[128 * 64];
    __shared__ unsigned short Bb[128 * 66];

    const int tid = threadIdx.x;
    const int wid = tid >> 6, lane = tid & 63;
    const int l15 = lane & 15, kq = lane >> 4;

    f32x4 acc[2][8];
#pragma unroll
    for (int m = 0; m < 2; ++m)
#pragma unroll
        for (int n = 0; n < 8; ++n)
#pragma unroll
            for (int r = 0; r < 4; ++r) acc[m][n][r] = 0.f;

    for (int k0 = 0; k0 < D_DIM; k0 += 64) {
        __syncthreads();
#pragma unroll
        for (int j = 0; j < 4; ++j) {
            const int o = wid * 4096 + j * 1024 + lane * 16;
            const int row = o >> 7, kb = o & 127;
            int gr = off + m0 + row; gr = (gr < TK) ? gr : (TK - 1);
            const unsigned short* gp = xg + (size_t)gr * D_DIM + k0 + (kb >> 1);
            __builtin_amdgcn_global_load_lds((gas_t)gp,
                (las_t)((char*)Ab + wid * 4096 + j * 1024), 16, 0, 0);
        }
        {
            const float* W1e = W1 + (size_t)e * D_DIM * (2 * H_DIM);
#pragma unroll
            for (int i = 0; i < 8; ++i) {
                const int flat = tid + 256 * i;
                const int cg = flat & 31, kk = flat >> 5;
                const int cc = cg * 4;
                const int gc = (cc < 64) ? (h0 + cc) : (H_DIM + h0 + cc - 64);
                const float4 v = *reinterpret_cast<const float4*>(
                    &W1e[(size_t)(k0 + kk) * (2 * H_DIM) + gc]);
                Bb[(cc + 0) * 66 + kk] = f2b(v.x);
                Bb[(cc + 1) * 66 + kk] = f2b(v.y);
                Bb[(cc + 2) * 66 + kk] = f2b(v.z);
                Bb[(cc + 3) * 66 + kk] = f2b(v.w);
            }
        }
        __syncthreads();
#pragma unroll
        for (int ks = 0; ks < 2; ++ks) {
            bf16x8 a[2], b[8];
#pragma unroll
            for (int m = 0; m < 2; ++m)
                a[m] = __builtin_bit_cast(bf16x8, *reinterpret_cast<const u16x8*>(
                    &Ab[(wid * 32 + m * 16 + l15) * 64 + ks * 32 + kq * 8]));
#pragma unroll
            for (int n = 0; n < 8; ++n)
                b[n] = __builtin_bit_cast(bf16x8, *reinterpret_cast<const u16x8*>(
                    &Bb[(n * 16 + l15) * 66 + ks * 32 + kq * 8]));
#pragma unroll
            for (int m = 0; m < 2; ++m)
#pragma unroll
                for (int n = 0; n < 8; ++n)
                    acc[m][n] = __builtin_amdgcn_mfma_f32_16x16x32_bf16(a[m], b[n], acc[m][n], 0, 0, 0);
        }
    }
#pragma unroll
    for (int m = 0; m < 2; ++m)
#pragma unroll
        for (int n = 0; n < 4; ++n)
#pragma unroll
            for (int r = 0; r < 4; ++r) {
                const int row = wid * 32 + m * 16 + kq * 4 + r;
                if (m0 + row < n_e) {
                    const float vv = acc[m][n][r], gg = acc[m][n + 4][r];
                    const float s = gg / (1.0f + __expf(-gg));
                    act[(size_t)(off + m0 + row) * H_DIM + h0 + n * 16 + l15] = f2b(vv * s);
                }
            }
}

__global__ __launch_bounds__(256) void k_gemm2_fb(
    const unsigned short* __restrict__ act, const float* __restrict__ W2,
    const int* __restrict__ offs, const int* __restrict__ tiletab,
    const float* __restrict__ wslot, unsigned short* __restrict__ slot_out,
    float* __restrict__ y, const int* __restrict__ rows, int atomic_mode) {
    const int tt = tiletab[blockIdx.x];
    if (tt < 0) return;
    const int e = tt >> 16, m0 = (tt & 0xffff) << 7;
    const int off = offs[e], n_e = offs[e + 1] - off;
    const int n0 = blockIdx.y * 64;

    __shared__ unsigned short Ab[128 * 64];
    __shared__ unsigned short Bb[64 * 66];

    const int tid = threadIdx.x;
    const int wid = tid >> 6, lane = tid & 63;
    const int l15 = lane & 15, kq = lane >> 4;

    f32x4 acc[2][4];
#pragma unroll
    for (int m = 0; m < 2; ++m)
#pragma unroll
        for (int n = 0; n < 4; ++n)
#pragma unroll
            for (int r = 0; r < 4; ++r) acc[m][n][r] = 0.f;

    for (int k0 = 0; k0 < H_DIM; k0 += 64) {
        __syncthreads();
#pragma unroll
        for (int j = 0; j < 4; ++j) {
            const int o = wid * 4096 + j * 1024 + lane * 16;
            const int row = o >> 7, kb = o & 127;
            int gr = off + m0 + row; gr = (gr < TK) ? gr : (TK - 1);
            const unsigned short* gp = act + (size_t)gr * H_DIM + k0 + (kb >> 1);
            __builtin_amdgcn_global_load_lds((gas_t)gp,
                (las_t)((char*)Ab + wid * 4096 + j * 1024), 16, 0, 0);
        }
        {
            const float* W2e = W2 + (size_t)e * H_DIM * D_DIM;
#pragma unroll
            for (int i = 0; i < 4; ++i) {
                const int flat = tid + 256 * i;
                const int cg = flat & 15, kk = flat >> 4;
                const int cc = cg * 4;
                const float4 v = *reinterpret_cast<const float4*>(
                    &W2e[(size_t)(k0 + kk) * D_DIM + n0 + cc]);
                Bb[(cc + 0) * 66 + kk] = f2b(v.x);
                Bb[(cc + 1) * 66 + kk] = f2b(v.y);
                Bb[(cc + 2) * 66 + kk] = f2b(v.z);
                Bb[(cc + 3) * 66 + kk] = f2b(v.w);
            }
        }
        __syncthreads();
#pragma unroll
        for (int ks = 0; ks < 2; ++ks) {
            bf16x8 a[2], b[4];
#pragma unroll
            for (int m = 0; m < 2; ++m)
                a[m] = __builtin_bit_cast(bf16x8, *reinterpret_cast<const u16x8*>(
                    &Ab[(wid * 32 + m * 16 + l15) * 64 + ks * 32 + kq * 8]));
#pragma unroll
            for (int n = 0; n < 4; ++n)
                b[n] = __builtin_bit_cast(bf16x8, *reinterpret_cast<const u16x8*>(
                    &Bb[(n * 16 + l15) * 66 + ks * 32 + kq * 8]));
#pragma unroll
            for (int m = 0; m < 2; ++m)
#pragma unroll
                for (int n = 0; n < 4; ++n)
                    acc[m][n] = __builtin_amdgcn_mfma_f32_16x16x32_bf16(a[m], b[n], acc[m][n], 0, 0, 0);
        }
    }
#pragma unroll
    for (int m = 0; m < 2; ++m)
#pragma unroll
        for (int r = 0; r < 4; ++r) {
            const int row = wid * 32 + m * 16 + kq * 4 + r;
            if (m0 + row < n_e) {
                const int slot = off + m0 + row;
                const float w = wslot[slot];
#pragma unroll
                for (int n = 0; n < 4; ++n) {
                    const float o = w * acc[m][n][r];
                    if (atomic_mode)
                        atomicAdd(&y[(size_t)rows[slot] * D_DIM + n0 + n * 16 + l15], o);
                    else
                        slot_out[(size_t)slot * D_DIM + n0 + n * 16 + l15] = f2b(o);
                }
            }
        }
}

// ---------------- combine ----------------
__global__ __launch_bounds__(256) void k_combine(
    const unsigned short* __restrict__ slot_out, const int* __restrict__ slot_of,
    float* __restrict__ y) {
    const int t = blockIdx.x;
    const int d = threadIdx.x * 4;
    const int s0 = slot_of[2 * t], s1 = slot_of[2 * t + 1];
    const ushort4 a = *reinterpret_cast<const ushort4*>(&slot_out[(size_t)s0 * D_DIM + d]);
    const ushort4 b = *reinterpret_cast<const ushort4*>(&slot_out[(size_t)s1 * D_DIM + d]);
    float4 r;
    r.x = b2f(a.x) + b2f(b.x);
    r.y = b2f(a.y) + b2f(b.y);
    r.z = b2f(a.z) + b2f(b.z);
    r.w = b2f(a.w) + b2f(b.w);
    *reinterpret_cast<float4*>(&y[(size_t)t * D_DIM + d]) = r;
}

extern "C" void kernel_launch(void* const* d_in, const int* in_sizes, int n_in,
                              void* d_out, int out_size, void* d_ws, size_t ws_size,
                              hipStream_t stream) {
    const float* x = (const float*)d_in[0];
    const float* wts = (const float*)d_in[1];
    const int* idx = (const int*)d_in[2];
    const float* W1 = (const float*)d_in[4];
    const float* W2 = (const float*)d_in[5];
    float* y = (float*)d_out;

    char* ws = (char*)d_ws;
    int* offs = (int*)(ws + 128);
    int* tiletab = (int*)(ws + 320);
    int* rows = (int*)(ws + 2048);
    float* wslot = (float*)(ws + 2048 + (size_t)TK * 4);
    int* slot_of = (int*)(ws + 2048 + (size_t)TK * 8);
    const size_t OFF_XG = 2048 + (size_t)TK * 12;
    unsigned short* xg = (unsigned short*)(ws + OFF_XG);
    unsigned short* xb = xg;
    const size_t OFF_ACT = OFF_XG + (size_t)TK * D_DIM * 2;
    unsigned short* act = (unsigned short*)(ws + OFF_ACT);
    const size_t OFF_SO = OFF_ACT + (size_t)TK * H_DIM * 2;
    unsigned short* slot_out = (unsigned short*)(ws + OFF_SO);
    const size_t MID_END = OFF_SO + (size_t)TK * D_DIM * 2;
    const size_t OFF_W1T = MID_END;
    unsigned short* W1T = (unsigned short*)(ws + OFF_W1T);
    const size_t OFF_W2T = OFF_W1T + (size_t)E_EXP * 2 * H_DIM * D_DIM * 2;
    unsigned short* W2T = (unsigned short*)(ws + OFF_W2T);
    const size_t FULL_END = OFF_W2T + (size_t)E_EXP * D_DIM * H_DIM * 2;

    const int full = (ws_size >= FULL_END) ? 1 : 0;
    const int atomic_mode = (!full && ws_size < MID_END) ? 1 : 0;

    if (full) {
        k_preproute<<<PRB_TOT, 512, 0, stream>>>(x, W1, W2, idx, wts, xb, W1T, W2T,
                                                 offs, tiletab, rows, wslot, slot_of);
        dim3 g1(NT128, H_DIM / 128);
        k_gemm1_fast<<<g1, 512, 0, stream>>>(xb, W1T, offs, tiletab, rows, act);
        dim3 g2(NT128, D_DIM / 256);
        k_gemm2_fast<<<g2, 512, 0, stream>>>(act, W2T, offs, tiletab, wslot, slot_out);
        k_combine<<<T_TOK, 256, 0, stream>>>(slot_out, slot_of, y);
    } else {
        k_route<<<1, 1024, 0, stream>>>(idx, wts, offs, tiletab, rows, wslot, slot_of);
        k_gather<<<TK, 256, 0, stream>>>(x, rows, xg);
        dim3 g1(NT128, H_DIM / 64);
        k_gemm1_fb<<<g1, 256, 0, stream>>>(xg, W1, offs, tiletab, act);
        if (atomic_mode) hipMemsetAsync(y, 0, (size_t)out_size * 4, stream);
        dim3 g2(NT128, D_DIM / 64);
        k_gemm2_fb<<<g2, 256, 0, stream>>>(act, W2, offs, tiletab, wslot, slot_out, y, rows, atomic_mode);
        if (!atomic_mode)
            k_combine<<<T_TOK, 256, 0, stream>>>(slot_out, slot_of, y);
    }
}